// Round 2
// baseline (2548.758 us; speedup 1.0000x reference)
//
#include <hip/hip_runtime.h>
#include <hip/hip_bf16.h>
#include <math.h>

#define RTOT 8192      // B*T
#define TSEQ 2048
#define NHEAD 16

__device__ __forceinline__ float sigmoidf_(float x) { return 1.f / (1.f + expf(-x)); }

// ---------------- generic fp32 GEMM: C = A[M,K] @ B[K,N], optional gated epilogue
// GATED=1: C[m,n] = P[m,n] * sigmoid(acc)
template<int GATED>
__global__ __launch_bounds__(256) void gemm_f32(const float* __restrict__ A,
                                                const float* __restrict__ Bm,
                                                float* __restrict__ C,
                                                const float* __restrict__ P,
                                                int M, int N, int K) {
  __shared__ float As[16][65];   // [k][m], padded
  __shared__ float Bs[16][64];   // [k][n]
  const int tid = threadIdx.x;
  const int m0 = blockIdx.y * 64;
  const int n0 = blockIdx.x * 64;
  const int ty = tid >> 4, tx = tid & 15;
  const int arow = tid >> 2, akq = tid & 3;
  const int bkr = tid >> 4, bnq = tid & 15;
  float acc[4][4] = {};
  for (int k0 = 0; k0 < K; k0 += 16) {
    float4 a4 = *(const float4*)(A + (size_t)(m0 + arow) * K + k0 + akq * 4);
    float4 b4 = *(const float4*)(Bm + (size_t)(k0 + bkr) * N + n0 + bnq * 4);
    As[akq*4+0][arow] = a4.x;
    As[akq*4+1][arow] = a4.y;
    As[akq*4+2][arow] = a4.z;
    As[akq*4+3][arow] = a4.w;
    *(float4*)(&Bs[bkr][bnq*4]) = b4;
    __syncthreads();
#pragma unroll
    for (int kk = 0; kk < 16; ++kk) {
      float av[4], bv[4];
#pragma unroll
      for (int i = 0; i < 4; ++i) av[i] = As[kk][ty*4+i];
      float4 bq = *(const float4*)(&Bs[kk][tx*4]);
      bv[0]=bq.x; bv[1]=bq.y; bv[2]=bq.z; bv[3]=bq.w;
#pragma unroll
      for (int i = 0; i < 4; ++i)
#pragma unroll
        for (int j = 0; j < 4; ++j) acc[i][j] = fmaf(av[i], bv[j], acc[i][j]);
    }
    __syncthreads();
  }
#pragma unroll
  for (int i = 0; i < 4; ++i) {
    int m = m0 + ty*4 + i;
#pragma unroll
    for (int j = 0; j < 4; ++j) {
      int n = n0 + tx*4 + j;
      float v = acc[i][j];
      if (GATED) v = P[(size_t)m * N + n] * sigmoidf_(v);
      C[(size_t)m * N + n] = v;
    }
  }
}

// ---------------- zero-centered RMSNorm per row (C = 1024 or 2048), in-place safe
template<int C>
__global__ __launch_bounds__(256) void zrms_kernel(const float* __restrict__ in,
                                                   const float* __restrict__ g,
                                                   float* __restrict__ out) {
  constexpr int NQ = C / 1024;
  __shared__ float red[4];
  const int tid = threadIdx.x;
  const size_t row = blockIdx.x;
  const float* x = in + row * C;
  float4 v[NQ];
  float s = 0.f;
#pragma unroll
  for (int i = 0; i < NQ; ++i) {
    v[i] = *(const float4*)(x + tid*4 + i*1024);
    s += v[i].x + v[i].y + v[i].z + v[i].w;
  }
#pragma unroll
  for (int o = 32; o > 0; o >>= 1) s += __shfl_xor(s, o, 64);
  if ((tid & 63) == 0) red[tid >> 6] = s;
  __syncthreads();
  const float mean = (red[0]+red[1]+red[2]+red[3]) * (1.f / C);
  __syncthreads();
  float ss = 0.f;
#pragma unroll
  for (int i = 0; i < NQ; ++i) {
    v[i].x -= mean; v[i].y -= mean; v[i].z -= mean; v[i].w -= mean;
    ss += v[i].x*v[i].x + v[i].y*v[i].y + v[i].z*v[i].z + v[i].w*v[i].w;
  }
#pragma unroll
  for (int o = 32; o > 0; o >>= 1) ss += __shfl_xor(ss, o, 64);
  if ((tid & 63) == 0) red[tid >> 6] = ss;
  __syncthreads();
  const float r = rsqrtf((red[0]+red[1]+red[2]+red[3]) * (1.f / C) + 1e-5f);
  float* y = out + row * C;
#pragma unroll
  for (int i = 0; i < NQ; ++i) {
    float4 g4 = *(const float4*)(g + tid*4 + i*1024);
    float4 o4;
    o4.x = v[i].x * r * g4.x;
    o4.y = v[i].y * r * g4.y;
    o4.z = v[i].z * r * g4.z;
    o4.w = v[i].w * r * g4.w;
    *(float4*)(y + tid*4 + i*1024) = o4;
  }
}

// ---------------- causal depthwise conv (K=4) + SiLU
template<int C>
__global__ __launch_bounds__(256) void convsilu_kernel(const float* __restrict__ zn,
                                                       const float* __restrict__ w,
                                                       float* __restrict__ out) {
  const size_t idx = (size_t)blockIdx.x * 256 + threadIdx.x;  // over RTOT*C/4
  const int c = (int)(idx % (C/4)) * 4;
  const int row = (int)(idx / (C/4));
  const int t = row % TSEQ;
  float4 acc = {0.f, 0.f, 0.f, 0.f};
#pragma unroll
  for (int d = 0; d < 4; ++d) {
    if (t - d >= 0) {
      float4 xv = *(const float4*)(zn + (size_t)(row - d) * C + c);
      float4 wv = *(const float4*)(w + (size_t)(3 - d) * C + c);
      acc.x = fmaf(xv.x, wv.x, acc.x);
      acc.y = fmaf(xv.y, wv.y, acc.y);
      acc.z = fmaf(xv.z, wv.z, acc.z);
      acc.w = fmaf(xv.w, wv.w, acc.w);
    }
  }
  float4 o4;
  o4.x = acc.x * sigmoidf_(acc.x);
  o4.y = acc.y * sigmoidf_(acc.y);
  o4.z = acc.z * sigmoidf_(acc.z);
  o4.w = acc.w * sigmoidf_(acc.w);
  *(float4*)(out + (size_t)row * C + c) = o4;
}

// ---------------- g = sigmoid(x@Wa) * sigmoid(x@Wb)  per (row, head)
__global__ __launch_bounds__(256) void gab_kernel(const float* __restrict__ x,
                                                  const float* __restrict__ Wa,
                                                  const float* __restrict__ Wb,
                                                  float* __restrict__ gout) {
  __shared__ float xs[1024];
  __shared__ float partial[256];
  const int tid = threadIdx.x;
  const size_t row = blockIdx.x;
  *(float4*)(&xs[tid*4]) = *(const float4*)(x + row*1024 + tid*4);
  __syncthreads();
  const int h = tid & 31;           // 0..15 -> Wa col h ; 16..31 -> Wb col h-16
  const int seg = tid >> 5;         // 0..7, each 128 k's
  const float* W = (h < 16) ? Wa : Wb;
  const int col = h & 15;
  float s = 0.f;
  const int k0 = seg * 128;
  for (int k = 0; k < 128; ++k) s = fmaf(xs[k0 + k], W[(size_t)(k0 + k) * 16 + col], s);
  partial[tid] = s;
  __syncthreads();
  if (tid < 32) {
    float t2 = 0.f;
#pragma unroll
    for (int j = 0; j < 8; ++j) t2 += partial[j*32 + tid];
    partial[tid] = t2;
  }
  __syncthreads();
  if (tid < 16)
    gout[row*16 + tid] = sigmoidf_(partial[tid]) * sigmoidf_(partial[tid + 16]);
}

// ---------------- chunked causal linear attention
// Gating identity: S_new = a*(S + b v k^T) + (1-a) S  ==  S + (a*b) v k^T
// => o_t = sum_{s<=t} g_s (q_t . k_s) v_s , g = alpha*beta scalar per (b,t,h).
// Block = (b, h, vgroup of 32 v-dims). Chunk = 32 timesteps. S kept in LDS.
__global__ __launch_bounds__(256) void recur_kernel(const float* __restrict__ q,
                                                    const float* __restrict__ k,
                                                    const float* __restrict__ v,
                                                    const float* __restrict__ g,
                                                    float* __restrict__ o) {
  __shared__ float qs[32][65], ks[32][65];
  __shared__ float As[32][33];
  __shared__ float vs[32][33];
  __shared__ float Ss[32][65];   // S[vd][kk]
  __shared__ float gs[32];
  const int tid = threadIdx.x;
  const int bid = blockIdx.x;
  const int vg = bid & 3;
  const int h = (bid >> 2) & 15;
  const int b = bid >> 6;
  for (int i = tid; i < 32*65; i += 256) (&Ss[0][0])[i] = 0.f;
  const size_t rb = (size_t)b * TSEQ;
  __syncthreads();
  for (int ci = 0; ci < 64; ++ci) {
    const int t0 = ci * 32;
    // ---- stage chunk
#pragma unroll
    for (int it = 0; it < 2; ++it) {
      int idx = tid + it*256;
      int r = idx >> 4, jq = idx & 15;
      float4 q4 = *(const float4*)(q + ((rb + t0 + r)*1024 + h*64 + jq*4));
      qs[r][jq*4+0]=q4.x; qs[r][jq*4+1]=q4.y; qs[r][jq*4+2]=q4.z; qs[r][jq*4+3]=q4.w;
      float4 k4 = *(const float4*)(k + ((rb + t0 + r)*1024 + h*64 + jq*4));
      ks[r][jq*4+0]=k4.x; ks[r][jq*4+1]=k4.y; ks[r][jq*4+2]=k4.z; ks[r][jq*4+3]=k4.w;
    }
    {
      int r = tid >> 3, jq = tid & 7;
      float4 v4 = *(const float4*)(v + ((rb + t0 + r)*2048 + h*128 + vg*32 + jq*4));
      vs[r][jq*4+0]=v4.x; vs[r][jq*4+1]=v4.y; vs[r][jq*4+2]=v4.z; vs[r][jq*4+3]=v4.w;
    }
    if (tid < 32) gs[tid] = g[(rb + t0 + tid)*16 + h];
    __syncthreads();
    // ---- A[t][s] = g_s * (q_t . k_s) for s<=t ; 2x2 tile per thread
    {
      const int ti = tid >> 4, si = tid & 15;
      float a00=0.f, a01=0.f, a10=0.f, a11=0.f;
#pragma unroll 4
      for (int kk = 0; kk < 64; ++kk) {
        float q0 = qs[ti*2+0][kk], q1 = qs[ti*2+1][kk];
        float k0v = ks[si*2+0][kk], k1v = ks[si*2+1][kk];
        a00 = fmaf(q0,k0v,a00); a01 = fmaf(q0,k1v,a01);
        a10 = fmaf(q1,k0v,a10); a11 = fmaf(q1,k1v,a11);
      }
      const int t_ = ti*2, s_ = si*2;
      As[t_+0][s_+0] = (s_+0 <= t_+0) ? a00*gs[s_+0] : 0.f;
      As[t_+0][s_+1] = (s_+1 <= t_+0) ? a01*gs[s_+1] : 0.f;
      As[t_+1][s_+0] = (s_+0 <= t_+1) ? a10*gs[s_+0] : 0.f;
      As[t_+1][s_+1] = (s_+1 <= t_+1) ? a11*gs[s_+1] : 0.f;
    }
    __syncthreads();
    // ---- o = A @ V + Q @ S^T  (uses S from previous chunks)
#pragma unroll
    for (int i = 0; i < 4; ++i) {
      int e = tid + i*256;
      int t = e >> 5, vd = e & 31;
      float acc = 0.f;
#pragma unroll 4
      for (int s = 0; s < 32; ++s) acc = fmaf(As[t][s], vs[s][vd], acc);
#pragma unroll 4
      for (int kk = 0; kk < 64; ++kk) acc = fmaf(qs[t][kk], Ss[vd][kk], acc);
      o[(rb + t0 + t)*2048 + h*128 + vg*32 + vd] = acc;
    }
    __syncthreads();
    // ---- S += (g v) k^T ; each thread owns 8 S-elements
    {
      const int vd = tid >> 3, kc = (tid & 7) * 8;
      float ds[8] = {};
      for (int s = 0; s < 32; ++s) {
        float gv = gs[s] * vs[s][vd];
#pragma unroll
        for (int j = 0; j < 8; ++j) ds[j] = fmaf(gv, ks[s][kc+j], ds[j]);
      }
#pragma unroll
      for (int j = 0; j < 8; ++j) Ss[vd][kc+j] += ds[j];
    }
    __syncthreads();
  }
}

extern "C" void kernel_launch(void* const* d_in, const int* in_sizes, int n_in,
                              void* d_out, int out_size, void* d_ws, size_t ws_size,
                              hipStream_t stream) {
  (void)in_sizes; (void)n_in; (void)out_size; (void)ws_size;
  const float* x  = (const float*)d_in[0];
  const float* Wq = (const float*)d_in[1];
  const float* Wk = (const float*)d_in[2];
  const float* Wv = (const float*)d_in[3];
  const float* gq = (const float*)d_in[4];
  const float* gk = (const float*)d_in[5];
  const float* gv = (const float*)d_in[6];
  const float* cq = (const float*)d_in[7];
  const float* ck = (const float*)d_in[8];
  const float* cv = (const float*)d_in[9];
  const float* Wa = (const float*)d_in[10];
  const float* Wb = (const float*)d_in[11];
  const float* Wo = (const float*)d_in[12];
  const float* Wg = (const float*)d_in[13];
  float* out = (float*)d_out;
  float* ws = (float*)d_ws;

  // workspace layout (floats), peak 48.13M floats = 192.5 MB (ws is >= 256MiB):
  //   W0 [8M]  q-proj / later conv-v out (low half)
  //   W1 [8M]  k-proj / later conv-v out (high half)
  //   W2 [16M] v-proj / later recurrence out
  //   W3 [8M]  conv-q out / later proj
  //   W4 [8M]  conv-k out
  //   gbuf [131072]
  const size_t M8 = (size_t)RTOT * 1024;  // 8M floats
  float* W0   = ws;
  float* W1   = W0 + M8;
  float* W2   = W1 + M8;           // 16M floats
  float* W3   = W2 + 2 * M8;
  float* W4   = W3 + M8;
  float* gbuf = W4 + M8;

  dim3 blk(256);
  // 1) projections
  gemm_f32<0><<<dim3(16,128), blk, 0, stream>>>(x, Wq, W0, nullptr, 8192, 1024, 1024);
  gemm_f32<0><<<dim3(16,128), blk, 0, stream>>>(x, Wk, W1, nullptr, 8192, 1024, 1024);
  gemm_f32<0><<<dim3(32,128), blk, 0, stream>>>(x, Wv, W2, nullptr, 8192, 2048, 1024);
  gab_kernel<<<dim3(8192), blk, 0, stream>>>(x, Wa, Wb, gbuf);
  // 2) zero-centered RMSNorm (in-place)
  zrms_kernel<1024><<<dim3(8192), blk, 0, stream>>>(W0, gq, W0);
  zrms_kernel<1024><<<dim3(8192), blk, 0, stream>>>(W1, gk, W1);
  zrms_kernel<2048><<<dim3(8192), blk, 0, stream>>>(W2, gv, W2);
  // 3) causal depthwise conv + SiLU
  convsilu_kernel<1024><<<dim3(8192), blk, 0, stream>>>(W0, cq, W3);   // q
  convsilu_kernel<1024><<<dim3(8192), blk, 0, stream>>>(W1, ck, W4);   // k
  convsilu_kernel<2048><<<dim3(16384), blk, 0, stream>>>(W2, cv, W0);  // v -> W0∪W1
  // 4+5) gated-delta recurrence == gain-scaled causal linear attention
  recur_kernel<<<dim3(256), blk, 0, stream>>>(W3, W4, W0, gbuf, W2);
  // 6) output projection + sigmoid gate
  gemm_f32<0><<<dim3(16,128), blk, 0, stream>>>(W2, Wo, W3, nullptr, 8192, 1024, 2048);
  gemm_f32<1><<<dim3(16,128), blk, 0, stream>>>(W3, Wg, out, W3, 8192, 1024, 1024);
}

// Round 5
// 1294.156 us; speedup vs baseline: 1.9694x; 1.9694x over previous
//
#include <hip/hip_runtime.h>
#include <hip/hip_bf16.h>
#include <math.h>

#define RTOT 8192      // B*T
#define TSEQ 2048

typedef __attribute__((ext_vector_type(8))) short short8;
typedef __attribute__((ext_vector_type(4))) float f32x4;
typedef unsigned short u16;
typedef unsigned int u32;

__device__ __forceinline__ float sigmoidf_(float x) { return 1.f / (1.f + expf(-x)); }
__device__ __forceinline__ float bf2f(u16 v) { u32 u = ((u32)v) << 16; float f; __builtin_memcpy(&f, &u, 4); return f; }
__device__ __forceinline__ u16 f2bf(float f) {
  u32 u; __builtin_memcpy(&u, &f, 4);
  u32 r = (u + 0x7FFFu + ((u >> 16) & 1u)) >> 16;
  return (u16)r;
}
// split f32 -> hi bf16 + lo bf16 (residual); |x - hi - lo| <= ~2^-18 |x|
__device__ __forceinline__ void split2(float x, u16& h, u16& l) {
  u16 hh = f2bf(x);
  float hf = bf2f(hh);
  h = hh; l = f2bf(x - hf);
}

typedef const void __attribute__((address_space(1))) gvoid_t;
typedef void __attribute__((address_space(3))) lvoid_t;
__device__ __forceinline__ void gload_lds16(const void* g, void* l) {
  __builtin_amdgcn_global_load_lds((gvoid_t*)g, (lvoid_t*)l, 16, 0, 0);
}

// ======= split-bf16 MFMA GEMM: C = A[M,K] @ Bt[N,K]^T at ~f32 precision =====
// A = Ah + Al, B = Bh + Bl (bf16 pairs);  C ~= Ah*Bh + Ah*Bl + Al*Bh (f32 acc)
// EPI 0: f32 out.  EPI 1: f32 out + split-bf16 pair out.  EPI 2: f32 out = Pin * sigmoid(acc)
template<int EPI>
__global__ __launch_bounds__(256) void gemm_sp(const u16* __restrict__ Ah, const u16* __restrict__ Al,
                                               const u16* __restrict__ Bh, const u16* __restrict__ Bl,
                                               float* __restrict__ Cf, u16* __restrict__ Ph,
                                               u16* __restrict__ Pl, const float* __restrict__ Pin,
                                               int M, int N, int K) {
  __shared__ u16 Ash[128 * 32], Asl[128 * 32];
  __shared__ u16 Bsh[128 * 32], Bsl[128 * 32];
  const int tid = threadIdx.x;
  const int l = tid & 63, w = tid >> 6;
  const int m0 = blockIdx.y * 128, n0 = blockIdx.x * 128;
  const int wr = w >> 1, wc = w & 1;
  f32x4 acc[4][4] = {};
  // staging geometry (m97 pattern): wave w fills LDS rows [w*32, w*32+32)
  const int srow = (w << 5) + (l >> 2);
  const int scol = (l & 3) << 3;
  const size_t gA = (size_t)(m0 + srow) * K + scol;
  const size_t gB = (size_t)(n0 + srow) * K + scol;
  const int lo0 = (w * 2 + 0) * 512, lo1 = (w * 2 + 1) * 512;
  const int arow = wr * 64 + (l & 15), brow = wc * 64 + (l & 15);
  const int koff = 8 * (l >> 4);
  for (int k0 = 0; k0 < K; k0 += 32) {
    gload_lds16(Ah + gA + k0, &Ash[lo0]);
    gload_lds16(Ah + gA + 16 * K + k0, &Ash[lo1]);
    gload_lds16(Al + gA + k0, &Asl[lo0]);
    gload_lds16(Al + gA + 16 * K + k0, &Asl[lo1]);
    gload_lds16(Bh + gB + k0, &Bsh[lo0]);
    gload_lds16(Bh + gB + 16 * K + k0, &Bsh[lo1]);
    gload_lds16(Bl + gB + k0, &Bsl[lo0]);
    gload_lds16(Bl + gB + 16 * K + k0, &Bsl[lo1]);
    __syncthreads();
    short8 afh[4], afl[4], bfh[4], bfl[4];
#pragma unroll
    for (int m = 0; m < 4; ++m) {
      afh[m] = *(const short8*)&Ash[(arow + m * 16) * 32 + koff];
      afl[m] = *(const short8*)&Asl[(arow + m * 16) * 32 + koff];
    }
#pragma unroll
    for (int n = 0; n < 4; ++n) {
      bfh[n] = *(const short8*)&Bsh[(brow + n * 16) * 32 + koff];
      bfl[n] = *(const short8*)&Bsl[(brow + n * 16) * 32 + koff];
    }
#pragma unroll
    for (int m = 0; m < 4; ++m)
#pragma unroll
      for (int n = 0; n < 4; ++n) {
        acc[m][n] = __builtin_amdgcn_mfma_f32_16x16x32_bf16(afh[m], bfh[n], acc[m][n], 0, 0, 0);
        acc[m][n] = __builtin_amdgcn_mfma_f32_16x16x32_bf16(afh[m], bfl[n], acc[m][n], 0, 0, 0);
        acc[m][n] = __builtin_amdgcn_mfma_f32_16x16x32_bf16(afl[m], bfh[n], acc[m][n], 0, 0, 0);
      }
    __syncthreads();
  }
  const int rbase = m0 + wr * 64 + 4 * (l >> 4);
  const int cbase = n0 + wc * 64 + (l & 15);
#pragma unroll
  for (int m = 0; m < 4; ++m)
#pragma unroll
    for (int n = 0; n < 4; ++n)
#pragma unroll
      for (int r = 0; r < 4; ++r) {
        size_t idx = (size_t)(rbase + m * 16 + r) * N + (cbase + n * 16);
        float v = acc[m][n][r];
        if (EPI == 0) {
          Cf[idx] = v;
        } else if (EPI == 1) {
          Cf[idx] = v;
          u16 h, lo; split2(v, h, lo);
          Ph[idx] = h; Pl[idx] = lo;
        } else {
          Cf[idx] = Pin[idx] * sigmoidf_(v);
        }
      }
}

// ======= weight cast+transpose+split: W[K][N] f32 -> Wt_h/Wt_l [N][K] =======
__global__ __launch_bounds__(256) void transcast_sp(const float* __restrict__ W,
                                                    u16* __restrict__ Wth, u16* __restrict__ Wtl,
                                                    int K, int N) {
  __shared__ float t[32][33];
  const int n0 = blockIdx.x * 32, k0 = blockIdx.y * 32;
  const int c = threadIdx.x & 31, rq = threadIdx.x >> 5;
#pragma unroll
  for (int i = 0; i < 4; ++i) t[rq * 4 + i][c] = W[(size_t)(k0 + rq * 4 + i) * N + n0 + c];
  __syncthreads();
#pragma unroll
  for (int i = 0; i < 4; ++i) {
    float v = t[c][rq * 4 + i];
    u16 h, lo; split2(v, h, lo);
    size_t idx = (size_t)(n0 + rq * 4 + i) * K + k0 + c;
    Wth[idx] = h; Wtl[idx] = lo;
  }
}

// ======= x cast+split f32 -> bf16 hi/lo =====================================
__global__ __launch_bounds__(256) void castx_sp(const float* __restrict__ x,
                                                u16* __restrict__ xh, u16* __restrict__ xl) {
  size_t i = (size_t)blockIdx.x * 256 + threadIdx.x;
  float4 v = ((const float4*)x)[i];
  ushort4 hh, ll;
  split2(v.x, hh.x, ll.x); split2(v.y, hh.y, ll.y);
  split2(v.z, hh.z, ll.z); split2(v.w, hh.w, ll.w);
  ((ushort4*)xh)[i] = hh; ((ushort4*)xl)[i] = ll;
}

// ======= o (4 per-batch f32 chunks) -> split bf16 hi/lo [8192][2048] ========
__global__ __launch_bounds__(256) void osplit(const float* __restrict__ o0, const float* __restrict__ o1,
                                              const float* __restrict__ o2, const float* __restrict__ o3,
                                              u16* __restrict__ oh, u16* __restrict__ ol) {
  size_t i = (size_t)blockIdx.x * 256 + threadIdx.x;   // float4 index, 8192*2048/4 total
  int row = (int)(i >> 9);                              // 512 float4 per row
  int cb = (int)(i & 511);
  const float* src = (row < 4096) ? ((row < 2048) ? o0 : o1) : ((row < 6144) ? o2 : o3);
  float4 v = ((const float4*)(src + (size_t)(row & 2047) * 2048))[cb];
  ushort4 hh, ll;
  split2(v.x, hh.x, ll.x); split2(v.y, hh.y, ll.y);
  split2(v.z, hh.z, ll.z); split2(v.w, hh.w, ll.w);
  ((ushort4*)(oh + (size_t)row * 2048))[cb] = hh;
  ((ushort4*)(ol + (size_t)row * 2048))[cb] = ll;
}

// ======= zero-centered RMSNorm per row, f32, in-place safe (r2 proven) ======
template<int C>
__global__ __launch_bounds__(256) void zrms_kernel(const float* __restrict__ in,
                                                   const float* __restrict__ g,
                                                   float* __restrict__ out) {
  constexpr int NQ = C / 1024;
  __shared__ float red[4];
  const int tid = threadIdx.x;
  const size_t row = blockIdx.x;
  const float* x = in + row * C;
  float4 v[NQ];
  float s = 0.f;
#pragma unroll
  for (int i = 0; i < NQ; ++i) {
    v[i] = *(const float4*)(x + tid*4 + i*1024);
    s += v[i].x + v[i].y + v[i].z + v[i].w;
  }
#pragma unroll
  for (int o = 32; o > 0; o >>= 1) s += __shfl_xor(s, o, 64);
  if ((tid & 63) == 0) red[tid >> 6] = s;
  __syncthreads();
  const float mean = (red[0]+red[1]+red[2]+red[3]) * (1.f / C);
  __syncthreads();
  float ss = 0.f;
#pragma unroll
  for (int i = 0; i < NQ; ++i) {
    v[i].x -= mean; v[i].y -= mean; v[i].z -= mean; v[i].w -= mean;
    ss += v[i].x*v[i].x + v[i].y*v[i].y + v[i].z*v[i].z + v[i].w*v[i].w;
  }
#pragma unroll
  for (int o = 32; o > 0; o >>= 1) ss += __shfl_xor(ss, o, 64);
  if ((tid & 63) == 0) red[tid >> 6] = ss;
  __syncthreads();
  const float r = rsqrtf((red[0]+red[1]+red[2]+red[3]) * (1.f / C) + 1e-5f);
  float* y = out + row * C;
#pragma unroll
  for (int i = 0; i < NQ; ++i) {
    float4 g4 = *(const float4*)(g + tid*4 + i*1024);
    float4 o4;
    o4.x = v[i].x * r * g4.x;
    o4.y = v[i].y * r * g4.y;
    o4.z = v[i].z * r * g4.z;
    o4.w = v[i].w * r * g4.w;
    *(float4*)(y + tid*4 + i*1024) = o4;
  }
}

// ======= causal depthwise conv (K=4) + SiLU, f32 (r2 proven) ================
// NROWS = rows this launch covers (full 8192 or per-batch 2048); t = row % TSEQ
template<int C>
__global__ __launch_bounds__(256) void convsilu_kernel(const float* __restrict__ zn,
                                                       const float* __restrict__ w,
                                                       float* __restrict__ out) {
  const size_t idx = (size_t)blockIdx.x * 256 + threadIdx.x;  // over NROWS*C/4
  const int c = (int)(idx % (C/4)) * 4;
  const int row = (int)(idx / (C/4));
  const int t = row % TSEQ;
  float4 acc = {0.f, 0.f, 0.f, 0.f};
#pragma unroll
  for (int d = 0; d < 4; ++d) {
    if (t - d >= 0) {
      float4 xv = *(const float4*)(zn + (size_t)(row - d) * C + c);
      float4 wv = *(const float4*)(w + (size_t)(3 - d) * C + c);
      acc.x = fmaf(xv.x, wv.x, acc.x);
      acc.y = fmaf(xv.y, wv.y, acc.y);
      acc.z = fmaf(xv.z, wv.z, acc.z);
      acc.w = fmaf(xv.w, wv.w, acc.w);
    }
  }
  float4 o4;
  o4.x = acc.x * sigmoidf_(acc.x);
  o4.y = acc.y * sigmoidf_(acc.y);
  o4.z = acc.z * sigmoidf_(acc.z);
  o4.w = acc.w * sigmoidf_(acc.w);
  *(float4*)(out + (size_t)row * C + c) = o4;
}

// ======= g = sigmoid(x@Wa)*sigmoid(x@Wb) per (row,head), f32 (r2 proven) ====
__global__ __launch_bounds__(256) void gab_kernel(const float* __restrict__ x,
                                                  const float* __restrict__ Wa,
                                                  const float* __restrict__ Wb,
                                                  float* __restrict__ gout) {
  __shared__ float xs[1024];
  __shared__ float partial[256];
  const int tid = threadIdx.x;
  const size_t row = blockIdx.x;
  *(float4*)(&xs[tid*4]) = *(const float4*)(x + row*1024 + tid*4);
  __syncthreads();
  const int h = tid & 31;
  const int seg = tid >> 5;
  const float* W = (h < 16) ? Wa : Wb;
  const int col = h & 15;
  float s = 0.f;
  const int k0 = seg * 128;
  for (int k = 0; k < 128; ++k) s = fmaf(xs[k0 + k], W[(size_t)(k0 + k) * 16 + col], s);
  partial[tid] = s;
  __syncthreads();
  if (tid < 32) {
    float t2 = 0.f;
#pragma unroll
    for (int j = 0; j < 8; ++j) t2 += partial[j*32 + tid];
    partial[tid] = t2;
  }
  __syncthreads();
  if (tid < 16)
    gout[row*16 + tid] = sigmoidf_(partial[tid]) * sigmoidf_(partial[tid + 16]);
}

// ======= chunked causal linear attention, f32 (r2 proven; per-batch o ptrs) =
__global__ __launch_bounds__(256) void recur_kernel(const float* __restrict__ q,
                                                    const float* __restrict__ k,
                                                    const float* __restrict__ v,
                                                    const float* __restrict__ g,
                                                    float* __restrict__ o0,
                                                    float* __restrict__ o1,
                                                    float* __restrict__ o2,
                                                    float* __restrict__ o3) {
  __shared__ float qs[32][65], ks[32][65];
  __shared__ float As[32][33];
  __shared__ float vs[32][33];
  __shared__ float Ss[32][65];   // S[vd][kk]
  __shared__ float gs[32];
  const int tid = threadIdx.x;
  const int bid = blockIdx.x;
  const int vg = bid & 3;
  const int h = (bid >> 2) & 15;
  const int b = bid >> 6;
  float* optr = (b == 0) ? o0 : ((b == 1) ? o1 : ((b == 2) ? o2 : o3));
  for (int i = tid; i < 32*65; i += 256) (&Ss[0][0])[i] = 0.f;
  const size_t rb = (size_t)b * TSEQ;
  __syncthreads();
  for (int ci = 0; ci < 64; ++ci) {
    const int t0 = ci * 32;
#pragma unroll
    for (int it = 0; it < 2; ++it) {
      int idx = tid + it*256;
      int r = idx >> 4, jq = idx & 15;
      float4 q4 = *(const float4*)(q + ((rb + t0 + r)*1024 + h*64 + jq*4));
      qs[r][jq*4+0]=q4.x; qs[r][jq*4+1]=q4.y; qs[r][jq*4+2]=q4.z; qs[r][jq*4+3]=q4.w;
      float4 k4 = *(const float4*)(k + ((rb + t0 + r)*1024 + h*64 + jq*4));
      ks[r][jq*4+0]=k4.x; ks[r][jq*4+1]=k4.y; ks[r][jq*4+2]=k4.z; ks[r][jq*4+3]=k4.w;
    }
    {
      int r = tid >> 3, jq = tid & 7;
      float4 v4 = *(const float4*)(v + ((rb + t0 + r)*2048 + h*128 + vg*32 + jq*4));
      vs[r][jq*4+0]=v4.x; vs[r][jq*4+1]=v4.y; vs[r][jq*4+2]=v4.z; vs[r][jq*4+3]=v4.w;
    }
    if (tid < 32) gs[tid] = g[(rb + t0 + tid)*16 + h];
    __syncthreads();
    {
      const int ti = tid >> 4, si = tid & 15;
      float a00=0.f, a01=0.f, a10=0.f, a11=0.f;
#pragma unroll 4
      for (int kk = 0; kk < 64; ++kk) {
        float q0 = qs[ti*2+0][kk], q1 = qs[ti*2+1][kk];
        float k0v = ks[si*2+0][kk], k1v = ks[si*2+1][kk];
        a00 = fmaf(q0,k0v,a00); a01 = fmaf(q0,k1v,a01);
        a10 = fmaf(q1,k0v,a10); a11 = fmaf(q1,k1v,a11);
      }
      const int t_ = ti*2, s_ = si*2;
      As[t_+0][s_+0] = (s_+0 <= t_+0) ? a00*gs[s_+0] : 0.f;
      As[t_+0][s_+1] = (s_+1 <= t_+0) ? a01*gs[s_+1] : 0.f;
      As[t_+1][s_+0] = (s_+0 <= t_+1) ? a10*gs[s_+0] : 0.f;
      As[t_+1][s_+1] = (s_+1 <= t_+1) ? a11*gs[s_+1] : 0.f;
    }
    __syncthreads();
#pragma unroll
    for (int i = 0; i < 4; ++i) {
      int e = tid + i*256;
      int t = e >> 5, vd = e & 31;
      float acc = 0.f;
#pragma unroll 4
      for (int s = 0; s < 32; ++s) acc = fmaf(As[t][s], vs[s][vd], acc);
#pragma unroll 4
      for (int kk = 0; kk < 64; ++kk) acc = fmaf(qs[t][kk], Ss[vd][kk], acc);
      optr[(size_t)(t0 + t)*2048 + h*128 + vg*32 + vd] = acc;
    }
    __syncthreads();
    {
      const int vd = tid >> 3, kc = (tid & 7) * 8;
      float ds[8] = {};
      for (int s = 0; s < 32; ++s) {
        float gv = gs[s] * vs[s][vd];
#pragma unroll
        for (int j = 0; j < 8; ++j) ds[j] = fmaf(gv, ks[s][kc+j], ds[j]);
      }
#pragma unroll
      for (int j = 0; j < 8; ++j) Ss[vd][kc+j] += ds[j];
    }
    __syncthreads();
  }
}

// ===========================================================================
extern "C" void kernel_launch(void* const* d_in, const int* in_sizes, int n_in,
                              void* d_out, int out_size, void* d_ws, size_t ws_size,
                              hipStream_t stream) {
  (void)in_sizes; (void)n_in; (void)out_size; (void)ws_size;
  const float* x  = (const float*)d_in[0];
  const float* Wq = (const float*)d_in[1];
  const float* Wk = (const float*)d_in[2];
  const float* Wv = (const float*)d_in[3];
  const float* gq = (const float*)d_in[4];
  const float* gk = (const float*)d_in[5];
  const float* gv = (const float*)d_in[6];
  const float* cq = (const float*)d_in[7];
  const float* ck = (const float*)d_in[8];
  const float* cv = (const float*)d_in[9];
  const float* Wa = (const float*)d_in[10];
  const float* Wb = (const float*)d_in[11];
  const float* Wo = (const float*)d_in[12];
  const float* Wg = (const float*)d_in[13];
  float* out = (float*)d_out;
  char* ws = (char*)d_ws;

  const size_t MiB = 1024 * 1024;
  // ---- workspace plan, peak 192 MiB; d_out doubles as qc scratch ----
  u16* x_h  = (u16*)(ws + 0 * MiB);      // 16
  u16* x_l  = (u16*)(ws + 16 * MiB);     // 16
  u16* Wo_h = (u16*)(ws + 32 * MiB);     // 4
  u16* Wo_l = (u16*)(ws + 36 * MiB);     // 4
  u16* Wg_h = (u16*)(ws + 40 * MiB);     // 2
  u16* Wg_l = (u16*)(ws + 42 * MiB);     // 2
  u16* Wq_h = (u16*)(ws + 44 * MiB);     // 2
  u16* Wq_l = (u16*)(ws + 46 * MiB);     // 2
  u16* Wk_h = (u16*)(ws + 48 * MiB);     // 2
  u16* Wk_l = (u16*)(ws + 50 * MiB);     // 2
  u16* Wv_h = (u16*)(ws + 52 * MiB);     // 4
  u16* Wv_l = (u16*)(ws + 56 * MiB);     // 4
  float* gbuf  = (float*)(ws + 60 * MiB);   // 0.5
  float* q_pre = (float*)(ws + 64 * MiB);   // 32
  float* k_pre = (float*)(ws + 96 * MiB);   // 32
  float* v_pre = (float*)(ws + 128 * MiB);  // 64
  float* kc    = (float*)(ws + 64 * MiB);   // reuse q_pre (dead after conv-q)
  float* vc    = (float*)(ws + 112 * MiB);  // 64, [8192][2048] f32, 4-launch staggered over v_pre
  float* qc    = (float*)d_out;             // 32, d_out as scratch
  float* o0 = (float*)(ws + 0 * MiB);       // 16 (x_h dead)
  float* o1 = (float*)(ws + 16 * MiB);      // 16 (x_l dead)
  float* o2 = (float*)(ws + 96 * MiB);      // 16 (k_pre head dead)
  float* o3 = (float*)(ws + 176 * MiB);     // 16 (v_pre tail dead)
  u16* oh = (u16*)(ws + 112 * MiB);         // 32 (vc dead after recur)
  u16* ol = (u16*)(ws + 144 * MiB);         // 32
  float* proj = (float*)(ws + 0 * MiB);     // 32 (o0/o1 dead after osplit)
  u16* p_h = (u16*)(ws + 64 * MiB);         // 16 (kc dead)
  u16* p_l = (u16*)(ws + 80 * MiB);         // 16

  dim3 blk(256);
  // casts + splits
  castx_sp<<<dim3(8192), blk, 0, stream>>>(x, x_h, x_l);
  transcast_sp<<<dim3(32, 32), blk, 0, stream>>>(Wq, Wq_h, Wq_l, 1024, 1024);
  transcast_sp<<<dim3(32, 32), blk, 0, stream>>>(Wk, Wk_h, Wk_l, 1024, 1024);
  transcast_sp<<<dim3(64, 32), blk, 0, stream>>>(Wv, Wv_h, Wv_l, 1024, 2048);
  transcast_sp<<<dim3(32, 64), blk, 0, stream>>>(Wo, Wo_h, Wo_l, 2048, 1024);
  transcast_sp<<<dim3(32, 32), blk, 0, stream>>>(Wg, Wg_h, Wg_l, 1024, 1024);
  gab_kernel<<<dim3(8192), blk, 0, stream>>>(x, Wa, Wb, gbuf);
  // projections (split-bf16 MFMA, f32 out)
  gemm_sp<0><<<dim3(8, 64), blk, 0, stream>>>(x_h, x_l, Wq_h, Wq_l, q_pre, nullptr, nullptr, nullptr, 8192, 1024, 1024);
  gemm_sp<0><<<dim3(8, 64), blk, 0, stream>>>(x_h, x_l, Wk_h, Wk_l, k_pre, nullptr, nullptr, nullptr, 8192, 1024, 1024);
  gemm_sp<0><<<dim3(16, 64), blk, 0, stream>>>(x_h, x_l, Wv_h, Wv_l, v_pre, nullptr, nullptr, nullptr, 8192, 2048, 1024);
  // zrms in-place (f32)
  zrms_kernel<1024><<<dim3(8192), blk, 0, stream>>>(q_pre, gq, q_pre);
  zrms_kernel<1024><<<dim3(8192), blk, 0, stream>>>(k_pre, gk, k_pre);
  zrms_kernel<2048><<<dim3(8192), blk, 0, stream>>>(v_pre, gv, v_pre);
  // conv+silu (f32): q -> d_out scratch, k -> old q_pre, v staggered per batch
  convsilu_kernel<1024><<<dim3(8192), blk, 0, stream>>>(q_pre, cq, qc);
  convsilu_kernel<1024><<<dim3(8192), blk, 0, stream>>>(k_pre, ck, kc);
  for (int b = 0; b < 4; ++b)
    convsilu_kernel<2048><<<dim3(4096), blk, 0, stream>>>(v_pre + (size_t)b * 2048 * 2048, cv,
                                                          vc + (size_t)b * 2048 * 2048);
  // gated-delta recurrence (f32, proven)
  recur_kernel<<<dim3(256), blk, 0, stream>>>(qc, kc, vc, gbuf, o0, o1, o2, o3);
  // o -> split bf16
  osplit<<<dim3(16384), blk, 0, stream>>>(o0, o1, o2, o3, oh, ol);
  // output projection (f32 + split pair out) and gated final GEMM
  gemm_sp<1><<<dim3(8, 64), blk, 0, stream>>>(oh, ol, Wo_h, Wo_l, proj, p_h, p_l, nullptr, 8192, 1024, 2048);
  gemm_sp<2><<<dim3(8, 64), blk, 0, stream>>>(p_h, p_l, Wg_h, Wg_l, out, nullptr, nullptr, proj, 8192, 1024, 1024);
}

// Round 6
// 763.517 us; speedup vs baseline: 3.3382x; 1.6950x over previous
//
#include <hip/hip_runtime.h>
#include <hip/hip_bf16.h>
#include <math.h>

#define RTOT 8192      // B*T
#define TSEQ 2048

typedef __attribute__((ext_vector_type(8))) short short8;
typedef __attribute__((ext_vector_type(4))) float f32x4;
typedef unsigned short u16;
typedef unsigned int u32;

union U16x8 { uint4 v; u16 s[8]; };

__device__ __forceinline__ float sigmoidf_(float x) { return 1.f / (1.f + expf(-x)); }
__device__ __forceinline__ float bf2f(u16 v) { u32 u = ((u32)v) << 16; float f; __builtin_memcpy(&f, &u, 4); return f; }
__device__ __forceinline__ u16 f2bf(float f) {
  u32 u; __builtin_memcpy(&u, &f, 4);
  u32 r = (u + 0x7FFFu + ((u >> 16) & 1u)) >> 16;
  return (u16)r;
}
// split f32 -> hi bf16 + lo bf16 (residual); |x - hi - lo| <= ~2^-18 |x|
__device__ __forceinline__ void split2(float x, u16& h, u16& l) {
  u16 hh = f2bf(x);
  float hf = bf2f(hh);
  h = hh; l = f2bf(x - hf);
}

typedef const void __attribute__((address_space(1))) gvoid_t;
typedef void __attribute__((address_space(3))) lvoid_t;
__device__ __forceinline__ void gload_lds16(const void* g, void* l) {
  __builtin_amdgcn_global_load_lds((gvoid_t*)g, (lvoid_t*)l, 16, 0, 0);
}

// ======= split-bf16 MFMA GEMM: C = A[M,K] @ Bt[N,K]^T at ~f32 precision =====
// A = Ah + Al, B = Bh + Bl (bf16 pairs);  C ~= Ah*Bh + Ah*Bl + Al*Bh (f32 acc)
// EPI 0: f32 out.  EPI 1: f32 out + split-bf16 pair out.  EPI 2: f32 out = Pin * sigmoid(acc)
template<int EPI>
__global__ __launch_bounds__(256) void gemm_sp(const u16* __restrict__ Ah, const u16* __restrict__ Al,
                                               const u16* __restrict__ Bh, const u16* __restrict__ Bl,
                                               float* __restrict__ Cf, u16* __restrict__ Ph,
                                               u16* __restrict__ Pl, const float* __restrict__ Pin,
                                               int M, int N, int K) {
  __shared__ u16 Ash[128 * 32], Asl[128 * 32];
  __shared__ u16 Bsh[128 * 32], Bsl[128 * 32];
  const int tid = threadIdx.x;
  const int l = tid & 63, w = tid >> 6;
  const int m0 = blockIdx.y * 128, n0 = blockIdx.x * 128;
  const int wr = w >> 1, wc = w & 1;
  f32x4 acc[4][4] = {};
  const int srow = (w << 5) + (l >> 2);
  const int scol = (l & 3) << 3;
  const size_t gA = (size_t)(m0 + srow) * K + scol;
  const size_t gB = (size_t)(n0 + srow) * K + scol;
  const int lo0 = (w * 2 + 0) * 512, lo1 = (w * 2 + 1) * 512;
  const int arow = wr * 64 + (l & 15), brow = wc * 64 + (l & 15);
  const int koff = 8 * (l >> 4);
  for (int k0 = 0; k0 < K; k0 += 32) {
    gload_lds16(Ah + gA + k0, &Ash[lo0]);
    gload_lds16(Ah + gA + 16 * K + k0, &Ash[lo1]);
    gload_lds16(Al + gA + k0, &Asl[lo0]);
    gload_lds16(Al + gA + 16 * K + k0, &Asl[lo1]);
    gload_lds16(Bh + gB + k0, &Bsh[lo0]);
    gload_lds16(Bh + gB + 16 * K + k0, &Bsh[lo1]);
    gload_lds16(Bl + gB + k0, &Bsl[lo0]);
    gload_lds16(Bl + gB + 16 * K + k0, &Bsl[lo1]);
    __syncthreads();
    short8 afh[4], afl[4], bfh[4], bfl[4];
#pragma unroll
    for (int m = 0; m < 4; ++m) {
      afh[m] = *(const short8*)&Ash[(arow + m * 16) * 32 + koff];
      afl[m] = *(const short8*)&Asl[(arow + m * 16) * 32 + koff];
    }
#pragma unroll
    for (int n = 0; n < 4; ++n) {
      bfh[n] = *(const short8*)&Bsh[(brow + n * 16) * 32 + koff];
      bfl[n] = *(const short8*)&Bsl[(brow + n * 16) * 32 + koff];
    }
#pragma unroll
    for (int m = 0; m < 4; ++m)
#pragma unroll
      for (int n = 0; n < 4; ++n) {
        acc[m][n] = __builtin_amdgcn_mfma_f32_16x16x32_bf16(afh[m], bfh[n], acc[m][n], 0, 0, 0);
        acc[m][n] = __builtin_amdgcn_mfma_f32_16x16x32_bf16(afh[m], bfl[n], acc[m][n], 0, 0, 0);
        acc[m][n] = __builtin_amdgcn_mfma_f32_16x16x32_bf16(afl[m], bfh[n], acc[m][n], 0, 0, 0);
      }
    __syncthreads();
  }
  const int rbase = m0 + wr * 64 + 4 * (l >> 4);
  const int cbase = n0 + wc * 64 + (l & 15);
#pragma unroll
  for (int m = 0; m < 4; ++m)
#pragma unroll
    for (int n = 0; n < 4; ++n)
#pragma unroll
      for (int r = 0; r < 4; ++r) {
        size_t idx = (size_t)(rbase + m * 16 + r) * N + (cbase + n * 16);
        float v = acc[m][n][r];
        if (EPI == 0) {
          Cf[idx] = v;
        } else if (EPI == 1) {
          Cf[idx] = v;
          u16 h, lo; split2(v, h, lo);
          Ph[idx] = h; Pl[idx] = lo;
        } else {
          Cf[idx] = Pin[idx] * sigmoidf_(v);
        }
      }
}

// ======= weight cast+transpose+split: W[K][N] f32 -> Wt_h/Wt_l [N][K] =======
__global__ __launch_bounds__(256) void transcast_sp(const float* __restrict__ W,
                                                    u16* __restrict__ Wth, u16* __restrict__ Wtl,
                                                    int K, int N) {
  __shared__ float t[32][33];
  const int n0 = blockIdx.x * 32, k0 = blockIdx.y * 32;
  const int c = threadIdx.x & 31, rq = threadIdx.x >> 5;
#pragma unroll
  for (int i = 0; i < 4; ++i) t[rq * 4 + i][c] = W[(size_t)(k0 + rq * 4 + i) * N + n0 + c];
  __syncthreads();
#pragma unroll
  for (int i = 0; i < 4; ++i) {
    float v = t[c][rq * 4 + i];
    u16 h, lo; split2(v, h, lo);
    size_t idx = (size_t)(n0 + rq * 4 + i) * K + k0 + c;
    Wth[idx] = h; Wtl[idx] = lo;
  }
}

// ======= x cast+split f32 -> bf16 hi/lo =====================================
__global__ __launch_bounds__(256) void castx_sp(const float* __restrict__ x,
                                                u16* __restrict__ xh, u16* __restrict__ xl) {
  size_t i = (size_t)blockIdx.x * 256 + threadIdx.x;
  float4 v = ((const float4*)x)[i];
  ushort4 hh, ll;
  split2(v.x, hh.x, ll.x); split2(v.y, hh.y, ll.y);
  split2(v.z, hh.z, ll.z); split2(v.w, hh.w, ll.w);
  ((ushort4*)xh)[i] = hh; ((ushort4*)xl)[i] = ll;
}

// ======= zero-centered RMSNorm per row, f32, in-place safe (proven) =========
template<int C>
__global__ __launch_bounds__(256) void zrms_kernel(const float* __restrict__ in,
                                                   const float* __restrict__ g,
                                                   float* __restrict__ out) {
  constexpr int NQ = C / 1024;
  __shared__ float red[4];
  const int tid = threadIdx.x;
  const size_t row = blockIdx.x;
  const float* x = in + row * C;
  float4 v[NQ];
  float s = 0.f;
#pragma unroll
  for (int i = 0; i < NQ; ++i) {
    v[i] = *(const float4*)(x + tid*4 + i*1024);
    s += v[i].x + v[i].y + v[i].z + v[i].w;
  }
#pragma unroll
  for (int o = 32; o > 0; o >>= 1) s += __shfl_xor(s, o, 64);
  if ((tid & 63) == 0) red[tid >> 6] = s;
  __syncthreads();
  const float mean = (red[0]+red[1]+red[2]+red[3]) * (1.f / C);
  __syncthreads();
  float ss = 0.f;
#pragma unroll
  for (int i = 0; i < NQ; ++i) {
    v[i].x -= mean; v[i].y -= mean; v[i].z -= mean; v[i].w -= mean;
    ss += v[i].x*v[i].x + v[i].y*v[i].y + v[i].z*v[i].z + v[i].w*v[i].w;
  }
#pragma unroll
  for (int o = 32; o > 0; o >>= 1) ss += __shfl_xor(ss, o, 64);
  if ((tid & 63) == 0) red[tid >> 6] = ss;
  __syncthreads();
  const float r = rsqrtf((red[0]+red[1]+red[2]+red[3]) * (1.f / C) + 1e-5f);
  float* y = out + row * C;
#pragma unroll
  for (int i = 0; i < NQ; ++i) {
    float4 g4 = *(const float4*)(g + tid*4 + i*1024);
    float4 o4;
    o4.x = v[i].x * r * g4.x;
    o4.y = v[i].y * r * g4.y;
    o4.z = v[i].z * r * g4.z;
    o4.w = v[i].w * r * g4.w;
    *(float4*)(y + tid*4 + i*1024) = o4;
  }
}

// ======= causal depthwise conv (K=4) + SiLU -> split pair; opt g-scale ======
template<int C, int GSCALE>
__global__ __launch_bounds__(256) void conv_sp(const float* __restrict__ zn,
                                               const float* __restrict__ w,
                                               const float* __restrict__ g,
                                               u16* __restrict__ oh,
                                               u16* __restrict__ ol) {
  const size_t idx = (size_t)blockIdx.x * 256 + threadIdx.x;  // over RTOT*C/4
  const int c = (int)(idx % (C/4)) * 4;
  const int row = (int)(idx / (C/4));
  const int t = row % TSEQ;
  float4 acc = {0.f, 0.f, 0.f, 0.f};
#pragma unroll
  for (int d = 0; d < 4; ++d) {
    if (t - d >= 0) {
      float4 xv = *(const float4*)(zn + (size_t)(row - d) * C + c);
      float4 wv = *(const float4*)(w + (size_t)(3 - d) * C + c);
      acc.x = fmaf(xv.x, wv.x, acc.x);
      acc.y = fmaf(xv.y, wv.y, acc.y);
      acc.z = fmaf(xv.z, wv.z, acc.z);
      acc.w = fmaf(xv.w, wv.w, acc.w);
    }
  }
  float a0 = acc.x * sigmoidf_(acc.x);
  float a1 = acc.y * sigmoidf_(acc.y);
  float a2 = acc.z * sigmoidf_(acc.z);
  float a3 = acc.w * sigmoidf_(acc.w);
  if (GSCALE) {
    float gv = g[(size_t)row * 16 + (c >> 7)];
    a0 *= gv; a1 *= gv; a2 *= gv; a3 *= gv;
  }
  ushort4 hh, ll;
  split2(a0, hh.x, ll.x); split2(a1, hh.y, ll.y);
  split2(a2, hh.z, ll.z); split2(a3, hh.w, ll.w);
  *(ushort4*)(oh + (size_t)row * C + c) = hh;
  *(ushort4*)(ol + (size_t)row * C + c) = ll;
}

// ======= g = sigmoid(x@Wa)*sigmoid(x@Wb) per (row,head), f32 (proven) =======
__global__ __launch_bounds__(256) void gab_kernel(const float* __restrict__ x,
                                                  const float* __restrict__ Wa,
                                                  const float* __restrict__ Wb,
                                                  float* __restrict__ gout) {
  __shared__ float xs[1024];
  __shared__ float partial[256];
  const int tid = threadIdx.x;
  const size_t row = blockIdx.x;
  *(float4*)(&xs[tid*4]) = *(const float4*)(x + row*1024 + tid*4);
  __syncthreads();
  const int h = tid & 31;
  const int seg = tid >> 5;
  const float* W = (h < 16) ? Wa : Wb;
  const int col = h & 15;
  float s = 0.f;
  const int k0 = seg * 128;
  for (int k = 0; k < 128; ++k) s = fmaf(xs[k0 + k], W[(size_t)(k0 + k) * 16 + col], s);
  partial[tid] = s;
  __syncthreads();
  if (tid < 32) {
    float t2 = 0.f;
#pragma unroll
    for (int j = 0; j < 8; ++j) t2 += partial[j*32 + tid];
    partial[tid] = t2;
  }
  __syncthreads();
  if (tid < 16)
    gout[row*16 + tid] = sigmoidf_(partial[tid]) * sigmoidf_(partial[tid + 16]);
}

// ======= scan: S_c = sum_{c'<c} Vg_c'^T K_c' ; writes exclusive prefix =====
// grid 256 = (b, h, vq); each block owns vd in [vq*32, vq*32+32), S in regs.
// Sp layout per chunk: [((b*16+h)*32 + c)*8192 + vd*64 + kd], split pair.
__global__ __launch_bounds__(256) void scan_kernel(const u16* __restrict__ kh,
                                                   const u16* __restrict__ kl,
                                                   const u16* __restrict__ vgh,
                                                   const u16* __restrict__ vgl,
                                                   u16* __restrict__ Sph,
                                                   u16* __restrict__ Spl) {
  __shared__ float Ks[64][68];
  __shared__ float Vs[64][36];
  const int tid = threadIdx.x;
  const int bid = blockIdx.x;
  const int vq = bid & 3, h = (bid >> 2) & 15, b = bid >> 6;
  const size_t rb = (size_t)b * TSEQ;
  const int vd_t = tid >> 3, kd0 = (tid & 7) * 8;
  float S[8] = {};
  const int sr = tid >> 2;               // staging row 0..63
  const int kc0 = (tid & 3) * 16;        // k cols
  const int vc0 = (tid & 3) * 8;         // vg cols (of 32)
  for (int c = 0; c < 32; ++c) {
    // stage K (pair -> f32) and Vg slice (pair -> f32)
    {
      size_t off = (rb + (size_t)c * 64 + sr) * 1024 + h * 64 + kc0;
      U16x8 a0, a1, b0, b1;
      a0.v = *(const uint4*)(kh + off);     a1.v = *(const uint4*)(kh + off + 8);
      b0.v = *(const uint4*)(kl + off);     b1.v = *(const uint4*)(kl + off + 8);
#pragma unroll
      for (int j = 0; j < 8; ++j) {
        Ks[sr][kc0 + j]     = bf2f(a0.s[j]) + bf2f(b0.s[j]);
        Ks[sr][kc0 + 8 + j] = bf2f(a1.s[j]) + bf2f(b1.s[j]);
      }
      size_t voff = (rb + (size_t)c * 64 + sr) * 2048 + h * 128 + vq * 32 + vc0;
      U16x8 va, vb;
      va.v = *(const uint4*)(vgh + voff);   vb.v = *(const uint4*)(vgl + voff);
#pragma unroll
      for (int j = 0; j < 8; ++j) Vs[sr][vc0 + j] = bf2f(va.s[j]) + bf2f(vb.s[j]);
    }
    // write exclusive prefix (register S, before update)
    {
      size_t spc = (((size_t)(b * 16 + h) * 32) + c) * 8192 + (size_t)(vq * 32 + vd_t) * 64 + kd0;
      ushort4 h0, h1, l0, l1;
      split2(S[0], h0.x, l0.x); split2(S[1], h0.y, l0.y);
      split2(S[2], h0.z, l0.z); split2(S[3], h0.w, l0.w);
      split2(S[4], h1.x, l1.x); split2(S[5], h1.y, l1.y);
      split2(S[6], h1.z, l1.z); split2(S[7], h1.w, l1.w);
      *(ushort4*)(Sph + spc)     = h0;  *(ushort4*)(Sph + spc + 4) = h1;
      *(ushort4*)(Spl + spc)     = l0;  *(ushort4*)(Spl + spc + 4) = l1;
    }
    __syncthreads();
    // S += Vg^T K over the 64 timesteps of this chunk
    for (int s = 0; s < 64; ++s) {
      float vv = Vs[s][vd_t];
      float k0v[4], k1v[4];
      *(float4*)k0v = *(const float4*)&Ks[s][kd0];
      *(float4*)k1v = *(const float4*)&Ks[s][kd0 + 4];
#pragma unroll
      for (int j = 0; j < 4; ++j) S[j] = fmaf(vv, k0v[j], S[j]);
#pragma unroll
      for (int j = 0; j < 4; ++j) S[4 + j] = fmaf(vv, k1v[j], S[4 + j]);
    }
    __syncthreads();
  }
}

// ======= pass2: O = mask(QK^T) Vg + Q Sp^T  (MFMA, split precision) ========
__global__ __launch_bounds__(256) void pass2_sp(const u16* __restrict__ qh,
                                                const u16* __restrict__ ql,
                                                const u16* __restrict__ kh,
                                                const u16* __restrict__ vgh,
                                                const u16* __restrict__ Sph,
                                                const u16* __restrict__ Spl,
                                                u16* __restrict__ oh,
                                                u16* __restrict__ ol) {
  __shared__ u16 Qsh[64 * 72];
  __shared__ u16 Qsl[64 * 72];
  __shared__ u16 Ksm[64 * 72];
  __shared__ u16 Am[64 * 72];
  __shared__ u16 Vth[128 * 72];
  const int tid = threadIdx.x;
  const int l = tid & 63, w = tid >> 6;
  const int bid = blockIdx.x;
  const int c = bid & 31, h = (bid >> 5) & 15, b = bid >> 9;
  const size_t rb = (size_t)b * TSEQ + c * 64;
  const int fr = l & 15, fq = l >> 4;
  // stage Qh, Ql, Kh
  {
    int r = tid >> 2, c0 = (tid & 3) * 16;
    size_t off = (rb + r) * 1024 + h * 64 + c0;
    *(uint4*)&Qsh[r * 72 + c0]     = *(const uint4*)(qh + off);
    *(uint4*)&Qsh[r * 72 + c0 + 8] = *(const uint4*)(qh + off + 8);
    *(uint4*)&Qsl[r * 72 + c0]     = *(const uint4*)(ql + off);
    *(uint4*)&Qsl[r * 72 + c0 + 8] = *(const uint4*)(ql + off + 8);
    *(uint4*)&Ksm[r * 72 + c0]     = *(const uint4*)(kh + off);
    *(uint4*)&Ksm[r * 72 + c0 + 8] = *(const uint4*)(kh + off + 8);
  }
  // stage Vg^T (hi only; intra-chunk contribution)
  {
    int s = tid >> 2, vd0 = (tid & 3) * 32;
    size_t off = (rb + s) * 2048 + h * 128 + vd0;
#pragma unroll
    for (int m4 = 0; m4 < 4; ++m4) {
      U16x8 r_; r_.v = *(const uint4*)(vgh + off + m4 * 8);
#pragma unroll
      for (int j = 0; j < 8; ++j) Vth[(vd0 + m4 * 8 + j) * 72 + s] = r_.s[j];
    }
  }
  __syncthreads();
  // phase A: A = mask(Q K^T), rows [w*16, w*16+16) per wave (hi x hi)
  short8 aqh[2], aql[2];
#pragma unroll
  for (int kk = 0; kk < 2; ++kk) {
    aqh[kk] = *(const short8*)&Qsh[(w * 16 + fr) * 72 + kk * 32 + 8 * fq];
    aql[kk] = *(const short8*)&Qsl[(w * 16 + fr) * 72 + kk * 32 + 8 * fq];
  }
  f32x4 accA[4] = {};
#pragma unroll
  for (int n = 0; n < 4; ++n)
#pragma unroll
    for (int kk = 0; kk < 2; ++kk) {
      short8 bk = *(const short8*)&Ksm[(n * 16 + fr) * 72 + kk * 32 + 8 * fq];
      accA[n] = __builtin_amdgcn_mfma_f32_16x16x32_bf16(aqh[kk], bk, accA[n], 0, 0, 0);
    }
#pragma unroll
  for (int n = 0; n < 4; ++n)
#pragma unroll
    for (int rr = 0; rr < 4; ++rr) {
      int tt = w * 16 + 4 * fq + rr;
      int s = n * 16 + fr;
      Am[tt * 72 + s] = f2bf((s <= tt) ? accA[n][rr] : 0.f);
    }
  __syncthreads();
  // phase B: O = A Vg + Q Sp^T
  f32x4 acc[8] = {};
#pragma unroll
  for (int kk = 0; kk < 2; ++kk) {
    short8 aa = *(const short8*)&Am[(w * 16 + fr) * 72 + kk * 32 + 8 * fq];
#pragma unroll
    for (int n = 0; n < 8; ++n) {
      short8 bv = *(const short8*)&Vth[(n * 16 + fr) * 72 + kk * 32 + 8 * fq];
      acc[n] = __builtin_amdgcn_mfma_f32_16x16x32_bf16(aa, bv, acc[n], 0, 0, 0);
    }
  }
  const size_t spb = (((size_t)(b * 16 + h) * 32) + c) * 8192;
#pragma unroll
  for (int n = 0; n < 8; ++n)
#pragma unroll
    for (int kk = 0; kk < 2; ++kk) {
      size_t soff = spb + (size_t)(n * 16 + fr) * 64 + kk * 32 + 8 * fq;
      short8 bh_ = *(const short8*)(Sph + soff);
      short8 bl_ = *(const short8*)(Spl + soff);
      acc[n] = __builtin_amdgcn_mfma_f32_16x16x32_bf16(aqh[kk], bh_, acc[n], 0, 0, 0);
      acc[n] = __builtin_amdgcn_mfma_f32_16x16x32_bf16(aqh[kk], bl_, acc[n], 0, 0, 0);
      acc[n] = __builtin_amdgcn_mfma_f32_16x16x32_bf16(aql[kk], bh_, acc[n], 0, 0, 0);
    }
  // epilogue: split o to hi/lo pairs
#pragma unroll
  for (int n = 0; n < 8; ++n)
#pragma unroll
    for (int rr = 0; rr < 4; ++rr) {
      int tt = w * 16 + 4 * fq + rr;
      int vd = n * 16 + fr;
      u16 hh, ll;
      split2(acc[n][rr], hh, ll);
      size_t off = (rb + tt) * 2048 + h * 128 + vd;
      oh[off] = hh; ol[off] = ll;
    }
}

// ===========================================================================
extern "C" void kernel_launch(void* const* d_in, const int* in_sizes, int n_in,
                              void* d_out, int out_size, void* d_ws, size_t ws_size,
                              hipStream_t stream) {
  (void)in_sizes; (void)n_in; (void)out_size; (void)ws_size;
  const float* x  = (const float*)d_in[0];
  const float* Wq = (const float*)d_in[1];
  const float* Wk = (const float*)d_in[2];
  const float* Wv = (const float*)d_in[3];
  const float* gq = (const float*)d_in[4];
  const float* gk = (const float*)d_in[5];
  const float* gv = (const float*)d_in[6];
  const float* cq = (const float*)d_in[7];
  const float* ck = (const float*)d_in[8];
  const float* cv = (const float*)d_in[9];
  const float* Wa = (const float*)d_in[10];
  const float* Wb = (const float*)d_in[11];
  const float* Wo = (const float*)d_in[12];
  const float* Wg = (const float*)d_in[13];
  float* out = (float*)d_out;
  char* ws = (char*)d_ws;

  const size_t MiB = 1024 * 1024;
  // ---- workspace plan, high-water 224 MiB; d_out doubles as vgl/ol scratch -
  u16* Wq_h = (u16*)(ws + 0 * MiB);      // 2
  u16* Wq_l = (u16*)(ws + 2 * MiB);      // 2
  u16* Wk_h = (u16*)(ws + 4 * MiB);      // 2
  u16* Wk_l = (u16*)(ws + 6 * MiB);      // 2
  u16* Wv_h = (u16*)(ws + 8 * MiB);      // 4
  u16* Wv_l = (u16*)(ws + 12 * MiB);     // 4
  u16* Wo_h = (u16*)(ws + 16 * MiB);     // 4
  u16* Wo_l = (u16*)(ws + 20 * MiB);     // 4
  u16* Wg_h = (u16*)(ws + 24 * MiB);     // 2
  u16* Wg_l = (u16*)(ws + 26 * MiB);     // 2
  float* gbuf  = (float*)(ws + 28 * MiB);   // 0.5
  u16* x_h  = (u16*)(ws + 32 * MiB);     // 16
  u16* x_l  = (u16*)(ws + 48 * MiB);     // 16
  float* q_pre = (float*)(ws + 64 * MiB);   // 32
  float* k_pre = (float*)(ws + 96 * MiB);   // 32
  float* v_pre = (float*)(ws + 128 * MiB);  // 64
  // post-conv aliases:
  u16* q_h = (u16*)(ws + 32 * MiB);      // 16 (x_h dead)
  u16* q_l = (u16*)(ws + 48 * MiB);      // 16 (x_l dead)
  u16* k_h = (u16*)(ws + 64 * MiB);      // 16 (q_pre dead after conv-q)
  u16* k_l = (u16*)(ws + 80 * MiB);      // 16
  u16* vg_h = (u16*)(ws + 96 * MiB);     // 32 (k_pre dead after conv-k)
  u16* vg_l = (u16*)d_out;               // 32 (d_out as scratch)
  u16* Sp_h = (u16*)(ws + 128 * MiB);    // 32 (v_pre dead after conv-v)
  u16* Sp_l = (u16*)(ws + 160 * MiB);    // 32
  u16* o_h  = (u16*)(ws + 192 * MiB);    // 32
  u16* o_l  = (u16*)d_out;               // 32 (vg_l dead after scan)
  float* proj = (float*)(ws + 64 * MiB); // 32 (k pair dead after pass2)
  u16* p_h  = (u16*)(ws + 96 * MiB);     // 16 (vg_h dead after pass2)
  u16* p_l  = (u16*)(ws + 112 * MiB);    // 16

  dim3 blk(256);
  // casts + splits
  castx_sp<<<dim3(8192), blk, 0, stream>>>(x, x_h, x_l);
  transcast_sp<<<dim3(32, 32), blk, 0, stream>>>(Wq, Wq_h, Wq_l, 1024, 1024);
  transcast_sp<<<dim3(32, 32), blk, 0, stream>>>(Wk, Wk_h, Wk_l, 1024, 1024);
  transcast_sp<<<dim3(64, 32), blk, 0, stream>>>(Wv, Wv_h, Wv_l, 1024, 2048);
  transcast_sp<<<dim3(32, 64), blk, 0, stream>>>(Wo, Wo_h, Wo_l, 2048, 1024);
  transcast_sp<<<dim3(32, 32), blk, 0, stream>>>(Wg, Wg_h, Wg_l, 1024, 1024);
  gab_kernel<<<dim3(8192), blk, 0, stream>>>(x, Wa, Wb, gbuf);
  // projections (split-bf16 MFMA, f32 out)
  gemm_sp<0><<<dim3(8, 64), blk, 0, stream>>>(x_h, x_l, Wq_h, Wq_l, q_pre, nullptr, nullptr, nullptr, 8192, 1024, 1024);
  gemm_sp<0><<<dim3(8, 64), blk, 0, stream>>>(x_h, x_l, Wk_h, Wk_l, k_pre, nullptr, nullptr, nullptr, 8192, 1024, 1024);
  gemm_sp<0><<<dim3(16, 64), blk, 0, stream>>>(x_h, x_l, Wv_h, Wv_l, v_pre, nullptr, nullptr, nullptr, 8192, 2048, 1024);
  // zrms in-place (f32)
  zrms_kernel<1024><<<dim3(8192), blk, 0, stream>>>(q_pre, gq, q_pre);
  zrms_kernel<1024><<<dim3(8192), blk, 0, stream>>>(k_pre, gk, k_pre);
  zrms_kernel<2048><<<dim3(8192), blk, 0, stream>>>(v_pre, gv, v_pre);
  // conv+silu -> split pairs; v additionally pre-scaled by g
  conv_sp<1024, 0><<<dim3(8192), blk, 0, stream>>>(q_pre, cq, nullptr, q_h, q_l);
  conv_sp<1024, 0><<<dim3(8192), blk, 0, stream>>>(k_pre, ck, nullptr, k_h, k_l);
  conv_sp<2048, 1><<<dim3(16384), blk, 0, stream>>>(v_pre, cv, gbuf, vg_h, vg_l);
  // chunked recurrence: sequential scan (exclusive prefix) + parallel pass2
  scan_kernel<<<dim3(256), blk, 0, stream>>>(k_h, k_l, vg_h, vg_l, Sp_h, Sp_l);
  pass2_sp<<<dim3(2048), blk, 0, stream>>>(q_h, q_l, k_h, vg_h, Sp_h, Sp_l, o_h, o_l);
  // output projection (f32 + split pair out) and gated final GEMM
  gemm_sp<1><<<dim3(8, 64), blk, 0, stream>>>(o_h, o_l, Wo_h, Wo_l, proj, p_h, p_l, nullptr, 8192, 1024, 2048);
  gemm_sp<2><<<dim3(8, 64), blk, 0, stream>>>(p_h, p_l, Wg_h, Wg_l, out, nullptr, nullptr, proj, 8192, 1024, 1024);
}

// Round 8
// 745.425 us; speedup vs baseline: 3.4192x; 1.0243x over previous
//
#include <hip/hip_runtime.h>
#include <hip/hip_bf16.h>
#include <math.h>

#define RTOT 8192      // B*T
#define TSEQ 2048

typedef __attribute__((ext_vector_type(8))) short short8;
typedef __attribute__((ext_vector_type(4))) float f32x4;
typedef unsigned short u16;
typedef unsigned int u32;

union U16x8 { uint4 v; u16 s[8]; };

__device__ __forceinline__ float sigmoidf_(float x) { return 1.f / (1.f + expf(-x)); }
__device__ __forceinline__ float bf2f(u16 v) { u32 u = ((u32)v) << 16; float f; __builtin_memcpy(&f, &u, 4); return f; }
__device__ __forceinline__ u16 f2bf(float f) {
  u32 u; __builtin_memcpy(&u, &f, 4);
  u32 r = (u + 0x7FFFu + ((u >> 16) & 1u)) >> 16;
  return (u16)r;
}
// split f32 -> hi bf16 + lo bf16 (residual)
__device__ __forceinline__ void split2(float x, u16& h, u16& l) {
  u16 hh = f2bf(x);
  float hf = bf2f(hh);
  h = hh; l = f2bf(x - hf);
}

typedef const void __attribute__((address_space(1))) gvoid_t;
typedef void __attribute__((address_space(3))) lvoid_t;
__device__ __forceinline__ void gload_lds16(const void* g, void* l) {
  __builtin_amdgcn_global_load_lds((gvoid_t*)g, (lvoid_t*)l, 16, 0, 0);
}

// XCD-chunked bijective block remap (nwg % 8 == 0 required)
__device__ __forceinline__ void xcd_remap(int& bx, int& by) {
  int gx = gridDim.x, nwg = gx * gridDim.y;
  int bid = blockIdx.y * gx + blockIdx.x;
  int cpx = nwg >> 3;
  int swz = (bid & 7) * cpx + (bid >> 3);
  bx = swz % gx; by = swz / gx;
}

// ======= split-bf16 MFMA GEMM at ~f32 precision =============================
// EPI 0: f32 out.  EPI 1: f32 out + split pair out.  EPI 2: f32 out = Pin * sigmoid(acc)
template<int EPI>
__global__ __launch_bounds__(256) void gemm_sp(const u16* __restrict__ Ah, const u16* __restrict__ Al,
                                               const u16* __restrict__ Bh, const u16* __restrict__ Bl,
                                               float* __restrict__ Cf, u16* __restrict__ Ph,
                                               u16* __restrict__ Pl, const float* __restrict__ Pin,
                                               int M, int N, int K) {
  __shared__ u16 Ash[128 * 32], Asl[128 * 32];
  __shared__ u16 Bsh[128 * 32], Bsl[128 * 32];
  int bx, by; xcd_remap(bx, by);
  const int tid = threadIdx.x;
  const int l = tid & 63, w = tid >> 6;
  const int m0 = by * 128, n0 = bx * 128;
  const int wr = w >> 1, wc = w & 1;
  f32x4 acc[4][4] = {};
  const int srow = (w << 5) + (l >> 2);
  const int scol = (l & 3) << 3;
  const size_t gA = (size_t)(m0 + srow) * K + scol;
  const size_t gB = (size_t)(n0 + srow) * K + scol;
  const int lo0 = (w * 2 + 0) * 512, lo1 = (w * 2 + 1) * 512;
  const int arow = wr * 64 + (l & 15), brow = wc * 64 + (l & 15);
  const int koff = 8 * (l >> 4);
  for (int k0 = 0; k0 < K; k0 += 32) {
    gload_lds16(Ah + gA + k0, &Ash[lo0]);
    gload_lds16(Ah + gA + 16 * K + k0, &Ash[lo1]);
    gload_lds16(Al + gA + k0, &Asl[lo0]);
    gload_lds16(Al + gA + 16 * K + k0, &Asl[lo1]);
    gload_lds16(Bh + gB + k0, &Bsh[lo0]);
    gload_lds16(Bh + gB + 16 * K + k0, &Bsh[lo1]);
    gload_lds16(Bl + gB + k0, &Bsl[lo0]);
    gload_lds16(Bl + gB + 16 * K + k0, &Bsl[lo1]);
    __syncthreads();
    short8 afh[4], afl[4], bfh[4], bfl[4];
#pragma unroll
    for (int m = 0; m < 4; ++m) {
      afh[m] = *(const short8*)&Ash[(arow + m * 16) * 32 + koff];
      afl[m] = *(const short8*)&Asl[(arow + m * 16) * 32 + koff];
    }
#pragma unroll
    for (int n = 0; n < 4; ++n) {
      bfh[n] = *(const short8*)&Bsh[(brow + n * 16) * 32 + koff];
      bfl[n] = *(const short8*)&Bsl[(brow + n * 16) * 32 + koff];
    }
#pragma unroll
    for (int m = 0; m < 4; ++m)
#pragma unroll
      for (int n = 0; n < 4; ++n) {
        acc[m][n] = __builtin_amdgcn_mfma_f32_16x16x32_bf16(afh[m], bfh[n], acc[m][n], 0, 0, 0);
        acc[m][n] = __builtin_amdgcn_mfma_f32_16x16x32_bf16(afh[m], bfl[n], acc[m][n], 0, 0, 0);
        acc[m][n] = __builtin_amdgcn_mfma_f32_16x16x32_bf16(afl[m], bfh[n], acc[m][n], 0, 0, 0);
      }
    __syncthreads();
  }
  const int rbase = m0 + wr * 64 + 4 * (l >> 4);
  const int cbase = n0 + wc * 64 + (l & 15);
#pragma unroll
  for (int m = 0; m < 4; ++m)
#pragma unroll
    for (int n = 0; n < 4; ++n)
#pragma unroll
      for (int r = 0; r < 4; ++r) {
        size_t idx = (size_t)(rbase + m * 16 + r) * N + (cbase + n * 16);
        float v = acc[m][n][r];
        if (EPI == 0) {
          Cf[idx] = v;
        } else if (EPI == 1) {
          Cf[idx] = v;
          u16 h, lo; split2(v, h, lo);
          Ph[idx] = h; Pl[idx] = lo;
        } else {
          Cf[idx] = Pin[idx] * sigmoidf_(v);
        }
      }
}

// ======= weight cast+transpose+split: W[K][N] f32 -> Wt_h/Wt_l [N][K] =======
__global__ __launch_bounds__(256) void transcast_sp(const float* __restrict__ W,
                                                    u16* __restrict__ Wth, u16* __restrict__ Wtl,
                                                    int K, int N) {
  __shared__ float t[32][33];
  const int n0 = blockIdx.x * 32, k0 = blockIdx.y * 32;
  const int c = threadIdx.x & 31, rq = threadIdx.x >> 5;
#pragma unroll
  for (int i = 0; i < 4; ++i) t[rq * 4 + i][c] = W[(size_t)(k0 + rq * 4 + i) * N + n0 + c];
  __syncthreads();
#pragma unroll
  for (int i = 0; i < 4; ++i) {
    float v = t[c][rq * 4 + i];
    u16 h, lo; split2(v, h, lo);
    size_t idx = (size_t)(n0 + rq * 4 + i) * K + k0 + c;
    Wth[idx] = h; Wtl[idx] = lo;
  }
}

// ======= x cast+split f32 -> bf16 hi/lo =====================================
__global__ __launch_bounds__(256) void castx_sp(const float* __restrict__ x,
                                                u16* __restrict__ xh, u16* __restrict__ xl) {
  size_t i = (size_t)blockIdx.x * 256 + threadIdx.x;
  float4 v = ((const float4*)x)[i];
  ushort4 hh, ll;
  split2(v.x, hh.x, ll.x); split2(v.y, hh.y, ll.y);
  split2(v.z, hh.z, ll.z); split2(v.w, hh.w, ll.w);
  ((ushort4*)xh)[i] = hh; ((ushort4*)xl)[i] = ll;
}

// ======= per-row zrms stats: mean + rstd of section (row stride 2048) =======
template<int C>
__global__ __launch_bounds__(256) void stats_kernel(const float* __restrict__ base,
                                                    float* __restrict__ st) {
  constexpr int NQ = C / 1024;
  __shared__ float red[4];
  const int tid = threadIdx.x;
  const size_t row = blockIdx.x;
  const float* x = base + row * 2048;
  float4 v[NQ];
  float s = 0.f;
#pragma unroll
  for (int i = 0; i < NQ; ++i) {
    v[i] = *(const float4*)(x + tid*4 + i*1024);
    s += v[i].x + v[i].y + v[i].z + v[i].w;
  }
#pragma unroll
  for (int o = 32; o > 0; o >>= 1) s += __shfl_xor(s, o, 64);
  if ((tid & 63) == 0) red[tid >> 6] = s;
  __syncthreads();
  const float mean = (red[0]+red[1]+red[2]+red[3]) * (1.f / C);
  __syncthreads();
  float ss = 0.f;
#pragma unroll
  for (int i = 0; i < NQ; ++i) {
    float a = v[i].x - mean, b = v[i].y - mean, c = v[i].z - mean, d = v[i].w - mean;
    ss += a*a + b*b + c*c + d*d;
  }
#pragma unroll
  for (int o = 32; o > 0; o >>= 1) ss += __shfl_xor(ss, o, 64);
  if ((tid & 63) == 0) red[tid >> 6] = ss;
  __syncthreads();
  if (tid == 0) {
    st[row * 2] = mean;
    st[row * 2 + 1] = rsqrtf((red[0]+red[1]+red[2]+red[3]) * (1.f / C) + 1e-5f);
  }
}

// ======= conv(K=4)+SiLU with inline zrms (stats) -> split pair; opt g-scale =
template<int C, int GSCALE>
__global__ __launch_bounds__(256) void conv_ns(const float* __restrict__ zn,
                                               const float* __restrict__ st,
                                               const float* __restrict__ w,
                                               const float* __restrict__ g,
                                               const float* __restrict__ gab,
                                               u16* __restrict__ oh,
                                               u16* __restrict__ ol) {
  const size_t idx = (size_t)blockIdx.x * 256 + threadIdx.x;  // RTOT*C/4
  const int c = (int)(idx % (C/4)) * 4;
  const int row = (int)(idx / (C/4));
  const int t = row % TSEQ;
  float4 g4 = *(const float4*)(g + c);
  float4 acc = {0.f, 0.f, 0.f, 0.f};
#pragma unroll
  for (int d = 0; d < 4; ++d) {
    if (t - d >= 0) {
      const int r2 = row - d;
      const float mean = st[r2 * 2], rstd = st[r2 * 2 + 1];
      float4 xv = *(const float4*)(zn + (size_t)r2 * 2048 + c);
      float4 wv = *(const float4*)(w + (size_t)(3 - d) * C + c);
      acc.x = fmaf((xv.x - mean) * rstd * g4.x, wv.x, acc.x);
      acc.y = fmaf((xv.y - mean) * rstd * g4.y, wv.y, acc.y);
      acc.z = fmaf((xv.z - mean) * rstd * g4.z, wv.z, acc.z);
      acc.w = fmaf((xv.w - mean) * rstd * g4.w, wv.w, acc.w);
    }
  }
  float a0 = acc.x * sigmoidf_(acc.x);
  float a1 = acc.y * sigmoidf_(acc.y);
  float a2 = acc.z * sigmoidf_(acc.z);
  float a3 = acc.w * sigmoidf_(acc.w);
  if (GSCALE) {
    float gv = gab[(size_t)row * 16 + (c >> 7)];
    a0 *= gv; a1 *= gv; a2 *= gv; a3 *= gv;
  }
  ushort4 hh, ll;
  split2(a0, hh.x, ll.x); split2(a1, hh.y, ll.y);
  split2(a2, hh.z, ll.z); split2(a3, hh.w, ll.w);
  *(ushort4*)(oh + (size_t)row * C + c) = hh;
  *(ushort4*)(ol + (size_t)row * C + c) = ll;
}

// ======= g = sigmoid(x@Wa)*sigmoid(x@Wb) per (row,head) (proven) ============
__global__ __launch_bounds__(256) void gab_kernel(const float* __restrict__ x,
                                                  const float* __restrict__ Wa,
                                                  const float* __restrict__ Wb,
                                                  float* __restrict__ gout) {
  __shared__ float xs[1024];
  __shared__ float partial[256];
  const int tid = threadIdx.x;
  const size_t row = blockIdx.x;
  *(float4*)(&xs[tid*4]) = *(const float4*)(x + row*1024 + tid*4);
  __syncthreads();
  const int h = tid & 31;
  const int seg = tid >> 5;
  const float* W = (h < 16) ? Wa : Wb;
  const int col = h & 15;
  float s = 0.f;
  const int k0 = seg * 128;
  for (int k = 0; k < 128; ++k) s = fmaf(xs[k0 + k], W[(size_t)(k0 + k) * 16 + col], s);
  partial[tid] = s;
  __syncthreads();
  if (tid < 32) {
    float t2 = 0.f;
#pragma unroll
    for (int j = 0; j < 8; ++j) t2 += partial[j*32 + tid];
    partial[tid] = t2;
  }
  __syncthreads();
  if (tid < 16)
    gout[row*16 + tid] = sigmoidf_(partial[tid]) * sigmoidf_(partial[tid + 16]);
}

// ======= scan: exclusive chunk-prefix of Vg^T K, kd-split (512 blocks) ======
__global__ __launch_bounds__(256) void scan_kernel(const u16* __restrict__ kh,
                                                   const u16* __restrict__ kl,
                                                   const u16* __restrict__ vgh,
                                                   const u16* __restrict__ vgl,
                                                   u16* __restrict__ Sph,
                                                   u16* __restrict__ Spl) {
  __shared__ float Ks[64][36];
  __shared__ float Vs[64][36];
  const int tid = threadIdx.x;
  const int bid = blockIdx.x;
  const int kq = bid & 1, vq = (bid >> 1) & 3, h = (bid >> 3) & 15, b = bid >> 7;
  const size_t rb = (size_t)b * TSEQ;
  const int vd_t = tid >> 3, kd0 = (tid & 7) * 4;
  float S[4] = {};
  const int sr = tid >> 2;            // staging row 0..63
  const int cc0 = (tid & 3) * 8;      // 8-col slice
  for (int c = 0; c < 32; ++c) {
    {
      size_t koffg = (rb + (size_t)c * 64 + sr) * 1024 + h * 64 + kq * 32 + cc0;
      U16x8 a0, b0;
      a0.v = *(const uint4*)(kh + koffg);
      b0.v = *(const uint4*)(kl + koffg);
#pragma unroll
      for (int j = 0; j < 8; ++j) Ks[sr][cc0 + j] = bf2f(a0.s[j]) + bf2f(b0.s[j]);
      size_t voffg = (rb + (size_t)c * 64 + sr) * 2048 + h * 128 + vq * 32 + cc0;
      U16x8 va, vb;
      va.v = *(const uint4*)(vgh + voffg);
      vb.v = *(const uint4*)(vgl + voffg);
#pragma unroll
      for (int j = 0; j < 8; ++j) Vs[sr][cc0 + j] = bf2f(va.s[j]) + bf2f(vb.s[j]);
    }
    {
      size_t spc = (((size_t)(b * 16 + h) * 32) + c) * 8192
                 + (size_t)(vq * 32 + vd_t) * 64 + kq * 32 + kd0;
      ushort4 h0, l0;
      split2(S[0], h0.x, l0.x); split2(S[1], h0.y, l0.y);
      split2(S[2], h0.z, l0.z); split2(S[3], h0.w, l0.w);
      *(ushort4*)(Sph + spc) = h0;
      *(ushort4*)(Spl + spc) = l0;
    }
    __syncthreads();
    for (int s = 0; s < 64; ++s) {
      float vv = Vs[s][vd_t];
      float kv[4];
      *(float4*)kv = *(const float4*)&Ks[s][kd0];
#pragma unroll
      for (int j = 0; j < 4; ++j) S[j] = fmaf(vv, kv[j], S[j]);
    }
    __syncthreads();
  }
}

// ======= pass2: O = mask(QK^T) Vg + Q Sp^T  (MFMA, split; proven r6) ========
__global__ __launch_bounds__(256) void pass2_sp(const u16* __restrict__ qh,
                                                const u16* __restrict__ ql,
                                                const u16* __restrict__ kh,
                                                const u16* __restrict__ vgh,
                                                const u16* __restrict__ Sph,
                                                const u16* __restrict__ Spl,
                                                u16* __restrict__ oh,
                                                u16* __restrict__ ol) {
  __shared__ u16 Qsh[64 * 72];
  __shared__ u16 Qsl[64 * 72];
  __shared__ u16 Ksm[64 * 72];
  __shared__ u16 Am[64 * 72];
  __shared__ u16 Vth[128 * 72];
  const int tid = threadIdx.x;
  const int l = tid & 63, w = tid >> 6;
  const int bid = blockIdx.x;
  const int c = bid & 31, h = (bid >> 5) & 15, b = bid >> 9;
  const size_t rb = (size_t)b * TSEQ + c * 64;
  const int fr = l & 15, fq = l >> 4;
  {
    int r = tid >> 2, c0 = (tid & 3) * 16;
    size_t off = (rb + r) * 1024 + h * 64 + c0;
    *(uint4*)&Qsh[r * 72 + c0]     = *(const uint4*)(qh + off);
    *(uint4*)&Qsh[r * 72 + c0 + 8] = *(const uint4*)(qh + off + 8);
    *(uint4*)&Qsl[r * 72 + c0]     = *(const uint4*)(ql + off);
    *(uint4*)&Qsl[r * 72 + c0 + 8] = *(const uint4*)(ql + off + 8);
    *(uint4*)&Ksm[r * 72 + c0]     = *(const uint4*)(kh + off);
    *(uint4*)&Ksm[r * 72 + c0 + 8] = *(const uint4*)(kh + off + 8);
  }
  {
    int s = tid >> 2, vd0 = (tid & 3) * 32;
    size_t off = (rb + s) * 2048 + h * 128 + vd0;
#pragma unroll
    for (int m4 = 0; m4 < 4; ++m4) {
      U16x8 r_; r_.v = *(const uint4*)(vgh + off + m4 * 8);
#pragma unroll
      for (int j = 0; j < 8; ++j) Vth[(vd0 + m4 * 8 + j) * 72 + s] = r_.s[j];
    }
  }
  __syncthreads();
  short8 aqh[2], aql[2];
#pragma unroll
  for (int kk = 0; kk < 2; ++kk) {
    aqh[kk] = *(const short8*)&Qsh[(w * 16 + fr) * 72 + kk * 32 + 8 * fq];
    aql[kk] = *(const short8*)&Qsl[(w * 16 + fr) * 72 + kk * 32 + 8 * fq];
  }
  f32x4 accA[4] = {};
#pragma unroll
  for (int n = 0; n < 4; ++n)
#pragma unroll
    for (int kk = 0; kk < 2; ++kk) {
      short8 bk = *(const short8*)&Ksm[(n * 16 + fr) * 72 + kk * 32 + 8 * fq];
      accA[n] = __builtin_amdgcn_mfma_f32_16x16x32_bf16(aqh[kk], bk, accA[n], 0, 0, 0);
    }
#pragma unroll
  for (int n = 0; n < 4; ++n)
#pragma unroll
    for (int rr = 0; rr < 4; ++rr) {
      int tt = w * 16 + 4 * fq + rr;
      int s = n * 16 + fr;
      Am[tt * 72 + s] = f2bf((s <= tt) ? accA[n][rr] : 0.f);
    }
  __syncthreads();
  f32x4 acc[8] = {};
#pragma unroll
  for (int kk = 0; kk < 2; ++kk) {
    short8 aa = *(const short8*)&Am[(w * 16 + fr) * 72 + kk * 32 + 8 * fq];
#pragma unroll
    for (int n = 0; n < 8; ++n) {
      short8 bv = *(const short8*)&Vth[(n * 16 + fr) * 72 + kk * 32 + 8 * fq];
      acc[n] = __builtin_amdgcn_mfma_f32_16x16x32_bf16(aa, bv, acc[n], 0, 0, 0);
    }
  }
  const size_t spb = (((size_t)(b * 16 + h) * 32) + c) * 8192;
#pragma unroll
  for (int n = 0; n < 8; ++n)
#pragma unroll
    for (int kk = 0; kk < 2; ++kk) {
      size_t soff = spb + (size_t)(n * 16 + fr) * 64 + kk * 32 + 8 * fq;
      short8 bh_ = *(const short8*)(Sph + soff);
      short8 bl_ = *(const short8*)(Spl + soff);
      acc[n] = __builtin_amdgcn_mfma_f32_16x16x32_bf16(aqh[kk], bh_, acc[n], 0, 0, 0);
      acc[n] = __builtin_amdgcn_mfma_f32_16x16x32_bf16(aqh[kk], bl_, acc[n], 0, 0, 0);
      acc[n] = __builtin_amdgcn_mfma_f32_16x16x32_bf16(aql[kk], bh_, acc[n], 0, 0, 0);
    }
#pragma unroll
  for (int n = 0; n < 8; ++n)
#pragma unroll
    for (int rr = 0; rr < 4; ++rr) {
      int tt = w * 16 + 4 * fq + rr;
      int vd = n * 16 + fr;
      u16 hh, ll;
      split2(acc[n][rr], hh, ll);
      size_t off = (rb + tt) * 2048 + h * 128 + vd;
      oh[off] = hh; ol[off] = ll;
    }
}

// ===========================================================================
extern "C" void kernel_launch(void* const* d_in, const int* in_sizes, int n_in,
                              void* d_out, int out_size, void* d_ws, size_t ws_size,
                              hipStream_t stream) {
  (void)in_sizes; (void)n_in; (void)out_size; (void)ws_size;
  const float* x  = (const float*)d_in[0];
  const float* Wq = (const float*)d_in[1];
  const float* Wk = (const float*)d_in[2];
  const float* Wv = (const float*)d_in[3];
  const float* gq = (const float*)d_in[4];
  const float* gk = (const float*)d_in[5];
  const float* gv = (const float*)d_in[6];
  const float* cq = (const float*)d_in[7];
  const float* ck = (const float*)d_in[8];
  const float* cv = (const float*)d_in[9];
  const float* Wa = (const float*)d_in[10];
  const float* Wb = (const float*)d_in[11];
  const float* Wo = (const float*)d_in[12];
  const float* Wg = (const float*)d_in[13];
  float* out = (float*)d_out;
  char* ws = (char*)d_ws;

  const size_t MiB = 1024 * 1024;
  // ---- workspace plan (peak exactly 256 MiB, liveness-audited) ----
  u16* Wqk_h = (u16*)(ws + 0 * MiB);       // 4  ([2048][1024])
  u16* Wqk_l = (u16*)(ws + 4 * MiB);       // 4
  u16* Wv_h  = (u16*)(ws + 8 * MiB);       // 4
  u16* Wv_l  = (u16*)(ws + 12 * MiB);      // 4
  u16* Wo_h  = (u16*)(ws + 16 * MiB);      // 4
  u16* Wo_l  = (u16*)(ws + 20 * MiB);      // 4
  u16* Wg_h  = (u16*)(ws + 24 * MiB);      // 2
  u16* Wg_l  = (u16*)(ws + 26 * MiB);      // 2
  float* gbuf = (float*)(ws + 28 * MiB);   // 0.5
  float* st_q = (float*)(ws + 28 * MiB + 524288);            // 64 KB
  float* st_k = (float*)(ws + 28 * MiB + 524288 + 65536);    // 64 KB
  float* st_v = (float*)(ws + 28 * MiB + 524288 + 131072);   // 64 KB
  u16* x_h   = (u16*)(ws + 32 * MiB);      // 16        [dead after proj gemms]
  u16* x_l   = (u16*)(ws + 48 * MiB);      // 16
  float* qk  = (float*)(ws + 64 * MiB);    // 64        [dead after conv q,k]
  float* vbuf = (float*)(ws + 128 * MiB);  // 64        [dead after conv v]
  u16* q_h = (u16*)(ws + 192 * MiB);       // 16
  u16* q_l = (u16*)(ws + 208 * MiB);       // 16
  u16* k_h = (u16*)(ws + 224 * MiB);       // 16
  u16* k_l = (u16*)(ws + 240 * MiB);       // 16 (ends at 256)
  u16* vg_h = (u16*)(ws + 64 * MiB);       // 32 (qk dead)
  u16* vg_l = (u16*)(ws + 96 * MiB);       // 32
  u16* Sp_h = (u16*)(ws + 128 * MiB);      // 32 (vbuf dead)
  u16* Sp_l = (u16*)(ws + 160 * MiB);      // 32
  u16* o_h  = (u16*)(ws + 32 * MiB);       // 32 (x pair dead)
  u16* o_l  = (u16*)d_out;                 // 32 (d_out scratch)
  float* proj = (float*)(ws + 64 * MiB);   // 32 (vg_h dead after pass2)
  u16* p_h  = (u16*)(ws + 96 * MiB);       // 16 (vg_l dead)
  u16* p_l  = (u16*)(ws + 112 * MiB);      // 16

  dim3 blk(256);
  // casts + splits
  castx_sp<<<dim3(8192), blk, 0, stream>>>(x, x_h, x_l);
  transcast_sp<<<dim3(32, 32), blk, 0, stream>>>(Wq, Wqk_h, Wqk_l, 1024, 1024);
  transcast_sp<<<dim3(32, 32), blk, 0, stream>>>(Wk, Wqk_h + 1024 * 1024, Wqk_l + 1024 * 1024, 1024, 1024);
  transcast_sp<<<dim3(64, 32), blk, 0, stream>>>(Wv, Wv_h, Wv_l, 1024, 2048);
  transcast_sp<<<dim3(32, 64), blk, 0, stream>>>(Wo, Wo_h, Wo_l, 2048, 1024);
  transcast_sp<<<dim3(32, 32), blk, 0, stream>>>(Wg, Wg_h, Wg_l, 1024, 1024);
  gab_kernel<<<dim3(8192), blk, 0, stream>>>(x, Wa, Wb, gbuf);
  // projections: split-bf16 (f32-class; r7's plain-bf16 failed at absmax 181)
  gemm_sp<0><<<dim3(16, 64), blk, 0, stream>>>(x_h, x_l, Wqk_h, Wqk_l, qk, nullptr, nullptr, nullptr, 8192, 2048, 1024);
  gemm_sp<0><<<dim3(16, 64), blk, 0, stream>>>(x_h, x_l, Wv_h, Wv_l, vbuf, nullptr, nullptr, nullptr, 8192, 2048, 1024);
  // zrms stats (mean, rstd per row-section)
  stats_kernel<1024><<<dim3(8192), blk, 0, stream>>>(qk, st_q);
  stats_kernel<1024><<<dim3(8192), blk, 0, stream>>>(qk + 1024, st_k);
  stats_kernel<2048><<<dim3(8192), blk, 0, stream>>>(vbuf, st_v);
  // conv+silu with inline norm -> split pairs; v pre-scaled by g
  conv_ns<1024, 0><<<dim3(8192), blk, 0, stream>>>(qk, st_q, cq, gq, nullptr, q_h, q_l);
  conv_ns<1024, 0><<<dim3(8192), blk, 0, stream>>>(qk + 1024, st_k, ck, gk, nullptr, k_h, k_l);
  conv_ns<2048, 1><<<dim3(16384), blk, 0, stream>>>(vbuf, st_v, cv, gv, gbuf, vg_h, vg_l);
  // chunked recurrence
  scan_kernel<<<dim3(512), blk, 0, stream>>>(k_h, k_l, vg_h, vg_l, Sp_h, Sp_l);
  pass2_sp<<<dim3(2048), blk, 0, stream>>>(q_h, q_l, k_h, vg_h, Sp_h, Sp_l, o_h, o_l);
  // output projection + gated final GEMM (split precision)
  gemm_sp<1><<<dim3(8, 64), blk, 0, stream>>>(o_h, o_l, Wo_h, Wo_l, proj, p_h, p_l, nullptr, 8192, 1024, 2048);
  gemm_sp<2><<<dim3(8, 64), blk, 0, stream>>>(p_h, p_l, Wg_h, Wg_l, out, nullptr, nullptr, proj, 8192, 1024, 1024);
}

// Round 9
// 718.047 us; speedup vs baseline: 3.5496x; 1.0381x over previous
//
#include <hip/hip_runtime.h>
#include <hip/hip_bf16.h>
#include <math.h>

#define RTOT 8192      // B*T
#define TSEQ 2048

typedef __attribute__((ext_vector_type(8))) short short8;
typedef __attribute__((ext_vector_type(4))) float f32x4;
typedef unsigned short u16;
typedef unsigned int u32;

union U16x8 { uint4 v; u16 s[8]; };

__device__ __forceinline__ float sigmoidf_(float x) { return 1.f / (1.f + expf(-x)); }
__device__ __forceinline__ float bf2f(u16 v) { u32 u = ((u32)v) << 16; float f; __builtin_memcpy(&f, &u, 4); return f; }
__device__ __forceinline__ u16 f2bf(float f) {
  u32 u; __builtin_memcpy(&u, &f, 4);
  u32 r = (u + 0x7FFFu + ((u >> 16) & 1u)) >> 16;
  return (u16)r;
}
// split f32 -> hi bf16 + lo bf16 (residual)
__device__ __forceinline__ void split2(float x, u16& h, u16& l) {
  u16 hh = f2bf(x);
  float hf = bf2f(hh);
  h = hh; l = f2bf(x - hf);
}

typedef const void __attribute__((address_space(1))) gvoid_t;
typedef void __attribute__((address_space(3))) lvoid_t;
__device__ __forceinline__ void gload_lds16(const void* g, void* l) {
  __builtin_amdgcn_global_load_lds((gvoid_t*)g, (lvoid_t*)l, 16, 0, 0);
}

// XCD-chunked bijective block remap (nwg % 8 == 0 required)
__device__ __forceinline__ void xcd_remap(int& bx, int& by) {
  int gx = gridDim.x, nwg = gx * gridDim.y;
  int bid = blockIdx.y * gx + blockIdx.x;
  int cpx = nwg >> 3;
  int swz = (bid & 7) * cpx + (bid >> 3);
  bx = swz % gx; by = swz / gx;
}

// ======= split-bf16 MFMA GEMM at ~f32 precision (proven) ====================
// EPI 0: f32 out.  EPI 1: f32 out + split pair out.  EPI 2: f32 out = Pin * sigmoid(acc)
template<int EPI>
__global__ __launch_bounds__(256) void gemm_sp(const u16* __restrict__ Ah, const u16* __restrict__ Al,
                                               const u16* __restrict__ Bh, const u16* __restrict__ Bl,
                                               float* __restrict__ Cf, u16* __restrict__ Ph,
                                               u16* __restrict__ Pl, const float* __restrict__ Pin,
                                               int M, int N, int K) {
  __shared__ u16 Ash[128 * 32], Asl[128 * 32];
  __shared__ u16 Bsh[128 * 32], Bsl[128 * 32];
  int bx, by; xcd_remap(bx, by);
  const int tid = threadIdx.x;
  const int l = tid & 63, w = tid >> 6;
  const int m0 = by * 128, n0 = bx * 128;
  const int wr = w >> 1, wc = w & 1;
  f32x4 acc[4][4] = {};
  const int srow = (w << 5) + (l >> 2);
  const int scol = (l & 3) << 3;
  const size_t gA = (size_t)(m0 + srow) * K + scol;
  const size_t gB = (size_t)(n0 + srow) * K + scol;
  const int lo0 = (w * 2 + 0) * 512, lo1 = (w * 2 + 1) * 512;
  const int arow = wr * 64 + (l & 15), brow = wc * 64 + (l & 15);
  const int koff = 8 * (l >> 4);
  for (int k0 = 0; k0 < K; k0 += 32) {
    gload_lds16(Ah + gA + k0, &Ash[lo0]);
    gload_lds16(Ah + gA + 16 * K + k0, &Ash[lo1]);
    gload_lds16(Al + gA + k0, &Asl[lo0]);
    gload_lds16(Al + gA + 16 * K + k0, &Asl[lo1]);
    gload_lds16(Bh + gB + k0, &Bsh[lo0]);
    gload_lds16(Bh + gB + 16 * K + k0, &Bsh[lo1]);
    gload_lds16(Bl + gB + k0, &Bsl[lo0]);
    gload_lds16(Bl + gB + 16 * K + k0, &Bsl[lo1]);
    __syncthreads();
    short8 afh[4], afl[4], bfh[4], bfl[4];
#pragma unroll
    for (int m = 0; m < 4; ++m) {
      afh[m] = *(const short8*)&Ash[(arow + m * 16) * 32 + koff];
      afl[m] = *(const short8*)&Asl[(arow + m * 16) * 32 + koff];
    }
#pragma unroll
    for (int n = 0; n < 4; ++n) {
      bfh[n] = *(const short8*)&Bsh[(brow + n * 16) * 32 + koff];
      bfl[n] = *(const short8*)&Bsl[(brow + n * 16) * 32 + koff];
    }
#pragma unroll
    for (int m = 0; m < 4; ++m)
#pragma unroll
      for (int n = 0; n < 4; ++n) {
        acc[m][n] = __builtin_amdgcn_mfma_f32_16x16x32_bf16(afh[m], bfh[n], acc[m][n], 0, 0, 0);
        acc[m][n] = __builtin_amdgcn_mfma_f32_16x16x32_bf16(afh[m], bfl[n], acc[m][n], 0, 0, 0);
        acc[m][n] = __builtin_amdgcn_mfma_f32_16x16x32_bf16(afl[m], bfh[n], acc[m][n], 0, 0, 0);
      }
    __syncthreads();
  }
  const int rbase = m0 + wr * 64 + 4 * (l >> 4);
  const int cbase = n0 + wc * 64 + (l & 15);
#pragma unroll
  for (int m = 0; m < 4; ++m)
#pragma unroll
    for (int n = 0; n < 4; ++n)
#pragma unroll
      for (int r = 0; r < 4; ++r) {
        size_t idx = (size_t)(rbase + m * 16 + r) * N + (cbase + n * 16);
        float v = acc[m][n][r];
        if (EPI == 0) {
          Cf[idx] = v;
        } else if (EPI == 1) {
          Cf[idx] = v;
          u16 h, lo; split2(v, h, lo);
          Ph[idx] = h; Pl[idx] = lo;
        } else {
          Cf[idx] = Pin[idx] * sigmoidf_(v);
        }
      }
}

// ======= weight cast+transpose+split: W[K][N] f32 -> Wt_h/Wt_l [N][K] =======
__global__ __launch_bounds__(256) void transcast_sp(const float* __restrict__ W,
                                                    u16* __restrict__ Wth, u16* __restrict__ Wtl,
                                                    int K, int N) {
  __shared__ float t[32][33];
  const int n0 = blockIdx.x * 32, k0 = blockIdx.y * 32;
  const int c = threadIdx.x & 31, rq = threadIdx.x >> 5;
#pragma unroll
  for (int i = 0; i < 4; ++i) t[rq * 4 + i][c] = W[(size_t)(k0 + rq * 4 + i) * N + n0 + c];
  __syncthreads();
#pragma unroll
  for (int i = 0; i < 4; ++i) {
    float v = t[c][rq * 4 + i];
    u16 h, lo; split2(v, h, lo);
    size_t idx = (size_t)(n0 + rq * 4 + i) * K + k0 + c;
    Wth[idx] = h; Wtl[idx] = lo;
  }
}

// ======= x cast+split f32 -> bf16 hi/lo =====================================
__global__ __launch_bounds__(256) void castx_sp(const float* __restrict__ x,
                                                u16* __restrict__ xh, u16* __restrict__ xl) {
  size_t i = (size_t)blockIdx.x * 256 + threadIdx.x;
  float4 v = ((const float4*)x)[i];
  ushort4 hh, ll;
  split2(v.x, hh.x, ll.x); split2(v.y, hh.y, ll.y);
  split2(v.z, hh.z, ll.z); split2(v.w, hh.w, ll.w);
  ((ushort4*)xh)[i] = hh; ((ushort4*)xl)[i] = ll;
}

// ======= fused zrms(stats inline) + conv(K=4) + SiLU -> split pair ==========
// One block per row; section base zn (row stride 4096); out row stride C.
// GSCALE: multiply by gab[row][head] (v path).
template<int C, int GSCALE>
__global__ __launch_bounds__(C / 4) void conv_fs(const float* __restrict__ zn,
                                                 const float* __restrict__ w,
                                                 const float* __restrict__ g,
                                                 const float* __restrict__ gab,
                                                 u16* __restrict__ oh,
                                                 u16* __restrict__ ol) {
  constexpr int NW = C / 256;   // waves per block (4 or 8)
  __shared__ float redA[NW * 4];
  __shared__ float redB[NW * 4];
  const int tid = threadIdx.x;
  const int row = blockIdx.x;
  const int t = row & (TSEQ - 1);
  const int c = tid * 4;
  const int lane = tid & 63, wid = tid >> 6;
  float4 xv[4];
  float psum[4];
#pragma unroll
  for (int d = 0; d < 4; ++d) {
    if (t - d >= 0) xv[d] = *(const float4*)(zn + (size_t)(row - d) * 4096 + c);
    else { xv[d].x = 0.f; xv[d].y = 0.f; xv[d].z = 0.f; xv[d].w = 0.f; }
    psum[d] = xv[d].x + xv[d].y + xv[d].z + xv[d].w;
  }
#pragma unroll
  for (int d = 0; d < 4; ++d)
#pragma unroll
    for (int o = 32; o > 0; o >>= 1) psum[d] += __shfl_xor(psum[d], o, 64);
  if (lane == 0) {
    redA[wid * 4 + 0] = psum[0]; redA[wid * 4 + 1] = psum[1];
    redA[wid * 4 + 2] = psum[2]; redA[wid * 4 + 3] = psum[3];
  }
  __syncthreads();
  float mean[4];
#pragma unroll
  for (int d = 0; d < 4; ++d) {
    float s = 0.f;
#pragma unroll
    for (int j = 0; j < NW; ++j) s += redA[j * 4 + d];
    mean[d] = s * (1.f / C);
  }
  float psq[4];
#pragma unroll
  for (int d = 0; d < 4; ++d) {
    float a = xv[d].x - mean[d], b = xv[d].y - mean[d];
    float e = xv[d].z - mean[d], f = xv[d].w - mean[d];
    psq[d] = a * a + b * b + e * e + f * f;
  }
#pragma unroll
  for (int d = 0; d < 4; ++d)
#pragma unroll
    for (int o = 32; o > 0; o >>= 1) psq[d] += __shfl_xor(psq[d], o, 64);
  if (lane == 0) {
    redB[wid * 4 + 0] = psq[0]; redB[wid * 4 + 1] = psq[1];
    redB[wid * 4 + 2] = psq[2]; redB[wid * 4 + 3] = psq[3];
  }
  __syncthreads();
  float rstd[4];
#pragma unroll
  for (int d = 0; d < 4; ++d) {
    float s = 0.f;
#pragma unroll
    for (int j = 0; j < NW; ++j) s += redB[j * 4 + d];
    rstd[d] = rsqrtf(s * (1.f / C) + 1e-5f);
  }
  float4 g4 = *(const float4*)(g + c);
  float4 acc; acc.x = 0.f; acc.y = 0.f; acc.z = 0.f; acc.w = 0.f;
#pragma unroll
  for (int d = 0; d < 4; ++d) {
    if (t - d >= 0) {
      float4 wv = *(const float4*)(w + (size_t)(3 - d) * C + c);
      acc.x = fmaf((xv[d].x - mean[d]) * rstd[d] * g4.x, wv.x, acc.x);
      acc.y = fmaf((xv[d].y - mean[d]) * rstd[d] * g4.y, wv.y, acc.y);
      acc.z = fmaf((xv[d].z - mean[d]) * rstd[d] * g4.z, wv.z, acc.z);
      acc.w = fmaf((xv[d].w - mean[d]) * rstd[d] * g4.w, wv.w, acc.w);
    }
  }
  float a0 = acc.x * sigmoidf_(acc.x);
  float a1 = acc.y * sigmoidf_(acc.y);
  float a2 = acc.z * sigmoidf_(acc.z);
  float a3 = acc.w * sigmoidf_(acc.w);
  if (GSCALE) {
    float gv = gab[(size_t)row * 16 + (c >> 7)];
    a0 *= gv; a1 *= gv; a2 *= gv; a3 *= gv;
  }
  ushort4 hh, ll;
  split2(a0, hh.x, ll.x); split2(a1, hh.y, ll.y);
  split2(a2, hh.z, ll.z); split2(a3, hh.w, ll.w);
  *(ushort4*)(oh + (size_t)row * C + c) = hh;
  *(ushort4*)(ol + (size_t)row * C + c) = ll;
}

// ======= g = sigmoid(x@Wa)*sigmoid(x@Wb) per (row,head) (proven) ============
__global__ __launch_bounds__(256) void gab_kernel(const float* __restrict__ x,
                                                  const float* __restrict__ Wa,
                                                  const float* __restrict__ Wb,
                                                  float* __restrict__ gout) {
  __shared__ float xs[1024];
  __shared__ float partial[256];
  const int tid = threadIdx.x;
  const size_t row = blockIdx.x;
  *(float4*)(&xs[tid*4]) = *(const float4*)(x + row*1024 + tid*4);
  __syncthreads();
  const int h = tid & 31;
  const int seg = tid >> 5;
  const float* W = (h < 16) ? Wa : Wb;
  const int col = h & 15;
  float s = 0.f;
  const int k0 = seg * 128;
  for (int k = 0; k < 128; ++k) s = fmaf(xs[k0 + k], W[(size_t)(k0 + k) * 16 + col], s);
  partial[tid] = s;
  __syncthreads();
  if (tid < 32) {
    float t2 = 0.f;
#pragma unroll
    for (int j = 0; j < 8; ++j) t2 += partial[j*32 + tid];
    partial[tid] = t2;
  }
  __syncthreads();
  if (tid < 16)
    gout[row*16 + tid] = sigmoidf_(partial[tid]) * sigmoidf_(partial[tid + 16]);
}

// ======= scan: exclusive chunk-prefix of Vg^T K, kd-split (512 blocks) ======
__global__ __launch_bounds__(256) void scan_kernel(const u16* __restrict__ kh,
                                                   const u16* __restrict__ kl,
                                                   const u16* __restrict__ vgh,
                                                   const u16* __restrict__ vgl,
                                                   u16* __restrict__ Sph,
                                                   u16* __restrict__ Spl) {
  __shared__ float Ks[64][36];
  __shared__ float Vs[64][36];
  const int tid = threadIdx.x;
  const int bid = blockIdx.x;
  const int kq = bid & 1, vq = (bid >> 1) & 3, h = (bid >> 3) & 15, b = bid >> 7;
  const size_t rb = (size_t)b * TSEQ;
  const int vd_t = tid >> 3, kd0 = (tid & 7) * 4;
  float S[4] = {};
  const int sr = tid >> 2;            // staging row 0..63
  const int cc0 = (tid & 3) * 8;      // 8-col slice
  for (int c = 0; c < 32; ++c) {
    {
      size_t koffg = (rb + (size_t)c * 64 + sr) * 1024 + h * 64 + kq * 32 + cc0;
      U16x8 a0, b0;
      a0.v = *(const uint4*)(kh + koffg);
      b0.v = *(const uint4*)(kl + koffg);
#pragma unroll
      for (int j = 0; j < 8; ++j) Ks[sr][cc0 + j] = bf2f(a0.s[j]) + bf2f(b0.s[j]);
      size_t voffg = (rb + (size_t)c * 64 + sr) * 2048 + h * 128 + vq * 32 + cc0;
      U16x8 va, vb;
      va.v = *(const uint4*)(vgh + voffg);
      vb.v = *(const uint4*)(vgl + voffg);
#pragma unroll
      for (int j = 0; j < 8; ++j) Vs[sr][cc0 + j] = bf2f(va.s[j]) + bf2f(vb.s[j]);
    }
    {
      size_t spc = (((size_t)(b * 16 + h) * 32) + c) * 8192
                 + (size_t)(vq * 32 + vd_t) * 64 + kq * 32 + kd0;
      ushort4 h0, l0;
      split2(S[0], h0.x, l0.x); split2(S[1], h0.y, l0.y);
      split2(S[2], h0.z, l0.z); split2(S[3], h0.w, l0.w);
      *(ushort4*)(Sph + spc) = h0;
      *(ushort4*)(Spl + spc) = l0;
    }
    __syncthreads();
    for (int s = 0; s < 64; ++s) {
      float vv = Vs[s][vd_t];
      float kv[4];
      *(float4*)kv = *(const float4*)&Ks[s][kd0];
#pragma unroll
      for (int j = 0; j < 4; ++j) S[j] = fmaf(vv, kv[j], S[j]);
    }
    __syncthreads();
  }
}

// ======= pass2: O = mask(QK^T) Vg + Q Sp^T  (MFMA, split; proven) ===========
__global__ __launch_bounds__(256) void pass2_sp(const u16* __restrict__ qh,
                                                const u16* __restrict__ ql,
                                                const u16* __restrict__ kh,
                                                const u16* __restrict__ vgh,
                                                const u16* __restrict__ Sph,
                                                const u16* __restrict__ Spl,
                                                u16* __restrict__ oh,
                                                u16* __restrict__ ol) {
  __shared__ u16 Qsh[64 * 72];
  __shared__ u16 Qsl[64 * 72];
  __shared__ u16 Ksm[64 * 72];
  __shared__ u16 Am[64 * 72];
  __shared__ u16 Vth[128 * 72];
  const int tid = threadIdx.x;
  const int l = tid & 63, w = tid >> 6;
  const int bid = blockIdx.x;
  const int c = bid & 31, h = (bid >> 5) & 15, b = bid >> 9;
  const size_t rb = (size_t)b * TSEQ + c * 64;
  const int fr = l & 15, fq = l >> 4;
  {
    int r = tid >> 2, c0 = (tid & 3) * 16;
    size_t off = (rb + r) * 1024 + h * 64 + c0;
    *(uint4*)&Qsh[r * 72 + c0]     = *(const uint4*)(qh + off);
    *(uint4*)&Qsh[r * 72 + c0 + 8] = *(const uint4*)(qh + off + 8);
    *(uint4*)&Qsl[r * 72 + c0]     = *(const uint4*)(ql + off);
    *(uint4*)&Qsl[r * 72 + c0 + 8] = *(const uint4*)(ql + off + 8);
    *(uint4*)&Ksm[r * 72 + c0]     = *(const uint4*)(kh + off);
    *(uint4*)&Ksm[r * 72 + c0 + 8] = *(const uint4*)(kh + off + 8);
  }
  {
    int s = tid >> 2, vd0 = (tid & 3) * 32;
    size_t off = (rb + s) * 2048 + h * 128 + vd0;
#pragma unroll
    for (int m4 = 0; m4 < 4; ++m4) {
      U16x8 r_; r_.v = *(const uint4*)(vgh + off + m4 * 8);
#pragma unroll
      for (int j = 0; j < 8; ++j) Vth[(vd0 + m4 * 8 + j) * 72 + s] = r_.s[j];
    }
  }
  __syncthreads();
  short8 aqh[2], aql[2];
#pragma unroll
  for (int kk = 0; kk < 2; ++kk) {
    aqh[kk] = *(const short8*)&Qsh[(w * 16 + fr) * 72 + kk * 32 + 8 * fq];
    aql[kk] = *(const short8*)&Qsl[(w * 16 + fr) * 72 + kk * 32 + 8 * fq];
  }
  f32x4 accA[4] = {};
#pragma unroll
  for (int n = 0; n < 4; ++n)
#pragma unroll
    for (int kk = 0; kk < 2; ++kk) {
      short8 bk = *(const short8*)&Ksm[(n * 16 + fr) * 72 + kk * 32 + 8 * fq];
      accA[n] = __builtin_amdgcn_mfma_f32_16x16x32_bf16(aqh[kk], bk, accA[n], 0, 0, 0);
    }
#pragma unroll
  for (int n = 0; n < 4; ++n)
#pragma unroll
    for (int rr = 0; rr < 4; ++rr) {
      int tt = w * 16 + 4 * fq + rr;
      int s = n * 16 + fr;
      Am[tt * 72 + s] = f2bf((s <= tt) ? accA[n][rr] : 0.f);
    }
  __syncthreads();
  f32x4 acc[8] = {};
#pragma unroll
  for (int kk = 0; kk < 2; ++kk) {
    short8 aa = *(const short8*)&Am[(w * 16 + fr) * 72 + kk * 32 + 8 * fq];
#pragma unroll
    for (int n = 0; n < 8; ++n) {
      short8 bv = *(const short8*)&Vth[(n * 16 + fr) * 72 + kk * 32 + 8 * fq];
      acc[n] = __builtin_amdgcn_mfma_f32_16x16x32_bf16(aa, bv, acc[n], 0, 0, 0);
    }
  }
  const size_t spb = (((size_t)(b * 16 + h) * 32) + c) * 8192;
#pragma unroll
  for (int n = 0; n < 8; ++n)
#pragma unroll
    for (int kk = 0; kk < 2; ++kk) {
      size_t soff = spb + (size_t)(n * 16 + fr) * 64 + kk * 32 + 8 * fq;
      short8 bh_ = *(const short8*)(Sph + soff);
      short8 bl_ = *(const short8*)(Spl + soff);
      acc[n] = __builtin_amdgcn_mfma_f32_16x16x32_bf16(aqh[kk], bh_, acc[n], 0, 0, 0);
      acc[n] = __builtin_amdgcn_mfma_f32_16x16x32_bf16(aqh[kk], bl_, acc[n], 0, 0, 0);
      acc[n] = __builtin_amdgcn_mfma_f32_16x16x32_bf16(aql[kk], bh_, acc[n], 0, 0, 0);
    }
#pragma unroll
  for (int n = 0; n < 8; ++n)
#pragma unroll
    for (int rr = 0; rr < 4; ++rr) {
      int tt = w * 16 + 4 * fq + rr;
      int vd = n * 16 + fr;
      u16 hh, ll;
      split2(acc[n][rr], hh, ll);
      size_t off = (rb + tt) * 2048 + h * 128 + vd;
      oh[off] = hh; ol[off] = ll;
    }
}

// ===========================================================================
extern "C" void kernel_launch(void* const* d_in, const int* in_sizes, int n_in,
                              void* d_out, int out_size, void* d_ws, size_t ws_size,
                              hipStream_t stream) {
  (void)in_sizes; (void)n_in; (void)out_size; (void)ws_size;
  const float* x  = (const float*)d_in[0];
  const float* Wq = (const float*)d_in[1];
  const float* Wk = (const float*)d_in[2];
  const float* Wv = (const float*)d_in[3];
  const float* gq = (const float*)d_in[4];
  const float* gk = (const float*)d_in[5];
  const float* gv = (const float*)d_in[6];
  const float* cq = (const float*)d_in[7];
  const float* ck = (const float*)d_in[8];
  const float* cv = (const float*)d_in[9];
  const float* Wa = (const float*)d_in[10];
  const float* Wb = (const float*)d_in[11];
  const float* Wo = (const float*)d_in[12];
  const float* Wg = (const float*)d_in[13];
  float* out = (float*)d_out;
  char* ws = (char*)d_ws;

  const size_t MiB = 1024 * 1024;
  // ---- workspace (peak exactly 256 MiB, liveness-audited) ----
  u16* Wqkv_h = (u16*)(ws + 0 * MiB);      // 8  ([4096][1024])
  u16* Wqkv_l = (u16*)(ws + 8 * MiB);      // 8
  u16* Wo_h   = (u16*)(ws + 16 * MiB);     // 4
  u16* Wo_l   = (u16*)(ws + 20 * MiB);     // 4
  u16* Wg_h   = (u16*)(ws + 24 * MiB);     // 2
  u16* Wg_l   = (u16*)(ws + 26 * MiB);     // 2
  float* gbuf = (float*)(ws + 28 * MiB);   // 0.5
  u16* x_h    = (u16*)(ws + 32 * MiB);     // 16  [dead after qkv gemm]
  u16* x_l    = (u16*)(ws + 48 * MiB);     // 16
  float* qkv  = (float*)(ws + 64 * MiB);   // 128 [dead after convs]
  u16* q_h = (u16*)(ws + 192 * MiB);       // 16
  u16* q_l = (u16*)(ws + 208 * MiB);       // 16
  u16* k_h = (u16*)(ws + 224 * MiB);       // 16
  u16* k_l = (u16*)(ws + 240 * MiB);       // 16 (ends at 256)
  u16* vg_h = (u16*)(ws + 32 * MiB);       // 32 (x pair dead)
  u16* vg_l = (u16*)d_out;                 // 32 (d_out scratch; dead after scan)
  u16* Sp_h = (u16*)(ws + 96 * MiB);       // 32 (qkv dead)
  u16* Sp_l = (u16*)(ws + 128 * MiB);      // 32
  u16* o_h  = (u16*)(ws + 64 * MiB);       // 32 (qkv head dead)
  u16* o_l  = (u16*)d_out;                 // 32 (vg_l dead after scan)
  float* proj = (float*)(ws + 96 * MiB);   // 32 (Sp_h dead after pass2)
  u16* p_h  = (u16*)(ws + 128 * MiB);      // 16 (Sp_l dead)
  u16* p_l  = (u16*)(ws + 144 * MiB);      // 16

  dim3 blk(256);
  // casts + splits
  castx_sp<<<dim3(8192), blk, 0, stream>>>(x, x_h, x_l);
  transcast_sp<<<dim3(32, 32), blk, 0, stream>>>(Wq, Wqkv_h, Wqkv_l, 1024, 1024);
  transcast_sp<<<dim3(32, 32), blk, 0, stream>>>(Wk, Wqkv_h + 1024 * 1024, Wqkv_l + 1024 * 1024, 1024, 1024);
  transcast_sp<<<dim3(64, 32), blk, 0, stream>>>(Wv, Wqkv_h + 2048 * 1024, Wqkv_l + 2048 * 1024, 1024, 2048);
  transcast_sp<<<dim3(32, 64), blk, 0, stream>>>(Wo, Wo_h, Wo_l, 2048, 1024);
  transcast_sp<<<dim3(32, 32), blk, 0, stream>>>(Wg, Wg_h, Wg_l, 1024, 1024);
  gab_kernel<<<dim3(8192), blk, 0, stream>>>(x, Wa, Wb, gbuf);
  // merged QKV projection (split precision), output [8192][4096] f32
  gemm_sp<0><<<dim3(32, 64), blk, 0, stream>>>(x_h, x_l, Wqkv_h, Wqkv_l, qkv, nullptr, nullptr, nullptr, 8192, 4096, 1024);
  // fused zrms+conv+silu -> split pairs; v pre-scaled by gab
  conv_fs<1024, 0><<<dim3(8192), dim3(256), 0, stream>>>(qkv, cq, gq, nullptr, q_h, q_l);
  conv_fs<1024, 0><<<dim3(8192), dim3(256), 0, stream>>>(qkv + 1024, ck, gk, nullptr, k_h, k_l);
  conv_fs<2048, 1><<<dim3(8192), dim3(512), 0, stream>>>(qkv + 2048, cv, gv, gbuf, vg_h, vg_l);
  // chunked recurrence
  scan_kernel<<<dim3(512), blk, 0, stream>>>(k_h, k_l, vg_h, vg_l, Sp_h, Sp_l);
  pass2_sp<<<dim3(2048), blk, 0, stream>>>(q_h, q_l, k_h, vg_h, Sp_h, Sp_l, o_h, o_l);
  // output projection + gated final GEMM (split precision)
  gemm_sp<1><<<dim3(8, 64), blk, 0, stream>>>(o_h, o_l, Wo_h, Wo_l, proj, p_h, p_l, nullptr, 8192, 1024, 2048);
  gemm_sp<2><<<dim3(8, 64), blk, 0, stream>>>(p_h, p_l, Wg_h, Wg_l, out, nullptr, nullptr, proj, 8192, 1024, 1024);
}

// Round 10
// 692.231 us; speedup vs baseline: 3.6819x; 1.0373x over previous
//
#include <hip/hip_runtime.h>
#include <hip/hip_bf16.h>
#include <math.h>

#define RTOT 8192      // B*T
#define TSEQ 2048

typedef __attribute__((ext_vector_type(8))) short short8;
typedef __attribute__((ext_vector_type(4))) float f32x4;
typedef unsigned short u16;
typedef unsigned int u32;

union U16x8 { uint4 v; u16 s[8]; };

__device__ __forceinline__ float sigmoidf_(float x) { return 1.f / (1.f + expf(-x)); }
__device__ __forceinline__ float bf2f(u16 v) { u32 u = ((u32)v) << 16; float f; __builtin_memcpy(&f, &u, 4); return f; }
__device__ __forceinline__ u16 f2bf(float f) {
  u32 u; __builtin_memcpy(&u, &f, 4);
  u32 r = (u + 0x7FFFu + ((u >> 16) & 1u)) >> 16;
  return (u16)r;
}
// split f32 -> hi bf16 + lo bf16 (residual)
__device__ __forceinline__ void split2(float x, u16& h, u16& l) {
  u16 hh = f2bf(x);
  float hf = bf2f(hh);
  h = hh; l = f2bf(x - hf);
}

typedef const void __attribute__((address_space(1))) gvoid_t;
typedef void __attribute__((address_space(3))) lvoid_t;
__device__ __forceinline__ void gload_lds16(const void* g, void* l) {
  __builtin_amdgcn_global_load_lds((gvoid_t*)g, (lvoid_t*)l, 16, 0, 0);
}

// XCD-chunked bijective block remap (nwg % 8 == 0 required)
__device__ __forceinline__ void xcd_remap(int& bx, int& by) {
  int gx = gridDim.x, nwg = gx * gridDim.y;
  int bid = blockIdx.y * gx + blockIdx.x;
  int cpx = nwg >> 3;
  int swz = (bid & 7) * cpx + (bid >> 3);
  bx = swz % gx; by = swz / gx;
}

// ======= 256^2-tile counted-vmcnt pipelined split-bf16 GEMM (QKV) ===========
// C = A[M,K] @ Bt[N,K]^T, 3-term split (AhBh + AhBl + AlBh), f32 out.
// 512 threads = 8 waves (2M x 4N); BK=32; LDS 128 KB double-buffered.
__global__ __launch_bounds__(512) void gemm_sp_big(const u16* __restrict__ Ah, const u16* __restrict__ Al,
                                                   const u16* __restrict__ Bh, const u16* __restrict__ Bl,
                                                   float* __restrict__ Cf,
                                                   int M, int N, int K) {
  __shared__ u16 lds[2][4][256 * 32];   // [buf][Ah,Al,Bh,Bl][row][k]
  int bx, by; xcd_remap(bx, by);
  const int tid = threadIdx.x;
  const int l = tid & 63, w = tid >> 6;
  const int wr = w >> 2, wc = w & 3;           // 2 x 4 wave grid
  const int m0 = by * 256, n0 = bx * 256;
  const int fr = l & 15, fq = l >> 4;
  const int koff = 8 * fq;
  // staging: thread tid covers rows {tid>>2, 128+(tid>>2)}, cols (tid&3)*8
  const int srow = tid >> 2, scol = (tid & 3) * 8;
  const u16* gA_h = Ah + (size_t)(m0 + srow) * K + scol;
  const u16* gA_l = Al + (size_t)(m0 + srow) * K + scol;
  const u16* gB_h = Bh + (size_t)(n0 + srow) * K + scol;
  const u16* gB_l = Bl + (size_t)(n0 + srow) * K + scol;
  const int lo = srow * 32 + scol;             // = wave_base + lane*8 elems
  const int NT = K >> 5;                       // K-steps of 32

#define STAGE_QKV(buf, t)                                            \
  do {                                                               \
    const int k0_ = (t) << 5;                                        \
    gload_lds16(gA_h + k0_, &lds[buf][0][lo]);                       \
    gload_lds16(gA_h + 128 * K + k0_, &lds[buf][0][lo + 4096]);      \
    gload_lds16(gA_l + k0_, &lds[buf][1][lo]);                       \
    gload_lds16(gA_l + 128 * K + k0_, &lds[buf][1][lo + 4096]);      \
    gload_lds16(gB_h + k0_, &lds[buf][2][lo]);                       \
    gload_lds16(gB_h + 128 * K + k0_, &lds[buf][2][lo + 4096]);      \
    gload_lds16(gB_l + k0_, &lds[buf][3][lo]);                       \
    gload_lds16(gB_l + 128 * K + k0_, &lds[buf][3][lo + 4096]);      \
  } while (0)

  f32x4 acc[8][4] = {};
  // prologue: fill both buffers
  STAGE_QKV(0, 0);
  STAGE_QKV(1, 1);
  asm volatile("s_waitcnt vmcnt(8)" ::: "memory");   // tile 0 complete
  __builtin_amdgcn_s_barrier();

  for (int t = 0; t < NT; ++t) {
    const int cur = t & 1;
    // ---- read fragments for this K-step
    short8 bh8[4], bl8[4];
#pragma unroll
    for (int n = 0; n < 4; ++n) {
      bh8[n] = *(const short8*)&lds[cur][2][(wc * 64 + n * 16 + fr) * 32 + koff];
      bl8[n] = *(const short8*)&lds[cur][3][(wc * 64 + n * 16 + fr) * 32 + koff];
    }
    short8 ah8[8], al8[8];
#pragma unroll
    for (int m = 0; m < 8; ++m) {
      ah8[m] = *(const short8*)&lds[cur][0][(wr * 128 + m * 16 + fr) * 32 + koff];
      al8[m] = *(const short8*)&lds[cur][1][(wr * 128 + m * 16 + fr) * 32 + koff];
    }
    asm volatile("s_waitcnt lgkmcnt(0)" ::: "memory");   // reads done; buf dead
    __builtin_amdgcn_s_barrier();                         // all waves done reading
    if (t + 2 < NT) STAGE_QKV(cur, t + 2);                // overwrite freed buffer
    __builtin_amdgcn_s_setprio(1);
#pragma unroll
    for (int m = 0; m < 8; ++m)
#pragma unroll
      for (int n = 0; n < 4; ++n) {
        acc[m][n] = __builtin_amdgcn_mfma_f32_16x16x32_bf16(ah8[m], bh8[n], acc[m][n], 0, 0, 0);
        acc[m][n] = __builtin_amdgcn_mfma_f32_16x16x32_bf16(ah8[m], bl8[n], acc[m][n], 0, 0, 0);
        acc[m][n] = __builtin_amdgcn_mfma_f32_16x16x32_bf16(al8[m], bh8[n], acc[m][n], 0, 0, 0);
      }
    __builtin_amdgcn_s_setprio(0);
    if (t + 2 < NT) {
      asm volatile("s_waitcnt vmcnt(8)" ::: "memory");   // tile t+1 complete
    } else if (t + 1 < NT) {
      asm volatile("s_waitcnt vmcnt(0)" ::: "memory");
    }
    __builtin_amdgcn_s_barrier();
  }
#undef STAGE_QKV
  // epilogue: f32 C-write
#pragma unroll
  for (int m = 0; m < 8; ++m)
#pragma unroll
    for (int n = 0; n < 4; ++n)
#pragma unroll
      for (int r = 0; r < 4; ++r)
        Cf[(size_t)(m0 + wr * 128 + m * 16 + 4 * fq + r) * N + (n0 + wc * 64 + n * 16 + fr)] = acc[m][n][r];
}

// ======= split-bf16 MFMA GEMM at ~f32 precision (proven, 128^2) =============
// EPI 0: f32 out.  EPI 1: f32 out + split pair out.  EPI 2: f32 out = Pin * sigmoid(acc)
template<int EPI>
__global__ __launch_bounds__(256) void gemm_sp(const u16* __restrict__ Ah, const u16* __restrict__ Al,
                                               const u16* __restrict__ Bh, const u16* __restrict__ Bl,
                                               float* __restrict__ Cf, u16* __restrict__ Ph,
                                               u16* __restrict__ Pl, const float* __restrict__ Pin,
                                               int M, int N, int K) {
  __shared__ u16 Ash[128 * 32], Asl[128 * 32];
  __shared__ u16 Bsh[128 * 32], Bsl[128 * 32];
  int bx, by; xcd_remap(bx, by);
  const int tid = threadIdx.x;
  const int l = tid & 63, w = tid >> 6;
  const int m0 = by * 128, n0 = bx * 128;
  const int wr = w >> 1, wc = w & 1;
  f32x4 acc[4][4] = {};
  const int srow = (w << 5) + (l >> 2);
  const int scol = (l & 3) << 3;
  const size_t gA = (size_t)(m0 + srow) * K + scol;
  const size_t gB = (size_t)(n0 + srow) * K + scol;
  const int lo0 = (w * 2 + 0) * 512, lo1 = (w * 2 + 1) * 512;
  const int arow = wr * 64 + (l & 15), brow = wc * 64 + (l & 15);
  const int koff = 8 * (l >> 4);
  for (int k0 = 0; k0 < K; k0 += 32) {
    gload_lds16(Ah + gA + k0, &Ash[lo0]);
    gload_lds16(Ah + gA + 16 * K + k0, &Ash[lo1]);
    gload_lds16(Al + gA + k0, &Asl[lo0]);
    gload_lds16(Al + gA + 16 * K + k0, &Asl[lo1]);
    gload_lds16(Bh + gB + k0, &Bsh[lo0]);
    gload_lds16(Bh + gB + 16 * K + k0, &Bsh[lo1]);
    gload_lds16(Bl + gB + k0, &Bsl[lo0]);
    gload_lds16(Bl + gB + 16 * K + k0, &Bsl[lo1]);
    __syncthreads();
    short8 afh[4], afl[4], bfh[4], bfl[4];
#pragma unroll
    for (int m = 0; m < 4; ++m) {
      afh[m] = *(const short8*)&Ash[(arow + m * 16) * 32 + koff];
      afl[m] = *(const short8*)&Asl[(arow + m * 16) * 32 + koff];
    }
#pragma unroll
    for (int n = 0; n < 4; ++n) {
      bfh[n] = *(const short8*)&Bsh[(brow + n * 16) * 32 + koff];
      bfl[n] = *(const short8*)&Bsl[(brow + n * 16) * 32 + koff];
    }
#pragma unroll
    for (int m = 0; m < 4; ++m)
#pragma unroll
      for (int n = 0; n < 4; ++n) {
        acc[m][n] = __builtin_amdgcn_mfma_f32_16x16x32_bf16(afh[m], bfh[n], acc[m][n], 0, 0, 0);
        acc[m][n] = __builtin_amdgcn_mfma_f32_16x16x32_bf16(afh[m], bfl[n], acc[m][n], 0, 0, 0);
        acc[m][n] = __builtin_amdgcn_mfma_f32_16x16x32_bf16(afl[m], bfh[n], acc[m][n], 0, 0, 0);
      }
    __syncthreads();
  }
  const int rbase = m0 + wr * 64 + 4 * (l >> 4);
  const int cbase = n0 + wc * 64 + (l & 15);
#pragma unroll
  for (int m = 0; m < 4; ++m)
#pragma unroll
    for (int n = 0; n < 4; ++n)
#pragma unroll
      for (int r = 0; r < 4; ++r) {
        size_t idx = (size_t)(rbase + m * 16 + r) * N + (cbase + n * 16);
        float v = acc[m][n][r];
        if (EPI == 0) {
          Cf[idx] = v;
        } else if (EPI == 1) {
          Cf[idx] = v;
          u16 h, lo; split2(v, h, lo);
          Ph[idx] = h; Pl[idx] = lo;
        } else {
          Cf[idx] = Pin[idx] * sigmoidf_(v);
        }
      }
}

// ======= weight cast+transpose+split: W[K][N] f32 -> Wt_h/Wt_l [N][K] =======
__global__ __launch_bounds__(256) void transcast_sp(const float* __restrict__ W,
                                                    u16* __restrict__ Wth, u16* __restrict__ Wtl,
                                                    int K, int N) {
  __shared__ float t[32][33];
  const int n0 = blockIdx.x * 32, k0 = blockIdx.y * 32;
  const int c = threadIdx.x & 31, rq = threadIdx.x >> 5;
#pragma unroll
  for (int i = 0; i < 4; ++i) t[rq * 4 + i][c] = W[(size_t)(k0 + rq * 4 + i) * N + n0 + c];
  __syncthreads();
#pragma unroll
  for (int i = 0; i < 4; ++i) {
    float v = t[c][rq * 4 + i];
    u16 h, lo; split2(v, h, lo);
    size_t idx = (size_t)(n0 + rq * 4 + i) * K + k0 + c;
    Wth[idx] = h; Wtl[idx] = lo;
  }
}

// ======= x cast+split f32 -> bf16 hi/lo =====================================
__global__ __launch_bounds__(256) void castx_sp(const float* __restrict__ x,
                                                u16* __restrict__ xh, u16* __restrict__ xl) {
  size_t i = (size_t)blockIdx.x * 256 + threadIdx.x;
  float4 v = ((const float4*)x)[i];
  ushort4 hh, ll;
  split2(v.x, hh.x, ll.x); split2(v.y, hh.y, ll.y);
  split2(v.z, hh.z, ll.z); split2(v.w, hh.w, ll.w);
  ((ushort4*)xh)[i] = hh; ((ushort4*)xl)[i] = ll;
}

// ======= fused zrms(stats inline) + conv(K=4) + SiLU -> split pair ==========
template<int C, int GSCALE>
__global__ __launch_bounds__(C / 4) void conv_fs(const float* __restrict__ zn,
                                                 const float* __restrict__ w,
                                                 const float* __restrict__ g,
                                                 const float* __restrict__ gab,
                                                 u16* __restrict__ oh,
                                                 u16* __restrict__ ol) {
  constexpr int NW = C / 256;   // waves per block (4 or 8)
  __shared__ float redA[NW * 4];
  __shared__ float redB[NW * 4];
  const int tid = threadIdx.x;
  const int row = blockIdx.x;
  const int t = row & (TSEQ - 1);
  const int c = tid * 4;
  const int lane = tid & 63, wid = tid >> 6;
  float4 xv[4];
  float psum[4];
#pragma unroll
  for (int d = 0; d < 4; ++d) {
    if (t - d >= 0) xv[d] = *(const float4*)(zn + (size_t)(row - d) * 4096 + c);
    else { xv[d].x = 0.f; xv[d].y = 0.f; xv[d].z = 0.f; xv[d].w = 0.f; }
    psum[d] = xv[d].x + xv[d].y + xv[d].z + xv[d].w;
  }
#pragma unroll
  for (int d = 0; d < 4; ++d)
#pragma unroll
    for (int o = 32; o > 0; o >>= 1) psum[d] += __shfl_xor(psum[d], o, 64);
  if (lane == 0) {
    redA[wid * 4 + 0] = psum[0]; redA[wid * 4 + 1] = psum[1];
    redA[wid * 4 + 2] = psum[2]; redA[wid * 4 + 3] = psum[3];
  }
  __syncthreads();
  float mean[4];
#pragma unroll
  for (int d = 0; d < 4; ++d) {
    float s = 0.f;
#pragma unroll
    for (int j = 0; j < NW; ++j) s += redA[j * 4 + d];
    mean[d] = s * (1.f / C);
  }
  float psq[4];
#pragma unroll
  for (int d = 0; d < 4; ++d) {
    float a = xv[d].x - mean[d], b = xv[d].y - mean[d];
    float e = xv[d].z - mean[d], f = xv[d].w - mean[d];
    psq[d] = a * a + b * b + e * e + f * f;
  }
#pragma unroll
  for (int d = 0; d < 4; ++d)
#pragma unroll
    for (int o = 32; o > 0; o >>= 1) psq[d] += __shfl_xor(psq[d], o, 64);
  if (lane == 0) {
    redB[wid * 4 + 0] = psq[0]; redB[wid * 4 + 1] = psq[1];
    redB[wid * 4 + 2] = psq[2]; redB[wid * 4 + 3] = psq[3];
  }
  __syncthreads();
  float rstd[4];
#pragma unroll
  for (int d = 0; d < 4; ++d) {
    float s = 0.f;
#pragma unroll
    for (int j = 0; j < NW; ++j) s += redB[j * 4 + d];
    rstd[d] = rsqrtf(s * (1.f / C) + 1e-5f);
  }
  float4 g4 = *(const float4*)(g + c);
  float4 acc; acc.x = 0.f; acc.y = 0.f; acc.z = 0.f; acc.w = 0.f;
#pragma unroll
  for (int d = 0; d < 4; ++d) {
    if (t - d >= 0) {
      float4 wv = *(const float4*)(w + (size_t)(3 - d) * C + c);
      acc.x = fmaf((xv[d].x - mean[d]) * rstd[d] * g4.x, wv.x, acc.x);
      acc.y = fmaf((xv[d].y - mean[d]) * rstd[d] * g4.y, wv.y, acc.y);
      acc.z = fmaf((xv[d].z - mean[d]) * rstd[d] * g4.z, wv.z, acc.z);
      acc.w = fmaf((xv[d].w - mean[d]) * rstd[d] * g4.w, wv.w, acc.w);
    }
  }
  float a0 = acc.x * sigmoidf_(acc.x);
  float a1 = acc.y * sigmoidf_(acc.y);
  float a2 = acc.z * sigmoidf_(acc.z);
  float a3 = acc.w * sigmoidf_(acc.w);
  if (GSCALE) {
    float gv = gab[(size_t)row * 16 + (c >> 7)];
    a0 *= gv; a1 *= gv; a2 *= gv; a3 *= gv;
  }
  ushort4 hh, ll;
  split2(a0, hh.x, ll.x); split2(a1, hh.y, ll.y);
  split2(a2, hh.z, ll.z); split2(a3, hh.w, ll.w);
  *(ushort4*)(oh + (size_t)row * C + c) = hh;
  *(ushort4*)(ol + (size_t)row * C + c) = ll;
}

// ======= g = sigmoid(x@Wa)*sigmoid(x@Wb) per (row,head) (proven) ============
__global__ __launch_bounds__(256) void gab_kernel(const float* __restrict__ x,
                                                  const float* __restrict__ Wa,
                                                  const float* __restrict__ Wb,
                                                  float* __restrict__ gout) {
  __shared__ float xs[1024];
  __shared__ float partial[256];
  const int tid = threadIdx.x;
  const size_t row = blockIdx.x;
  *(float4*)(&xs[tid*4]) = *(const float4*)(x + row*1024 + tid*4);
  __syncthreads();
  const int h = tid & 31;
  const int seg = tid >> 5;
  const float* W = (h < 16) ? Wa : Wb;
  const int col = h & 15;
  float s = 0.f;
  const int k0 = seg * 128;
  for (int k = 0; k < 128; ++k) s = fmaf(xs[k0 + k], W[(size_t)(k0 + k) * 16 + col], s);
  partial[tid] = s;
  __syncthreads();
  if (tid < 32) {
    float t2 = 0.f;
#pragma unroll
    for (int j = 0; j < 8; ++j) t2 += partial[j*32 + tid];
    partial[tid] = t2;
  }
  __syncthreads();
  if (tid < 16)
    gout[row*16 + tid] = sigmoidf_(partial[tid]) * sigmoidf_(partial[tid + 16]);
}

// ======= scan: exclusive chunk-prefix of Vg^T K, kd-split (512 blocks) ======
__global__ __launch_bounds__(256) void scan_kernel(const u16* __restrict__ kh,
                                                   const u16* __restrict__ kl,
                                                   const u16* __restrict__ vgh,
                                                   const u16* __restrict__ vgl,
                                                   u16* __restrict__ Sph,
                                                   u16* __restrict__ Spl) {
  __shared__ float Ks[64][36];
  __shared__ float Vs[64][36];
  const int tid = threadIdx.x;
  const int bid = blockIdx.x;
  const int kq = bid & 1, vq = (bid >> 1) & 3, h = (bid >> 3) & 15, b = bid >> 7;
  const size_t rb = (size_t)b * TSEQ;
  const int vd_t = tid >> 3, kd0 = (tid & 7) * 4;
  float S[4] = {};
  const int sr = tid >> 2;            // staging row 0..63
  const int cc0 = (tid & 3) * 8;      // 8-col slice
  for (int c = 0; c < 32; ++c) {
    {
      size_t koffg = (rb + (size_t)c * 64 + sr) * 1024 + h * 64 + kq * 32 + cc0;
      U16x8 a0, b0;
      a0.v = *(const uint4*)(kh + koffg);
      b0.v = *(const uint4*)(kl + koffg);
#pragma unroll
      for (int j = 0; j < 8; ++j) Ks[sr][cc0 + j] = bf2f(a0.s[j]) + bf2f(b0.s[j]);
      size_t voffg = (rb + (size_t)c * 64 + sr) * 2048 + h * 128 + vq * 32 + cc0;
      U16x8 va, vb;
      va.v = *(const uint4*)(vgh + voffg);
      vb.v = *(const uint4*)(vgl + voffg);
#pragma unroll
      for (int j = 0; j < 8; ++j) Vs[sr][cc0 + j] = bf2f(va.s[j]) + bf2f(vb.s[j]);
    }
    {
      size_t spc = (((size_t)(b * 16 + h) * 32) + c) * 8192
                 + (size_t)(vq * 32 + vd_t) * 64 + kq * 32 + kd0;
      ushort4 h0, l0;
      split2(S[0], h0.x, l0.x); split2(S[1], h0.y, l0.y);
      split2(S[2], h0.z, l0.z); split2(S[3], h0.w, l0.w);
      *(ushort4*)(Sph + spc) = h0;
      *(ushort4*)(Spl + spc) = l0;
    }
    __syncthreads();
    for (int s = 0; s < 64; ++s) {
      float vv = Vs[s][vd_t];
      float kv[4];
      *(float4*)kv = *(const float4*)&Ks[s][kd0];
#pragma unroll
      for (int j = 0; j < 4; ++j) S[j] = fmaf(vv, kv[j], S[j]);
    }
    __syncthreads();
  }
}

// ======= pass2: O = mask(QK^T) Vg + Q Sp^T  (MFMA, split; proven) ===========
__global__ __launch_bounds__(256) void pass2_sp(const u16* __restrict__ qh,
                                                const u16* __restrict__ ql,
                                                const u16* __restrict__ kh,
                                                const u16* __restrict__ vgh,
                                                const u16* __restrict__ Sph,
                                                const u16* __restrict__ Spl,
                                                u16* __restrict__ oh,
                                                u16* __restrict__ ol) {
  __shared__ u16 Qsh[64 * 72];
  __shared__ u16 Qsl[64 * 72];
  __shared__ u16 Ksm[64 * 72];
  __shared__ u16 Am[64 * 72];
  __shared__ u16 Vth[128 * 72];
  const int tid = threadIdx.x;
  const int l = tid & 63, w = tid >> 6;
  const int bid = blockIdx.x;
  const int c = bid & 31, h = (bid >> 5) & 15, b = bid >> 9;
  const size_t rb = (size_t)b * TSEQ + c * 64;
  const int fr = l & 15, fq = l >> 4;
  {
    int r = tid >> 2, c0 = (tid & 3) * 16;
    size_t off = (rb + r) * 1024 + h * 64 + c0;
    *(uint4*)&Qsh[r * 72 + c0]     = *(const uint4*)(qh + off);
    *(uint4*)&Qsh[r * 72 + c0 + 8] = *(const uint4*)(qh + off + 8);
    *(uint4*)&Qsl[r * 72 + c0]     = *(const uint4*)(ql + off);
    *(uint4*)&Qsl[r * 72 + c0 + 8] = *(const uint4*)(ql + off + 8);
    *(uint4*)&Ksm[r * 72 + c0]     = *(const uint4*)(kh + off);
    *(uint4*)&Ksm[r * 72 + c0 + 8] = *(const uint4*)(kh + off + 8);
  }
  {
    int s = tid >> 2, vd0 = (tid & 3) * 32;
    size_t off = (rb + s) * 2048 + h * 128 + vd0;
#pragma unroll
    for (int m4 = 0; m4 < 4; ++m4) {
      U16x8 r_; r_.v = *(const uint4*)(vgh + off + m4 * 8);
#pragma unroll
      for (int j = 0; j < 8; ++j) Vth[(vd0 + m4 * 8 + j) * 72 + s] = r_.s[j];
    }
  }
  __syncthreads();
  short8 aqh[2], aql[2];
#pragma unroll
  for (int kk = 0; kk < 2; ++kk) {
    aqh[kk] = *(const short8*)&Qsh[(w * 16 + fr) * 72 + kk * 32 + 8 * fq];
    aql[kk] = *(const short8*)&Qsl[(w * 16 + fr) * 72 + kk * 32 + 8 * fq];
  }
  f32x4 accA[4] = {};
#pragma unroll
  for (int n = 0; n < 4; ++n)
#pragma unroll
    for (int kk = 0; kk < 2; ++kk) {
      short8 bk = *(const short8*)&Ksm[(n * 16 + fr) * 72 + kk * 32 + 8 * fq];
      accA[n] = __builtin_amdgcn_mfma_f32_16x16x32_bf16(aqh[kk], bk, accA[n], 0, 0, 0);
    }
#pragma unroll
  for (int n = 0; n < 4; ++n)
#pragma unroll
    for (int rr = 0; rr < 4; ++rr) {
      int tt = w * 16 + 4 * fq + rr;
      int s = n * 16 + fr;
      Am[tt * 72 + s] = f2bf((s <= tt) ? accA[n][rr] : 0.f);
    }
  __syncthreads();
  f32x4 acc[8] = {};
#pragma unroll
  for (int kk = 0; kk < 2; ++kk) {
    short8 aa = *(const short8*)&Am[(w * 16 + fr) * 72 + kk * 32 + 8 * fq];
#pragma unroll
    for (int n = 0; n < 8; ++n) {
      short8 bv = *(const short8*)&Vth[(n * 16 + fr) * 72 + kk * 32 + 8 * fq];
      acc[n] = __builtin_amdgcn_mfma_f32_16x16x32_bf16(aa, bv, acc[n], 0, 0, 0);
    }
  }
  const size_t spb = (((size_t)(b * 16 + h) * 32) + c) * 8192;
#pragma unroll
  for (int n = 0; n < 8; ++n)
#pragma unroll
    for (int kk = 0; kk < 2; ++kk) {
      size_t soff = spb + (size_t)(n * 16 + fr) * 64 + kk * 32 + 8 * fq;
      short8 bh_ = *(const short8*)(Sph + soff);
      short8 bl_ = *(const short8*)(Spl + soff);
      acc[n] = __builtin_amdgcn_mfma_f32_16x16x32_bf16(aqh[kk], bh_, acc[n], 0, 0, 0);
      acc[n] = __builtin_amdgcn_mfma_f32_16x16x32_bf16(aqh[kk], bl_, acc[n], 0, 0, 0);
      acc[n] = __builtin_amdgcn_mfma_f32_16x16x32_bf16(aql[kk], bh_, acc[n], 0, 0, 0);
    }
#pragma unroll
  for (int n = 0; n < 8; ++n)
#pragma unroll
    for (int rr = 0; rr < 4; ++rr) {
      int tt = w * 16 + 4 * fq + rr;
      int vd = n * 16 + fr;
      u16 hh, ll;
      split2(acc[n][rr], hh, ll);
      size_t off = (rb + tt) * 2048 + h * 128 + vd;
      oh[off] = hh; ol[off] = ll;
    }
}

// ===========================================================================
extern "C" void kernel_launch(void* const* d_in, const int* in_sizes, int n_in,
                              void* d_out, int out_size, void* d_ws, size_t ws_size,
                              hipStream_t stream) {
  (void)in_sizes; (void)n_in; (void)out_size; (void)ws_size;
  const float* x  = (const float*)d_in[0];
  const float* Wq = (const float*)d_in[1];
  const float* Wk = (const float*)d_in[2];
  const float* Wv = (const float*)d_in[3];
  const float* gq = (const float*)d_in[4];
  const float* gk = (const float*)d_in[5];
  const float* gv = (const float*)d_in[6];
  const float* cq = (const float*)d_in[7];
  const float* ck = (const float*)d_in[8];
  const float* cv = (const float*)d_in[9];
  const float* Wa = (const float*)d_in[10];
  const float* Wb = (const float*)d_in[11];
  const float* Wo = (const float*)d_in[12];
  const float* Wg = (const float*)d_in[13];
  float* out = (float*)d_out;
  char* ws = (char*)d_ws;

  const size_t MiB = 1024 * 1024;
  // ---- workspace (peak exactly 256 MiB, liveness-audited; same as r9) ----
  u16* Wqkv_h = (u16*)(ws + 0 * MiB);      // 8  ([4096][1024])
  u16* Wqkv_l = (u16*)(ws + 8 * MiB);      // 8
  u16* Wo_h   = (u16*)(ws + 16 * MiB);     // 4
  u16* Wo_l   = (u16*)(ws + 20 * MiB);     // 4
  u16* Wg_h   = (u16*)(ws + 24 * MiB);     // 2
  u16* Wg_l   = (u16*)(ws + 26 * MiB);     // 2
  float* gbuf = (float*)(ws + 28 * MiB);   // 0.5
  u16* x_h    = (u16*)(ws + 32 * MiB);     // 16  [dead after qkv gemm]
  u16* x_l    = (u16*)(ws + 48 * MiB);     // 16
  float* qkv  = (float*)(ws + 64 * MiB);   // 128 [dead after convs]
  u16* q_h = (u16*)(ws + 192 * MiB);       // 16
  u16* q_l = (u16*)(ws + 208 * MiB);       // 16
  u16* k_h = (u16*)(ws + 224 * MiB);       // 16
  u16* k_l = (u16*)(ws + 240 * MiB);       // 16 (ends at 256)
  u16* vg_h = (u16*)(ws + 32 * MiB);       // 32 (x pair dead)
  u16* vg_l = (u16*)d_out;                 // 32 (d_out scratch; dead after scan)
  u16* Sp_h = (u16*)(ws + 96 * MiB);       // 32 (qkv dead)
  u16* Sp_l = (u16*)(ws + 128 * MiB);      // 32
  u16* o_h  = (u16*)(ws + 64 * MiB);       // 32 (qkv head dead)
  u16* o_l  = (u16*)d_out;                 // 32 (vg_l dead after scan)
  float* proj = (float*)(ws + 96 * MiB);   // 32 (Sp_h dead after pass2)
  u16* p_h  = (u16*)(ws + 128 * MiB);      // 16 (Sp_l dead)
  u16* p_l  = (u16*)(ws + 144 * MiB);      // 16

  dim3 blk(256);
  // casts + splits
  castx_sp<<<dim3(8192), blk, 0, stream>>>(x, x_h, x_l);
  transcast_sp<<<dim3(32, 32), blk, 0, stream>>>(Wq, Wqkv_h, Wqkv_l, 1024, 1024);
  transcast_sp<<<dim3(32, 32), blk, 0, stream>>>(Wk, Wqkv_h + 1024 * 1024, Wqkv_l + 1024 * 1024, 1024, 1024);
  transcast_sp<<<dim3(64, 32), blk, 0, stream>>>(Wv, Wqkv_h + 2048 * 1024, Wqkv_l + 2048 * 1024, 1024, 2048);
  transcast_sp<<<dim3(32, 64), blk, 0, stream>>>(Wo, Wo_h, Wo_l, 2048, 1024);
  transcast_sp<<<dim3(32, 32), blk, 0, stream>>>(Wg, Wg_h, Wg_l, 1024, 1024);
  gab_kernel<<<dim3(8192), blk, 0, stream>>>(x, Wa, Wb, gbuf);
  // merged QKV projection: 256^2-tile counted-vmcnt pipelined split GEMM
  gemm_sp_big<<<dim3(16, 32), dim3(512), 0, stream>>>(x_h, x_l, Wqkv_h, Wqkv_l, qkv, 8192, 4096, 1024);
  // fused zrms+conv+silu -> split pairs; v pre-scaled by gab
  conv_fs<1024, 0><<<dim3(8192), dim3(256), 0, stream>>>(qkv, cq, gq, nullptr, q_h, q_l);
  conv_fs<1024, 0><<<dim3(8192), dim3(256), 0, stream>>>(qkv + 1024, ck, gk, nullptr, k_h, k_l);
  conv_fs<2048, 1><<<dim3(8192), dim3(512), 0, stream>>>(qkv + 2048, cv, gv, gbuf, vg_h, vg_l);
  // chunked recurrence
  scan_kernel<<<dim3(512), blk, 0, stream>>>(k_h, k_l, vg_h, vg_l, Sp_h, Sp_l);
  pass2_sp<<<dim3(2048), blk, 0, stream>>>(q_h, q_l, k_h, vg_h, Sp_h, Sp_l, o_h, o_l);
  // output projection + gated final GEMM (split precision)
  gemm_sp<1><<<dim3(8, 64), blk, 0, stream>>>(o_h, o_l, Wo_h, Wo_l, proj, p_h, p_l, nullptr, 8192, 1024, 2048);
  gemm_sp<2><<<dim3(8, 64), blk, 0, stream>>>(p_h, p_l, Wg_h, Wg_l, out, nullptr, nullptr, proj, 8192, 1024, 1024);
}

// Round 11
// 676.029 us; speedup vs baseline: 3.7702x; 1.0240x over previous
//
#include <hip/hip_runtime.h>
#include <hip/hip_bf16.h>
#include <math.h>

#define RTOT 8192      // B*T
#define TSEQ 2048

typedef __attribute__((ext_vector_type(8))) short short8;
typedef __attribute__((ext_vector_type(4))) float f32x4;
typedef unsigned short u16;
typedef unsigned int u32;

union U16x8 { uint4 v; u16 s[8]; };

__device__ __forceinline__ float sigmoidf_(float x) { return 1.f / (1.f + expf(-x)); }
__device__ __forceinline__ float bf2f(u16 v) { u32 u = ((u32)v) << 16; float f; __builtin_memcpy(&f, &u, 4); return f; }
__device__ __forceinline__ u16 f2bf(float f) {
  u32 u; __builtin_memcpy(&u, &f, 4);
  u32 r = (u + 0x7FFFu + ((u >> 16) & 1u)) >> 16;
  return (u16)r;
}
// split f32 -> hi bf16 + lo bf16 (residual)
__device__ __forceinline__ void split2(float x, u16& h, u16& l) {
  u16 hh = f2bf(x);
  float hf = bf2f(hh);
  h = hh; l = f2bf(x - hf);
}

typedef const void __attribute__((address_space(1))) gvoid_t;
typedef void __attribute__((address_space(3))) lvoid_t;
__device__ __forceinline__ void gload_lds16(const void* g, void* l) {
  __builtin_amdgcn_global_load_lds((gvoid_t*)g, (lvoid_t*)l, 16, 0, 0);
}

// XCD-chunked bijective block remap (nwg % 8 == 0 required)
__device__ __forceinline__ void xcd_remap(int& bx, int& by) {
  int gx = gridDim.x, nwg = gx * gridDim.y;
  int bid = blockIdx.y * gx + blockIdx.x;
  int cpx = nwg >> 3;
  int swz = (bid & 7) * cpx + (bid >> 3);
  bx = swz % gx; by = swz / gx;
}

// ======= 256^2-tile counted-vmcnt pipelined split-bf16 GEMM (QKV) ===========
// C = A[M,K] @ Bt[N,K]^T, 3-term split (AhBh + AhBl + AlBh), f32 out.
// 512 threads = 8 waves (2M x 4N); BK=32; LDS 128 KB double-buffered.
// T2 swizzle: global source pre-swizzled (granule ^= row&3), linear LDS dest
// (global_load_lds constraint), reads use koff = 8*(fq ^ (fr&3)).
__global__ __launch_bounds__(512) void gemm_sp_big(const u16* __restrict__ Ah, const u16* __restrict__ Al,
                                                   const u16* __restrict__ Bh, const u16* __restrict__ Bl,
                                                   float* __restrict__ Cf,
                                                   int M, int N, int K) {
  __shared__ u16 lds[2][4][256 * 32];   // [buf][Ah,Al,Bh,Bl][row][k]
  int bx, by; xcd_remap(bx, by);
  const int tid = threadIdx.x;
  const int l = tid & 63, w = tid >> 6;
  const int wr = w >> 2, wc = w & 3;           // 2 x 4 wave grid
  const int m0 = by * 256, n0 = bx * 256;
  const int fr = l & 15, fq = l >> 4;
  const int koff = 8 * (fq ^ (fr & 3));        // swizzled read granule
  // staging: thread tid covers rows {tid>>2, 128+(tid>>2)}; global granule
  // pre-swizzled so LDS granule g of row r holds global granule g^(r&3).
  const int srow = tid >> 2;
  const int scol = ((tid & 3) ^ (srow & 3)) * 8;
  const u16* gA_h = Ah + (size_t)(m0 + srow) * K + scol;
  const u16* gA_l = Al + (size_t)(m0 + srow) * K + scol;
  const u16* gB_h = Bh + (size_t)(n0 + srow) * K + scol;
  const u16* gB_l = Bl + (size_t)(n0 + srow) * K + scol;
  const int lo = srow * 32 + (tid & 3) * 8;    // linear LDS dest (wave base + lane*8 elems)
  const int NT = K >> 5;                       // K-steps of 32

#define STAGE_QKV(buf, t)                                            \
  do {                                                               \
    const int k0_ = (t) << 5;                                        \
    gload_lds16(gA_h + k0_, &lds[buf][0][lo]);                       \
    gload_lds16(gA_h + 128 * K + k0_, &lds[buf][0][lo + 4096]);      \
    gload_lds16(gA_l + k0_, &lds[buf][1][lo]);                       \
    gload_lds16(gA_l + 128 * K + k0_, &lds[buf][1][lo + 4096]);      \
    gload_lds16(gB_h + k0_, &lds[buf][2][lo]);                       \
    gload_lds16(gB_h + 128 * K + k0_, &lds[buf][2][lo + 4096]);      \
    gload_lds16(gB_l + k0_, &lds[buf][3][lo]);                       \
    gload_lds16(gB_l + 128 * K + k0_, &lds[buf][3][lo + 4096]);      \
  } while (0)

  f32x4 acc[8][4] = {};
  // prologue: fill both buffers
  STAGE_QKV(0, 0);
  STAGE_QKV(1, 1);
  asm volatile("s_waitcnt vmcnt(8)" ::: "memory");   // tile 0 complete
  __builtin_amdgcn_s_barrier();

  for (int t = 0; t < NT; ++t) {
    const int cur = t & 1;
    // ---- fragment reads: compiler inserts fine-grained per-use lgkmcnt,
    //      so early MFMAs overlap late ds_reads (no explicit drain here).
    short8 bh8[4], bl8[4];
#pragma unroll
    for (int n = 0; n < 4; ++n) {
      bh8[n] = *(const short8*)&lds[cur][2][(wc * 64 + n * 16 + fr) * 32 + koff];
      bl8[n] = *(const short8*)&lds[cur][3][(wc * 64 + n * 16 + fr) * 32 + koff];
    }
    short8 ah8[8], al8[8];
#pragma unroll
    for (int m = 0; m < 8; ++m) {
      ah8[m] = *(const short8*)&lds[cur][0][(wr * 128 + m * 16 + fr) * 32 + koff];
      al8[m] = *(const short8*)&lds[cur][1][(wr * 128 + m * 16 + fr) * 32 + koff];
    }
    __builtin_amdgcn_s_setprio(1);
#pragma unroll
    for (int m = 0; m < 8; ++m)
#pragma unroll
      for (int n = 0; n < 4; ++n) {
        acc[m][n] = __builtin_amdgcn_mfma_f32_16x16x32_bf16(ah8[m], bh8[n], acc[m][n], 0, 0, 0);
        acc[m][n] = __builtin_amdgcn_mfma_f32_16x16x32_bf16(ah8[m], bl8[n], acc[m][n], 0, 0, 0);
        acc[m][n] = __builtin_amdgcn_mfma_f32_16x16x32_bf16(al8[m], bh8[n], acc[m][n], 0, 0, 0);
      }
    __builtin_amdgcn_s_setprio(0);
    asm volatile("s_waitcnt lgkmcnt(0)" ::: "memory");   // all reads consumed; buf dead
    __builtin_amdgcn_s_barrier();                         // all waves done with buf
    if (t + 2 < NT) {
      STAGE_QKV(cur, t + 2);                              // overwrite freed buffer
      asm volatile("s_waitcnt vmcnt(8)" ::: "memory");    // tile t+1 complete
    } else if (t + 1 < NT) {
      asm volatile("s_waitcnt vmcnt(0)" ::: "memory");
    }
    __builtin_amdgcn_s_barrier();
  }
#undef STAGE_QKV
  // epilogue: f32 C-write
#pragma unroll
  for (int m = 0; m < 8; ++m)
#pragma unroll
    for (int n = 0; n < 4; ++n)
#pragma unroll
      for (int r = 0; r < 4; ++r)
        Cf[(size_t)(m0 + wr * 128 + m * 16 + 4 * fq + r) * N + (n0 + wc * 64 + n * 16 + fr)] = acc[m][n][r];
}

// ======= split-bf16 MFMA GEMM at ~f32 precision (proven, 128^2) =============
// EPI 0: f32 out.  EPI 1: f32 out + split pair out.  EPI 2: f32 out = Pin * sigmoid(acc)
template<int EPI>
__global__ __launch_bounds__(256) void gemm_sp(const u16* __restrict__ Ah, const u16* __restrict__ Al,
                                               const u16* __restrict__ Bh, const u16* __restrict__ Bl,
                                               float* __restrict__ Cf, u16* __restrict__ Ph,
                                               u16* __restrict__ Pl, const float* __restrict__ Pin,
                                               int M, int N, int K) {
  __shared__ u16 Ash[128 * 32], Asl[128 * 32];
  __shared__ u16 Bsh[128 * 32], Bsl[128 * 32];
  int bx, by; xcd_remap(bx, by);
  const int tid = threadIdx.x;
  const int l = tid & 63, w = tid >> 6;
  const int m0 = by * 128, n0 = bx * 128;
  const int wr = w >> 1, wc = w & 1;
  f32x4 acc[4][4] = {};
  const int srow = (w << 5) + (l >> 2);
  const int scol = (l & 3) << 3;
  const size_t gA = (size_t)(m0 + srow) * K + scol;
  const size_t gB = (size_t)(n0 + srow) * K + scol;
  const int lo0 = (w * 2 + 0) * 512, lo1 = (w * 2 + 1) * 512;
  const int arow = wr * 64 + (l & 15), brow = wc * 64 + (l & 15);
  const int koff = 8 * (l >> 4);
  for (int k0 = 0; k0 < K; k0 += 32) {
    gload_lds16(Ah + gA + k0, &Ash[lo0]);
    gload_lds16(Ah + gA + 16 * K + k0, &Ash[lo1]);
    gload_lds16(Al + gA + k0, &Asl[lo0]);
    gload_lds16(Al + gA + 16 * K + k0, &Asl[lo1]);
    gload_lds16(Bh + gB + k0, &Bsh[lo0]);
    gload_lds16(Bh + gB + 16 * K + k0, &Bsh[lo1]);
    gload_lds16(Bl + gB + k0, &Bsl[lo0]);
    gload_lds16(Bl + gB + 16 * K + k0, &Bsl[lo1]);
    __syncthreads();
    short8 afh[4], afl[4], bfh[4], bfl[4];
#pragma unroll
    for (int m = 0; m < 4; ++m) {
      afh[m] = *(const short8*)&Ash[(arow + m * 16) * 32 + koff];
      afl[m] = *(const short8*)&Asl[(arow + m * 16) * 32 + koff];
    }
#pragma unroll
    for (int n = 0; n < 4; ++n) {
      bfh[n] = *(const short8*)&Bsh[(brow + n * 16) * 32 + koff];
      bfl[n] = *(const short8*)&Bsl[(brow + n * 16) * 32 + koff];
    }
#pragma unroll
    for (int m = 0; m < 4; ++m)
#pragma unroll
      for (int n = 0; n < 4; ++n) {
        acc[m][n] = __builtin_amdgcn_mfma_f32_16x16x32_bf16(afh[m], bfh[n], acc[m][n], 0, 0, 0);
        acc[m][n] = __builtin_amdgcn_mfma_f32_16x16x32_bf16(afh[m], bfl[n], acc[m][n], 0, 0, 0);
        acc[m][n] = __builtin_amdgcn_mfma_f32_16x16x32_bf16(afl[m], bfh[n], acc[m][n], 0, 0, 0);
      }
    __syncthreads();
  }
  const int rbase = m0 + wr * 64 + 4 * (l >> 4);
  const int cbase = n0 + wc * 64 + (l & 15);
#pragma unroll
  for (int m = 0; m < 4; ++m)
#pragma unroll
    for (int n = 0; n < 4; ++n)
#pragma unroll
      for (int r = 0; r < 4; ++r) {
        size_t idx = (size_t)(rbase + m * 16 + r) * N + (cbase + n * 16);
        float v = acc[m][n][r];
        if (EPI == 0) {
          Cf[idx] = v;
        } else if (EPI == 1) {
          Cf[idx] = v;
          u16 h, lo; split2(v, h, lo);
          Ph[idx] = h; Pl[idx] = lo;
        } else {
          Cf[idx] = Pin[idx] * sigmoidf_(v);
        }
      }
}

// ======= weight cast+transpose+split: W[K][N] f32 -> Wt_h/Wt_l [N][K] =======
__global__ __launch_bounds__(256) void transcast_sp(const float* __restrict__ W,
                                                    u16* __restrict__ Wth, u16* __restrict__ Wtl,
                                                    int K, int N) {
  __shared__ float t[32][33];
  const int n0 = blockIdx.x * 32, k0 = blockIdx.y * 32;
  const int c = threadIdx.x & 31, rq = threadIdx.x >> 5;
#pragma unroll
  for (int i = 0; i < 4; ++i) t[rq * 4 + i][c] = W[(size_t)(k0 + rq * 4 + i) * N + n0 + c];
  __syncthreads();
#pragma unroll
  for (int i = 0; i < 4; ++i) {
    float v = t[c][rq * 4 + i];
    u16 h, lo; split2(v, h, lo);
    size_t idx = (size_t)(n0 + rq * 4 + i) * K + k0 + c;
    Wth[idx] = h; Wtl[idx] = lo;
  }
}

// ======= x cast+split f32 -> bf16 hi/lo =====================================
__global__ __launch_bounds__(256) void castx_sp(const float* __restrict__ x,
                                                u16* __restrict__ xh, u16* __restrict__ xl) {
  size_t i = (size_t)blockIdx.x * 256 + threadIdx.x;
  float4 v = ((const float4*)x)[i];
  ushort4 hh, ll;
  split2(v.x, hh.x, ll.x); split2(v.y, hh.y, ll.y);
  split2(v.z, hh.z, ll.z); split2(v.w, hh.w, ll.w);
  ((ushort4*)xh)[i] = hh; ((ushort4*)xl)[i] = ll;
}

// ======= fused zrms(stats inline) + conv(K=4) + SiLU -> split pair ==========
template<int C, int GSCALE>
__global__ __launch_bounds__(C / 4) void conv_fs(const float* __restrict__ zn,
                                                 const float* __restrict__ w,
                                                 const float* __restrict__ g,
                                                 const float* __restrict__ gab,
                                                 u16* __restrict__ oh,
                                                 u16* __restrict__ ol) {
  constexpr int NW = C / 256;   // waves per block (4 or 8)
  __shared__ float redA[NW * 4];
  __shared__ float redB[NW * 4];
  const int tid = threadIdx.x;
  const int row = blockIdx.x;
  const int t = row & (TSEQ - 1);
  const int c = tid * 4;
  const int lane = tid & 63, wid = tid >> 6;
  float4 xv[4];
  float psum[4];
#pragma unroll
  for (int d = 0; d < 4; ++d) {
    if (t - d >= 0) xv[d] = *(const float4*)(zn + (size_t)(row - d) * 4096 + c);
    else { xv[d].x = 0.f; xv[d].y = 0.f; xv[d].z = 0.f; xv[d].w = 0.f; }
    psum[d] = xv[d].x + xv[d].y + xv[d].z + xv[d].w;
  }
#pragma unroll
  for (int d = 0; d < 4; ++d)
#pragma unroll
    for (int o = 32; o > 0; o >>= 1) psum[d] += __shfl_xor(psum[d], o, 64);
  if (lane == 0) {
    redA[wid * 4 + 0] = psum[0]; redA[wid * 4 + 1] = psum[1];
    redA[wid * 4 + 2] = psum[2]; redA[wid * 4 + 3] = psum[3];
  }
  __syncthreads();
  float mean[4];
#pragma unroll
  for (int d = 0; d < 4; ++d) {
    float s = 0.f;
#pragma unroll
    for (int j = 0; j < NW; ++j) s += redA[j * 4 + d];
    mean[d] = s * (1.f / C);
  }
  float psq[4];
#pragma unroll
  for (int d = 0; d < 4; ++d) {
    float a = xv[d].x - mean[d], b = xv[d].y - mean[d];
    float e = xv[d].z - mean[d], f = xv[d].w - mean[d];
    psq[d] = a * a + b * b + e * e + f * f;
  }
#pragma unroll
  for (int d = 0; d < 4; ++d)
#pragma unroll
    for (int o = 32; o > 0; o >>= 1) psq[d] += __shfl_xor(psq[d], o, 64);
  if (lane == 0) {
    redB[wid * 4 + 0] = psq[0]; redB[wid * 4 + 1] = psq[1];
    redB[wid * 4 + 2] = psq[2]; redB[wid * 4 + 3] = psq[3];
  }
  __syncthreads();
  float rstd[4];
#pragma unroll
  for (int d = 0; d < 4; ++d) {
    float s = 0.f;
#pragma unroll
    for (int j = 0; j < NW; ++j) s += redB[j * 4 + d];
    rstd[d] = rsqrtf(s * (1.f / C) + 1e-5f);
  }
  float4 g4 = *(const float4*)(g + c);
  float4 acc; acc.x = 0.f; acc.y = 0.f; acc.z = 0.f; acc.w = 0.f;
#pragma unroll
  for (int d = 0; d < 4; ++d) {
    if (t - d >= 0) {
      float4 wv = *(const float4*)(w + (size_t)(3 - d) * C + c);
      acc.x = fmaf((xv[d].x - mean[d]) * rstd[d] * g4.x, wv.x, acc.x);
      acc.y = fmaf((xv[d].y - mean[d]) * rstd[d] * g4.y, wv.y, acc.y);
      acc.z = fmaf((xv[d].z - mean[d]) * rstd[d] * g4.z, wv.z, acc.z);
      acc.w = fmaf((xv[d].w - mean[d]) * rstd[d] * g4.w, wv.w, acc.w);
    }
  }
  float a0 = acc.x * sigmoidf_(acc.x);
  float a1 = acc.y * sigmoidf_(acc.y);
  float a2 = acc.z * sigmoidf_(acc.z);
  float a3 = acc.w * sigmoidf_(acc.w);
  if (GSCALE) {
    float gv = gab[(size_t)row * 16 + (c >> 7)];
    a0 *= gv; a1 *= gv; a2 *= gv; a3 *= gv;
  }
  ushort4 hh, ll;
  split2(a0, hh.x, ll.x); split2(a1, hh.y, ll.y);
  split2(a2, hh.z, ll.z); split2(a3, hh.w, ll.w);
  *(ushort4*)(oh + (size_t)row * C + c) = hh;
  *(ushort4*)(ol + (size_t)row * C + c) = ll;
}

// ======= g = sigmoid(x@Wa)*sigmoid(x@Wb) per (row,head) (proven) ============
__global__ __launch_bounds__(256) void gab_kernel(const float* __restrict__ x,
                                                  const float* __restrict__ Wa,
                                                  const float* __restrict__ Wb,
                                                  float* __restrict__ gout) {
  __shared__ float xs[1024];
  __shared__ float partial[256];
  const int tid = threadIdx.x;
  const size_t row = blockIdx.x;
  *(float4*)(&xs[tid*4]) = *(const float4*)(x + row*1024 + tid*4);
  __syncthreads();
  const int h = tid & 31;
  const int seg = tid >> 5;
  const float* W = (h < 16) ? Wa : Wb;
  const int col = h & 15;
  float s = 0.f;
  const int k0 = seg * 128;
  for (int k = 0; k < 128; ++k) s = fmaf(xs[k0 + k], W[(size_t)(k0 + k) * 16 + col], s);
  partial[tid] = s;
  __syncthreads();
  if (tid < 32) {
    float t2 = 0.f;
#pragma unroll
    for (int j = 0; j < 8; ++j) t2 += partial[j*32 + tid];
    partial[tid] = t2;
  }
  __syncthreads();
  if (tid < 16)
    gout[row*16 + tid] = sigmoidf_(partial[tid]) * sigmoidf_(partial[tid + 16]);
}

// ======= scan: exclusive chunk-prefix of Vg^T K, kd-split (512 blocks) ======
__global__ __launch_bounds__(256) void scan_kernel(const u16* __restrict__ kh,
                                                   const u16* __restrict__ kl,
                                                   const u16* __restrict__ vgh,
                                                   const u16* __restrict__ vgl,
                                                   u16* __restrict__ Sph,
                                                   u16* __restrict__ Spl) {
  __shared__ float Ks[64][36];
  __shared__ float Vs[64][36];
  const int tid = threadIdx.x;
  const int bid = blockIdx.x;
  const int kq = bid & 1, vq = (bid >> 1) & 3, h = (bid >> 3) & 15, b = bid >> 7;
  const size_t rb = (size_t)b * TSEQ;
  const int vd_t = tid >> 3, kd0 = (tid & 7) * 4;
  float S[4] = {};
  const int sr = tid >> 2;            // staging row 0..63
  const int cc0 = (tid & 3) * 8;      // 8-col slice
  for (int c = 0; c < 32; ++c) {
    {
      size_t koffg = (rb + (size_t)c * 64 + sr) * 1024 + h * 64 + kq * 32 + cc0;
      U16x8 a0, b0;
      a0.v = *(const uint4*)(kh + koffg);
      b0.v = *(const uint4*)(kl + koffg);
#pragma unroll
      for (int j = 0; j < 8; ++j) Ks[sr][cc0 + j] = bf2f(a0.s[j]) + bf2f(b0.s[j]);
      size_t voffg = (rb + (size_t)c * 64 + sr) * 2048 + h * 128 + vq * 32 + cc0;
      U16x8 va, vb;
      va.v = *(const uint4*)(vgh + voffg);
      vb.v = *(const uint4*)(vgl + voffg);
#pragma unroll
      for (int j = 0; j < 8; ++j) Vs[sr][cc0 + j] = bf2f(va.s[j]) + bf2f(vb.s[j]);
    }
    {
      size_t spc = (((size_t)(b * 16 + h) * 32) + c) * 8192
                 + (size_t)(vq * 32 + vd_t) * 64 + kq * 32 + kd0;
      ushort4 h0, l0;
      split2(S[0], h0.x, l0.x); split2(S[1], h0.y, l0.y);
      split2(S[2], h0.z, l0.z); split2(S[3], h0.w, l0.w);
      *(ushort4*)(Sph + spc) = h0;
      *(ushort4*)(Spl + spc) = l0;
    }
    __syncthreads();
    for (int s = 0; s < 64; ++s) {
      float vv = Vs[s][vd_t];
      float kv[4];
      *(float4*)kv = *(const float4*)&Ks[s][kd0];
#pragma unroll
      for (int j = 0; j < 4; ++j) S[j] = fmaf(vv, kv[j], S[j]);
    }
    __syncthreads();
  }
}

// ======= pass2: O = mask(QK^T) Vg + Q Sp^T  (MFMA, split; proven) ===========
__global__ __launch_bounds__(256) void pass2_sp(const u16* __restrict__ qh,
                                                const u16* __restrict__ ql,
                                                const u16* __restrict__ kh,
                                                const u16* __restrict__ vgh,
                                                const u16* __restrict__ Sph,
                                                const u16* __restrict__ Spl,
                                                u16* __restrict__ oh,
                                                u16* __restrict__ ol) {
  __shared__ u16 Qsh[64 * 72];
  __shared__ u16 Qsl[64 * 72];
  __shared__ u16 Ksm[64 * 72];
  __shared__ u16 Am[64 * 72];
  __shared__ u16 Vth[128 * 72];
  const int tid = threadIdx.x;
  const int l = tid & 63, w = tid >> 6;
  const int bid = blockIdx.x;
  const int c = bid & 31, h = (bid >> 5) & 15, b = bid >> 9;
  const size_t rb = (size_t)b * TSEQ + c * 64;
  const int fr = l & 15, fq = l >> 4;
  {
    int r = tid >> 2, c0 = (tid & 3) * 16;
    size_t off = (rb + r) * 1024 + h * 64 + c0;
    *(uint4*)&Qsh[r * 72 + c0]     = *(const uint4*)(qh + off);
    *(uint4*)&Qsh[r * 72 + c0 + 8] = *(const uint4*)(qh + off + 8);
    *(uint4*)&Qsl[r * 72 + c0]     = *(const uint4*)(ql + off);
    *(uint4*)&Qsl[r * 72 + c0 + 8] = *(const uint4*)(ql + off + 8);
    *(uint4*)&Ksm[r * 72 + c0]     = *(const uint4*)(kh + off);
    *(uint4*)&Ksm[r * 72 + c0 + 8] = *(const uint4*)(kh + off + 8);
  }
  {
    int s = tid >> 2, vd0 = (tid & 3) * 32;
    size_t off = (rb + s) * 2048 + h * 128 + vd0;
#pragma unroll
    for (int m4 = 0; m4 < 4; ++m4) {
      U16x8 r_; r_.v = *(const uint4*)(vgh + off + m4 * 8);
#pragma unroll
      for (int j = 0; j < 8; ++j) Vth[(vd0 + m4 * 8 + j) * 72 + s] = r_.s[j];
    }
  }
  __syncthreads();
  short8 aqh[2], aql[2];
#pragma unroll
  for (int kk = 0; kk < 2; ++kk) {
    aqh[kk] = *(const short8*)&Qsh[(w * 16 + fr) * 72 + kk * 32 + 8 * fq];
    aql[kk] = *(const short8*)&Qsl[(w * 16 + fr) * 72 + kk * 32 + 8 * fq];
  }
  f32x4 accA[4] = {};
#pragma unroll
  for (int n = 0; n < 4; ++n)
#pragma unroll
    for (int kk = 0; kk < 2; ++kk) {
      short8 bk = *(const short8*)&Ksm[(n * 16 + fr) * 72 + kk * 32 + 8 * fq];
      accA[n] = __builtin_amdgcn_mfma_f32_16x16x32_bf16(aqh[kk], bk, accA[n], 0, 0, 0);
    }
#pragma unroll
  for (int n = 0; n < 4; ++n)
#pragma unroll
    for (int rr = 0; rr < 4; ++rr) {
      int tt = w * 16 + 4 * fq + rr;
      int s = n * 16 + fr;
      Am[tt * 72 + s] = f2bf((s <= tt) ? accA[n][rr] : 0.f);
    }
  __syncthreads();
  f32x4 acc[8] = {};
#pragma unroll
  for (int kk = 0; kk < 2; ++kk) {
    short8 aa = *(const short8*)&Am[(w * 16 + fr) * 72 + kk * 32 + 8 * fq];
#pragma unroll
    for (int n = 0; n < 8; ++n) {
      short8 bv = *(const short8*)&Vth[(n * 16 + fr) * 72 + kk * 32 + 8 * fq];
      acc[n] = __builtin_amdgcn_mfma_f32_16x16x32_bf16(aa, bv, acc[n], 0, 0, 0);
    }
  }
  const size_t spb = (((size_t)(b * 16 + h) * 32) + c) * 8192;
#pragma unroll
  for (int n = 0; n < 8; ++n)
#pragma unroll
    for (int kk = 0; kk < 2; ++kk) {
      size_t soff = spb + (size_t)(n * 16 + fr) * 64 + kk * 32 + 8 * fq;
      short8 bh_ = *(const short8*)(Sph + soff);
      short8 bl_ = *(const short8*)(Spl + soff);
      acc[n] = __builtin_amdgcn_mfma_f32_16x16x32_bf16(aqh[kk], bh_, acc[n], 0, 0, 0);
      acc[n] = __builtin_amdgcn_mfma_f32_16x16x32_bf16(aqh[kk], bl_, acc[n], 0, 0, 0);
      acc[n] = __builtin_amdgcn_mfma_f32_16x16x32_bf16(aql[kk], bh_, acc[n], 0, 0, 0);
    }
#pragma unroll
  for (int n = 0; n < 8; ++n)
#pragma unroll
    for (int rr = 0; rr < 4; ++rr) {
      int tt = w * 16 + 4 * fq + rr;
      int vd = n * 16 + fr;
      u16 hh, ll;
      split2(acc[n][rr], hh, ll);
      size_t off = (rb + tt) * 2048 + h * 128 + vd;
      oh[off] = hh; ol[off] = ll;
    }
}

// ===========================================================================
extern "C" void kernel_launch(void* const* d_in, const int* in_sizes, int n_in,
                              void* d_out, int out_size, void* d_ws, size_t ws_size,
                              hipStream_t stream) {
  (void)in_sizes; (void)n_in; (void)out_size; (void)ws_size;
  const float* x  = (const float*)d_in[0];
  const float* Wq = (const float*)d_in[1];
  const float* Wk = (const float*)d_in[2];
  const float* Wv = (const float*)d_in[3];
  const float* gq = (const float*)d_in[4];
  const float* gk = (const float*)d_in[5];
  const float* gv = (const float*)d_in[6];
  const float* cq = (const float*)d_in[7];
  const float* ck = (const float*)d_in[8];
  const float* cv = (const float*)d_in[9];
  const float* Wa = (const float*)d_in[10];
  const float* Wb = (const float*)d_in[11];
  const float* Wo = (const float*)d_in[12];
  const float* Wg = (const float*)d_in[13];
  float* out = (float*)d_out;
  char* ws = (char*)d_ws;

  const size_t MiB = 1024 * 1024;
  // ---- workspace (peak exactly 256 MiB, liveness-audited; same as r9) ----
  u16* Wqkv_h = (u16*)(ws + 0 * MiB);      // 8  ([4096][1024])
  u16* Wqkv_l = (u16*)(ws + 8 * MiB);      // 8
  u16* Wo_h   = (u16*)(ws + 16 * MiB);     // 4
  u16* Wo_l   = (u16*)(ws + 20 * MiB);     // 4
  u16* Wg_h   = (u16*)(ws + 24 * MiB);     // 2
  u16* Wg_l   = (u16*)(ws + 26 * MiB);     // 2
  float* gbuf = (float*)(ws + 28 * MiB);   // 0.5
  u16* x_h    = (u16*)(ws + 32 * MiB);     // 16  [dead after qkv gemm]
  u16* x_l    = (u16*)(ws + 48 * MiB);     // 16
  float* qkv  = (float*)(ws + 64 * MiB);   // 128 [dead after convs]
  u16* q_h = (u16*)(ws + 192 * MiB);       // 16
  u16* q_l = (u16*)(ws + 208 * MiB);       // 16
  u16* k_h = (u16*)(ws + 224 * MiB);       // 16
  u16* k_l = (u16*)(ws + 240 * MiB);       // 16 (ends at 256)
  u16* vg_h = (u16*)(ws + 32 * MiB);       // 32 (x pair dead)
  u16* vg_l = (u16*)d_out;                 // 32 (d_out scratch; dead after scan)
  u16* Sp_h = (u16*)(ws + 96 * MiB);       // 32 (qkv dead)
  u16* Sp_l = (u16*)(ws + 128 * MiB);      // 32
  u16* o_h  = (u16*)(ws + 64 * MiB);       // 32 (qkv head dead)
  u16* o_l  = (u16*)d_out;                 // 32 (vg_l dead after scan)
  float* proj = (float*)(ws + 96 * MiB);   // 32 (Sp_h dead after pass2)
  u16* p_h  = (u16*)(ws + 128 * MiB);      // 16 (Sp_l dead)
  u16* p_l  = (u16*)(ws + 144 * MiB);      // 16

  dim3 blk(256);
  // casts + splits
  castx_sp<<<dim3(8192), blk, 0, stream>>>(x, x_h, x_l);
  transcast_sp<<<dim3(32, 32), blk, 0, stream>>>(Wq, Wqkv_h, Wqkv_l, 1024, 1024);
  transcast_sp<<<dim3(32, 32), blk, 0, stream>>>(Wk, Wqkv_h + 1024 * 1024, Wqkv_l + 1024 * 1024, 1024, 1024);
  transcast_sp<<<dim3(64, 32), blk, 0, stream>>>(Wv, Wqkv_h + 2048 * 1024, Wqkv_l + 2048 * 1024, 1024, 2048);
  transcast_sp<<<dim3(32, 64), blk, 0, stream>>>(Wo, Wo_h, Wo_l, 2048, 1024);
  transcast_sp<<<dim3(32, 32), blk, 0, stream>>>(Wg, Wg_h, Wg_l, 1024, 1024);
  gab_kernel<<<dim3(8192), blk, 0, stream>>>(x, Wa, Wb, gbuf);
  // merged QKV projection: 256^2-tile counted-vmcnt pipelined split GEMM
  gemm_sp_big<<<dim3(16, 32), dim3(512), 0, stream>>>(x_h, x_l, Wqkv_h, Wqkv_l, qkv, 8192, 4096, 1024);
  // fused zrms+conv+silu -> split pairs; v pre-scaled by gab
  conv_fs<1024, 0><<<dim3(8192), dim3(256), 0, stream>>>(qkv, cq, gq, nullptr, q_h, q_l);
  conv_fs<1024, 0><<<dim3(8192), dim3(256), 0, stream>>>(qkv + 1024, ck, gk, nullptr, k_h, k_l);
  conv_fs<2048, 1><<<dim3(8192), dim3(512), 0, stream>>>(qkv + 2048, cv, gv, gbuf, vg_h, vg_l);
  // chunked recurrence
  scan_kernel<<<dim3(512), blk, 0, stream>>>(k_h, k_l, vg_h, vg_l, Sp_h, Sp_l);
  pass2_sp<<<dim3(2048), blk, 0, stream>>>(q_h, q_l, k_h, vg_h, Sp_h, Sp_l, o_h, o_l);
  // output projection + gated final GEMM (split precision)
  gemm_sp<1><<<dim3(8, 64), blk, 0, stream>>>(o_h, o_l, Wo_h, Wo_l, proj, p_h, p_l, nullptr, 8192, 1024, 2048);
  gemm_sp<2><<<dim3(8, 64), blk, 0, stream>>>(p_h, p_l, Wg_h, Wg_l, out, nullptr, nullptr, proj, 8192, 1024, 1024);
}

// Round 12
// 671.925 us; speedup vs baseline: 3.7932x; 1.0061x over previous
//
#include <hip/hip_runtime.h>
#include <hip/hip_bf16.h>
#include <math.h>

#define RTOT 8192      // B*T
#define TSEQ 2048

typedef __attribute__((ext_vector_type(8))) short short8;
typedef __attribute__((ext_vector_type(4))) float f32x4;
typedef unsigned short u16;
typedef unsigned int u32;

union U16x8 { uint4 v; u16 s[8]; };

__device__ __forceinline__ float sigmoidf_(float x) { return 1.f / (1.f + expf(-x)); }
__device__ __forceinline__ float bf2f(u16 v) { u32 u = ((u32)v) << 16; float f; __builtin_memcpy(&f, &u, 4); return f; }
__device__ __forceinline__ u16 f2bf(float f) {
  u32 u; __builtin_memcpy(&u, &f, 4);
  u32 r = (u + 0x7FFFu + ((u >> 16) & 1u)) >> 16;
  return (u16)r;
}
// split f32 -> hi bf16 + lo bf16 (residual)
__device__ __forceinline__ void split2(float x, u16& h, u16& l) {
  u16 hh = f2bf(x);
  float hf = bf2f(hh);
  h = hh; l = f2bf(x - hf);
}

typedef const void __attribute__((address_space(1))) gvoid_t;
typedef void __attribute__((address_space(3))) lvoid_t;
__device__ __forceinline__ void gload_lds16(const void* g, void* l) {
  __builtin_amdgcn_global_load_lds((gvoid_t*)g, (lvoid_t*)l, 16, 0, 0);
}

// XCD-chunked bijective block remap (nwg % 8 == 0 required)
__device__ __forceinline__ void xcd_remap(int& bx, int& by) {
  int gx = gridDim.x, nwg = gx * gridDim.y;
  int bid = blockIdx.y * gx + blockIdx.x;
  int cpx = nwg >> 3;
  int swz = (bid & 7) * cpx + (bid >> 3);
  bx = swz % gx; by = swz / gx;
}

// ======= 256^2-tile 4-phase pipelined split-bf16 GEMM (QKV) =================
// C = A[M,K] @ Bt[N,K]^T, 3-term split (AhBh + AhBl + AlBh), f32 out.
// 512 threads = 8 waves (2M x 4N); BK=32; LDS 128 KB double-buffered.
// Per K-step: 4 phases {ds_read subtile | stage -> barrier -> lgkm(0) ->
// setprio(1) -> 24 MFMA -> setprio(0) -> barrier}. Distance-1 prefetch into
// the buffer freed last iteration; vmcnt(0) only at P3 (loads 2-3 phases old).
__global__ __launch_bounds__(512) void gemm_sp_big(const u16* __restrict__ Ah, const u16* __restrict__ Al,
                                                   const u16* __restrict__ Bh, const u16* __restrict__ Bl,
                                                   float* __restrict__ Cf,
                                                   int M, int N, int K) {
  __shared__ u16 lds[2][4][256 * 32];   // [buf][Ah,Al,Bh,Bl][row][k]
  int bx, by; xcd_remap(bx, by);
  const int tid = threadIdx.x;
  const int l = tid & 63, w = tid >> 6;
  const int wr = w >> 2, wc = w & 3;           // 2 x 4 wave grid
  const int m0 = by * 256, n0 = bx * 256;
  const int fr = l & 15, fq = l >> 4;
  const int koff = 8 * (fq ^ (fr & 3));        // swizzled read granule (proven-neutral, kept)
  const int srow = tid >> 2;
  const int scol = ((tid & 3) ^ (srow & 3)) * 8;
  const u16* gA_h = Ah + (size_t)(m0 + srow) * K + scol;
  const u16* gA_l = Al + (size_t)(m0 + srow) * K + scol;
  const u16* gB_h = Bh + (size_t)(n0 + srow) * K + scol;
  const u16* gB_l = Bl + (size_t)(n0 + srow) * K + scol;
  const int lo = srow * 32 + (tid & 3) * 8;    // linear LDS dest
  const int NT = K >> 5;

#define STG(buf, mat, src, t)                                 \
  do {                                                        \
    const int k0_ = (t) << 5;                                 \
    gload_lds16(src + k0_, &lds[buf][mat][lo]);               \
    gload_lds16(src + 128 * K + k0_, &lds[buf][mat][lo + 4096]); \
  } while (0)

#define MFMA_PAIR(mi, a_h, a_l)                                                        \
  do {                                                                                 \
    _Pragma("unroll")                                                                  \
    for (int n = 0; n < 4; ++n) {                                                      \
      acc[mi][n] = __builtin_amdgcn_mfma_f32_16x16x32_bf16(a_h, bh8[n], acc[mi][n], 0, 0, 0); \
      acc[mi][n] = __builtin_amdgcn_mfma_f32_16x16x32_bf16(a_h, bl8[n], acc[mi][n], 0, 0, 0); \
      acc[mi][n] = __builtin_amdgcn_mfma_f32_16x16x32_bf16(a_l, bh8[n], acc[mi][n], 0, 0, 0); \
    }                                                                                  \
  } while (0)

  f32x4 acc[8][4] = {};
  // prologue: stage tile 0 into buf 0
  STG(0, 0, gA_h, 0); STG(0, 1, gA_l, 0); STG(0, 2, gB_h, 0); STG(0, 3, gB_l, 0);
  asm volatile("s_waitcnt vmcnt(0)" ::: "memory");
  __builtin_amdgcn_s_barrier();

  for (int t = 0; t < NT; ++t) {
    const int c = t & 1, o = c ^ 1;
    const bool pf = (t + 1 < NT);
    short8 bh8[4], bl8[4];
    // ================ P0: B-frags + A m=0,1 | stage B(t+1) ================
    {
#pragma unroll
      for (int n = 0; n < 4; ++n) {
        bh8[n] = *(const short8*)&lds[c][2][(wc * 64 + n * 16 + fr) * 32 + koff];
        bl8[n] = *(const short8*)&lds[c][3][(wc * 64 + n * 16 + fr) * 32 + koff];
      }
      short8 a0h = *(const short8*)&lds[c][0][(wr * 128 + 0 * 16 + fr) * 32 + koff];
      short8 a1h = *(const short8*)&lds[c][0][(wr * 128 + 1 * 16 + fr) * 32 + koff];
      short8 a0l = *(const short8*)&lds[c][1][(wr * 128 + 0 * 16 + fr) * 32 + koff];
      short8 a1l = *(const short8*)&lds[c][1][(wr * 128 + 1 * 16 + fr) * 32 + koff];
      if (pf) { STG(o, 2, gB_h, t + 1); STG(o, 3, gB_l, t + 1); }
      __builtin_amdgcn_s_barrier();
      asm volatile("s_waitcnt lgkmcnt(0)" ::: "memory");
      __builtin_amdgcn_s_setprio(1);
      MFMA_PAIR(0, a0h, a0l);
      MFMA_PAIR(1, a1h, a1l);
      __builtin_amdgcn_s_setprio(0);
      __builtin_amdgcn_s_barrier();
    }
    // ================ P1: A m=2,3 | stage A(t+1) ==========================
    {
      short8 a0h = *(const short8*)&lds[c][0][(wr * 128 + 2 * 16 + fr) * 32 + koff];
      short8 a1h = *(const short8*)&lds[c][0][(wr * 128 + 3 * 16 + fr) * 32 + koff];
      short8 a0l = *(const short8*)&lds[c][1][(wr * 128 + 2 * 16 + fr) * 32 + koff];
      short8 a1l = *(const short8*)&lds[c][1][(wr * 128 + 3 * 16 + fr) * 32 + koff];
      if (pf) { STG(o, 0, gA_h, t + 1); STG(o, 1, gA_l, t + 1); }
      __builtin_amdgcn_s_barrier();
      asm volatile("s_waitcnt lgkmcnt(0)" ::: "memory");
      __builtin_amdgcn_s_setprio(1);
      MFMA_PAIR(2, a0h, a0l);
      MFMA_PAIR(3, a1h, a1l);
      __builtin_amdgcn_s_setprio(0);
      __builtin_amdgcn_s_barrier();
    }
    // ================ P2: A m=4,5 =========================================
    {
      short8 a0h = *(const short8*)&lds[c][0][(wr * 128 + 4 * 16 + fr) * 32 + koff];
      short8 a1h = *(const short8*)&lds[c][0][(wr * 128 + 5 * 16 + fr) * 32 + koff];
      short8 a0l = *(const short8*)&lds[c][1][(wr * 128 + 4 * 16 + fr) * 32 + koff];
      short8 a1l = *(const short8*)&lds[c][1][(wr * 128 + 5 * 16 + fr) * 32 + koff];
      __builtin_amdgcn_s_barrier();
      asm volatile("s_waitcnt lgkmcnt(0)" ::: "memory");
      __builtin_amdgcn_s_setprio(1);
      MFMA_PAIR(4, a0h, a0l);
      MFMA_PAIR(5, a1h, a1l);
      __builtin_amdgcn_s_setprio(0);
      __builtin_amdgcn_s_barrier();
    }
    // ================ P3: A m=6,7 | drain t+1 loads =======================
    {
      short8 a0h = *(const short8*)&lds[c][0][(wr * 128 + 6 * 16 + fr) * 32 + koff];
      short8 a1h = *(const short8*)&lds[c][0][(wr * 128 + 7 * 16 + fr) * 32 + koff];
      short8 a0l = *(const short8*)&lds[c][1][(wr * 128 + 6 * 16 + fr) * 32 + koff];
      short8 a1l = *(const short8*)&lds[c][1][(wr * 128 + 7 * 16 + fr) * 32 + koff];
      __builtin_amdgcn_s_barrier();
      asm volatile("s_waitcnt lgkmcnt(0)" ::: "memory");
      __builtin_amdgcn_s_setprio(1);
      MFMA_PAIR(6, a0h, a0l);
      MFMA_PAIR(7, a1h, a1l);
      __builtin_amdgcn_s_setprio(0);
      if (pf) asm volatile("s_waitcnt vmcnt(0)" ::: "memory");  // t+1 ready (issued P0/P1)
      __builtin_amdgcn_s_barrier();
    }
  }
#undef STG
#undef MFMA_PAIR
  // epilogue: f32 C-write
#pragma unroll
  for (int m = 0; m < 8; ++m)
#pragma unroll
    for (int n = 0; n < 4; ++n)
#pragma unroll
      for (int r = 0; r < 4; ++r)
        Cf[(size_t)(m0 + wr * 128 + m * 16 + 4 * fq + r) * N + (n0 + wc * 64 + n * 16 + fr)] = acc[m][n][r];
}

// ======= split-bf16 MFMA GEMM at ~f32 precision (proven, 128^2) =============
// EPI 0: f32 out.  EPI 1: f32 out + split pair out.  EPI 2: f32 out = Pin * sigmoid(acc)
template<int EPI>
__global__ __launch_bounds__(256) void gemm_sp(const u16* __restrict__ Ah, const u16* __restrict__ Al,
                                               const u16* __restrict__ Bh, const u16* __restrict__ Bl,
                                               float* __restrict__ Cf, u16* __restrict__ Ph,
                                               u16* __restrict__ Pl, const float* __restrict__ Pin,
                                               int M, int N, int K) {
  __shared__ u16 Ash[128 * 32], Asl[128 * 32];
  __shared__ u16 Bsh[128 * 32], Bsl[128 * 32];
  int bx, by; xcd_remap(bx, by);
  const int tid = threadIdx.x;
  const int l = tid & 63, w = tid >> 6;
  const int m0 = by * 128, n0 = bx * 128;
  const int wr = w >> 1, wc = w & 1;
  f32x4 acc[4][4] = {};
  const int srow = (w << 5) + (l >> 2);
  const int scol = (l & 3) << 3;
  const size_t gA = (size_t)(m0 + srow) * K + scol;
  const size_t gB = (size_t)(n0 + srow) * K + scol;
  const int lo0 = (w * 2 + 0) * 512, lo1 = (w * 2 + 1) * 512;
  const int arow = wr * 64 + (l & 15), brow = wc * 64 + (l & 15);
  const int koff = 8 * (l >> 4);
  for (int k0 = 0; k0 < K; k0 += 32) {
    gload_lds16(Ah + gA + k0, &Ash[lo0]);
    gload_lds16(Ah + gA + 16 * K + k0, &Ash[lo1]);
    gload_lds16(Al + gA + k0, &Asl[lo0]);
    gload_lds16(Al + gA + 16 * K + k0, &Asl[lo1]);
    gload_lds16(Bh + gB + k0, &Bsh[lo0]);
    gload_lds16(Bh + gB + 16 * K + k0, &Bsh[lo1]);
    gload_lds16(Bl + gB + k0, &Bsl[lo0]);
    gload_lds16(Bl + gB + 16 * K + k0, &Bsl[lo1]);
    __syncthreads();
    short8 afh[4], afl[4], bfh[4], bfl[4];
#pragma unroll
    for (int m = 0; m < 4; ++m) {
      afh[m] = *(const short8*)&Ash[(arow + m * 16) * 32 + koff];
      afl[m] = *(const short8*)&Asl[(arow + m * 16) * 32 + koff];
    }
#pragma unroll
    for (int n = 0; n < 4; ++n) {
      bfh[n] = *(const short8*)&Bsh[(brow + n * 16) * 32 + koff];
      bfl[n] = *(const short8*)&Bsl[(brow + n * 16) * 32 + koff];
    }
#pragma unroll
    for (int m = 0; m < 4; ++m)
#pragma unroll
      for (int n = 0; n < 4; ++n) {
        acc[m][n] = __builtin_amdgcn_mfma_f32_16x16x32_bf16(afh[m], bfh[n], acc[m][n], 0, 0, 0);
        acc[m][n] = __builtin_amdgcn_mfma_f32_16x16x32_bf16(afh[m], bfl[n], acc[m][n], 0, 0, 0);
        acc[m][n] = __builtin_amdgcn_mfma_f32_16x16x32_bf16(afl[m], bfh[n], acc[m][n], 0, 0, 0);
      }
    __syncthreads();
  }
  const int rbase = m0 + wr * 64 + 4 * (l >> 4);
  const int cbase = n0 + wc * 64 + (l & 15);
#pragma unroll
  for (int m = 0; m < 4; ++m)
#pragma unroll
    for (int n = 0; n < 4; ++n)
#pragma unroll
      for (int r = 0; r < 4; ++r) {
        size_t idx = (size_t)(rbase + m * 16 + r) * N + (cbase + n * 16);
        float v = acc[m][n][r];
        if (EPI == 0) {
          Cf[idx] = v;
        } else if (EPI == 1) {
          Cf[idx] = v;
          u16 h, lo; split2(v, h, lo);
          Ph[idx] = h; Pl[idx] = lo;
        } else {
          Cf[idx] = Pin[idx] * sigmoidf_(v);
        }
      }
}

// ======= weight cast+transpose+split: W[K][N] f32 -> Wt_h/Wt_l [N][K] =======
__global__ __launch_bounds__(256) void transcast_sp(const float* __restrict__ W,
                                                    u16* __restrict__ Wth, u16* __restrict__ Wtl,
                                                    int K, int N) {
  __shared__ float t[32][33];
  const int n0 = blockIdx.x * 32, k0 = blockIdx.y * 32;
  const int c = threadIdx.x & 31, rq = threadIdx.x >> 5;
#pragma unroll
  for (int i = 0; i < 4; ++i) t[rq * 4 + i][c] = W[(size_t)(k0 + rq * 4 + i) * N + n0 + c];
  __syncthreads();
#pragma unroll
  for (int i = 0; i < 4; ++i) {
    float v = t[c][rq * 4 + i];
    u16 h, lo; split2(v, h, lo);
    size_t idx = (size_t)(n0 + rq * 4 + i) * K + k0 + c;
    Wth[idx] = h; Wtl[idx] = lo;
  }
}

// ======= x cast+split f32 -> bf16 hi/lo =====================================
__global__ __launch_bounds__(256) void castx_sp(const float* __restrict__ x,
                                                u16* __restrict__ xh, u16* __restrict__ xl) {
  size_t i = (size_t)blockIdx.x * 256 + threadIdx.x;
  float4 v = ((const float4*)x)[i];
  ushort4 hh, ll;
  split2(v.x, hh.x, ll.x); split2(v.y, hh.y, ll.y);
  split2(v.z, hh.z, ll.z); split2(v.w, hh.w, ll.w);
  ((ushort4*)xh)[i] = hh; ((ushort4*)xl)[i] = ll;
}

// ======= fused zrms(stats inline) + conv(K=4) + SiLU -> split pair ==========
template<int C, int GSCALE>
__global__ __launch_bounds__(C / 4) void conv_fs(const float* __restrict__ zn,
                                                 const float* __restrict__ w,
                                                 const float* __restrict__ g,
                                                 const float* __restrict__ gab,
                                                 u16* __restrict__ oh,
                                                 u16* __restrict__ ol) {
  constexpr int NW = C / 256;   // waves per block (4 or 8)
  __shared__ float redA[NW * 4];
  __shared__ float redB[NW * 4];
  const int tid = threadIdx.x;
  const int row = blockIdx.x;
  const int t = row & (TSEQ - 1);
  const int c = tid * 4;
  const int lane = tid & 63, wid = tid >> 6;
  float4 xv[4];
  float psum[4];
#pragma unroll
  for (int d = 0; d < 4; ++d) {
    if (t - d >= 0) xv[d] = *(const float4*)(zn + (size_t)(row - d) * 4096 + c);
    else { xv[d].x = 0.f; xv[d].y = 0.f; xv[d].z = 0.f; xv[d].w = 0.f; }
    psum[d] = xv[d].x + xv[d].y + xv[d].z + xv[d].w;
  }
#pragma unroll
  for (int d = 0; d < 4; ++d)
#pragma unroll
    for (int o = 32; o > 0; o >>= 1) psum[d] += __shfl_xor(psum[d], o, 64);
  if (lane == 0) {
    redA[wid * 4 + 0] = psum[0]; redA[wid * 4 + 1] = psum[1];
    redA[wid * 4 + 2] = psum[2]; redA[wid * 4 + 3] = psum[3];
  }
  __syncthreads();
  float mean[4];
#pragma unroll
  for (int d = 0; d < 4; ++d) {
    float s = 0.f;
#pragma unroll
    for (int j = 0; j < NW; ++j) s += redA[j * 4 + d];
    mean[d] = s * (1.f / C);
  }
  float psq[4];
#pragma unroll
  for (int d = 0; d < 4; ++d) {
    float a = xv[d].x - mean[d], b = xv[d].y - mean[d];
    float e = xv[d].z - mean[d], f = xv[d].w - mean[d];
    psq[d] = a * a + b * b + e * e + f * f;
  }
#pragma unroll
  for (int d = 0; d < 4; ++d)
#pragma unroll
    for (int o = 32; o > 0; o >>= 1) psq[d] += __shfl_xor(psq[d], o, 64);
  if (lane == 0) {
    redB[wid * 4 + 0] = psq[0]; redB[wid * 4 + 1] = psq[1];
    redB[wid * 4 + 2] = psq[2]; redB[wid * 4 + 3] = psq[3];
  }
  __syncthreads();
  float rstd[4];
#pragma unroll
  for (int d = 0; d < 4; ++d) {
    float s = 0.f;
#pragma unroll
    for (int j = 0; j < NW; ++j) s += redB[j * 4 + d];
    rstd[d] = rsqrtf(s * (1.f / C) + 1e-5f);
  }
  float4 g4 = *(const float4*)(g + c);
  float4 acc; acc.x = 0.f; acc.y = 0.f; acc.z = 0.f; acc.w = 0.f;
#pragma unroll
  for (int d = 0; d < 4; ++d) {
    if (t - d >= 0) {
      float4 wv = *(const float4*)(w + (size_t)(3 - d) * C + c);
      acc.x = fmaf((xv[d].x - mean[d]) * rstd[d] * g4.x, wv.x, acc.x);
      acc.y = fmaf((xv[d].y - mean[d]) * rstd[d] * g4.y, wv.y, acc.y);
      acc.z = fmaf((xv[d].z - mean[d]) * rstd[d] * g4.z, wv.z, acc.z);
      acc.w = fmaf((xv[d].w - mean[d]) * rstd[d] * g4.w, wv.w, acc.w);
    }
  }
  float a0 = acc.x * sigmoidf_(acc.x);
  float a1 = acc.y * sigmoidf_(acc.y);
  float a2 = acc.z * sigmoidf_(acc.z);
  float a3 = acc.w * sigmoidf_(acc.w);
  if (GSCALE) {
    float gv = gab[(size_t)row * 16 + (c >> 7)];
    a0 *= gv; a1 *= gv; a2 *= gv; a3 *= gv;
  }
  ushort4 hh, ll;
  split2(a0, hh.x, ll.x); split2(a1, hh.y, ll.y);
  split2(a2, hh.z, ll.z); split2(a3, hh.w, ll.w);
  *(ushort4*)(oh + (size_t)row * C + c) = hh;
  *(ushort4*)(ol + (size_t)row * C + c) = ll;
}

// ======= g = sigmoid(x@Wa)*sigmoid(x@Wb) per (row,head) (proven) ============
__global__ __launch_bounds__(256) void gab_kernel(const float* __restrict__ x,
                                                  const float* __restrict__ Wa,
                                                  const float* __restrict__ Wb,
                                                  float* __restrict__ gout) {
  __shared__ float xs[1024];
  __shared__ float partial[256];
  const int tid = threadIdx.x;
  const size_t row = blockIdx.x;
  *(float4*)(&xs[tid*4]) = *(const float4*)(x + row*1024 + tid*4);
  __syncthreads();
  const int h = tid & 31;
  const int seg = tid >> 5;
  const float* W = (h < 16) ? Wa : Wb;
  const int col = h & 15;
  float s = 0.f;
  const int k0 = seg * 128;
  for (int k = 0; k < 128; ++k) s = fmaf(xs[k0 + k], W[(size_t)(k0 + k) * 16 + col], s);
  partial[tid] = s;
  __syncthreads();
  if (tid < 32) {
    float t2 = 0.f;
#pragma unroll
    for (int j = 0; j < 8; ++j) t2 += partial[j*32 + tid];
    partial[tid] = t2;
  }
  __syncthreads();
  if (tid < 16)
    gout[row*16 + tid] = sigmoidf_(partial[tid]) * sigmoidf_(partial[tid + 16]);
}

// ======= scan: exclusive chunk-prefix of Vg^T K, kd-split (512 blocks) ======
__global__ __launch_bounds__(256) void scan_kernel(const u16* __restrict__ kh,
                                                   const u16* __restrict__ kl,
                                                   const u16* __restrict__ vgh,
                                                   const u16* __restrict__ vgl,
                                                   u16* __restrict__ Sph,
                                                   u16* __restrict__ Spl) {
  __shared__ float Ks[64][36];
  __shared__ float Vs[64][36];
  const int tid = threadIdx.x;
  const int bid = blockIdx.x;
  const int kq = bid & 1, vq = (bid >> 1) & 3, h = (bid >> 3) & 15, b = bid >> 7;
  const size_t rb = (size_t)b * TSEQ;
  const int vd_t = tid >> 3, kd0 = (tid & 7) * 4;
  float S[4] = {};
  const int sr = tid >> 2;            // staging row 0..63
  const int cc0 = (tid & 3) * 8;      // 8-col slice
  for (int c = 0; c < 32; ++c) {
    {
      size_t koffg = (rb + (size_t)c * 64 + sr) * 1024 + h * 64 + kq * 32 + cc0;
      U16x8 a0, b0;
      a0.v = *(const uint4*)(kh + koffg);
      b0.v = *(const uint4*)(kl + koffg);
#pragma unroll
      for (int j = 0; j < 8; ++j) Ks[sr][cc0 + j] = bf2f(a0.s[j]) + bf2f(b0.s[j]);
      size_t voffg = (rb + (size_t)c * 64 + sr) * 2048 + h * 128 + vq * 32 + cc0;
      U16x8 va, vb;
      va.v = *(const uint4*)(vgh + voffg);
      vb.v = *(const uint4*)(vgl + voffg);
#pragma unroll
      for (int j = 0; j < 8; ++j) Vs[sr][cc0 + j] = bf2f(va.s[j]) + bf2f(vb.s[j]);
    }
    {
      size_t spc = (((size_t)(b * 16 + h) * 32) + c) * 8192
                 + (size_t)(vq * 32 + vd_t) * 64 + kq * 32 + kd0;
      ushort4 h0, l0;
      split2(S[0], h0.x, l0.x); split2(S[1], h0.y, l0.y);
      split2(S[2], h0.z, l0.z); split2(S[3], h0.w, l0.w);
      *(ushort4*)(Sph + spc) = h0;
      *(ushort4*)(Spl + spc) = l0;
    }
    __syncthreads();
    for (int s = 0; s < 64; ++s) {
      float vv = Vs[s][vd_t];
      float kv[4];
      *(float4*)kv = *(const float4*)&Ks[s][kd0];
#pragma unroll
      for (int j = 0; j < 4; ++j) S[j] = fmaf(vv, kv[j], S[j]);
    }
    __syncthreads();
  }
}

// ======= pass2: O = mask(QK^T) Vg + Q Sp^T  (MFMA, split; proven) ===========
__global__ __launch_bounds__(256) void pass2_sp(const u16* __restrict__ qh,
                                                const u16* __restrict__ ql,
                                                const u16* __restrict__ kh,
                                                const u16* __restrict__ vgh,
                                                const u16* __restrict__ Sph,
                                                const u16* __restrict__ Spl,
                                                u16* __restrict__ oh,
                                                u16* __restrict__ ol) {
  __shared__ u16 Qsh[64 * 72];
  __shared__ u16 Qsl[64 * 72];
  __shared__ u16 Ksm[64 * 72];
  __shared__ u16 Am[64 * 72];
  __shared__ u16 Vth[128 * 72];
  const int tid = threadIdx.x;
  const int l = tid & 63, w = tid >> 6;
  const int bid = blockIdx.x;
  const int c = bid & 31, h = (bid >> 5) & 15, b = bid >> 9;
  const size_t rb = (size_t)b * TSEQ + c * 64;
  const int fr = l & 15, fq = l >> 4;
  {
    int r = tid >> 2, c0 = (tid & 3) * 16;
    size_t off = (rb + r) * 1024 + h * 64 + c0;
    *(uint4*)&Qsh[r * 72 + c0]     = *(const uint4*)(qh + off);
    *(uint4*)&Qsh[r * 72 + c0 + 8] = *(const uint4*)(qh + off + 8);
    *(uint4*)&Qsl[r * 72 + c0]     = *(const uint4*)(ql + off);
    *(uint4*)&Qsl[r * 72 + c0 + 8] = *(const uint4*)(ql + off + 8);
    *(uint4*)&Ksm[r * 72 + c0]     = *(const uint4*)(kh + off);
    *(uint4*)&Ksm[r * 72 + c0 + 8] = *(const uint4*)(kh + off + 8);
  }
  {
    int s = tid >> 2, vd0 = (tid & 3) * 32;
    size_t off = (rb + s) * 2048 + h * 128 + vd0;
#pragma unroll
    for (int m4 = 0; m4 < 4; ++m4) {
      U16x8 r_; r_.v = *(const uint4*)(vgh + off + m4 * 8);
#pragma unroll
      for (int j = 0; j < 8; ++j) Vth[(vd0 + m4 * 8 + j) * 72 + s] = r_.s[j];
    }
  }
  __syncthreads();
  short8 aqh[2], aql[2];
#pragma unroll
  for (int kk = 0; kk < 2; ++kk) {
    aqh[kk] = *(const short8*)&Qsh[(w * 16 + fr) * 72 + kk * 32 + 8 * fq];
    aql[kk] = *(const short8*)&Qsl[(w * 16 + fr) * 72 + kk * 32 + 8 * fq];
  }
  f32x4 accA[4] = {};
#pragma unroll
  for (int n = 0; n < 4; ++n)
#pragma unroll
    for (int kk = 0; kk < 2; ++kk) {
      short8 bk = *(const short8*)&Ksm[(n * 16 + fr) * 72 + kk * 32 + 8 * fq];
      accA[n] = __builtin_amdgcn_mfma_f32_16x16x32_bf16(aqh[kk], bk, accA[n], 0, 0, 0);
    }
#pragma unroll
  for (int n = 0; n < 4; ++n)
#pragma unroll
    for (int rr = 0; rr < 4; ++rr) {
      int tt = w * 16 + 4 * fq + rr;
      int s = n * 16 + fr;
      Am[tt * 72 + s] = f2bf((s <= tt) ? accA[n][rr] : 0.f);
    }
  __syncthreads();
  f32x4 acc[8] = {};
#pragma unroll
  for (int kk = 0; kk < 2; ++kk) {
    short8 aa = *(const short8*)&Am[(w * 16 + fr) * 72 + kk * 32 + 8 * fq];
#pragma unroll
    for (int n = 0; n < 8; ++n) {
      short8 bv = *(const short8*)&Vth[(n * 16 + fr) * 72 + kk * 32 + 8 * fq];
      acc[n] = __builtin_amdgcn_mfma_f32_16x16x32_bf16(aa, bv, acc[n], 0, 0, 0);
    }
  }
  const size_t spb = (((size_t)(b * 16 + h) * 32) + c) * 8192;
#pragma unroll
  for (int n = 0; n < 8; ++n)
#pragma unroll
    for (int kk = 0; kk < 2; ++kk) {
      size_t soff = spb + (size_t)(n * 16 + fr) * 64 + kk * 32 + 8 * fq;
      short8 bh_ = *(const short8*)(Sph + soff);
      short8 bl_ = *(const short8*)(Spl + soff);
      acc[n] = __builtin_amdgcn_mfma_f32_16x16x32_bf16(aqh[kk], bh_, acc[n], 0, 0, 0);
      acc[n] = __builtin_amdgcn_mfma_f32_16x16x32_bf16(aqh[kk], bl_, acc[n], 0, 0, 0);
      acc[n] = __builtin_amdgcn_mfma_f32_16x16x32_bf16(aql[kk], bh_, acc[n], 0, 0, 0);
    }
#pragma unroll
  for (int n = 0; n < 8; ++n)
#pragma unroll
    for (int rr = 0; rr < 4; ++rr) {
      int tt = w * 16 + 4 * fq + rr;
      int vd = n * 16 + fr;
      u16 hh, ll;
      split2(acc[n][rr], hh, ll);
      size_t off = (rb + tt) * 2048 + h * 128 + vd;
      oh[off] = hh; ol[off] = ll;
    }
}

// ===========================================================================
extern "C" void kernel_launch(void* const* d_in, const int* in_sizes, int n_in,
                              void* d_out, int out_size, void* d_ws, size_t ws_size,
                              hipStream_t stream) {
  (void)in_sizes; (void)n_in; (void)out_size; (void)ws_size;
  const float* x  = (const float*)d_in[0];
  const float* Wq = (const float*)d_in[1];
  const float* Wk = (const float*)d_in[2];
  const float* Wv = (const float*)d_in[3];
  const float* gq = (const float*)d_in[4];
  const float* gk = (const float*)d_in[5];
  const float* gv = (const float*)d_in[6];
  const float* cq = (const float*)d_in[7];
  const float* ck = (const float*)d_in[8];
  const float* cv = (const float*)d_in[9];
  const float* Wa = (const float*)d_in[10];
  const float* Wb = (const float*)d_in[11];
  const float* Wo = (const float*)d_in[12];
  const float* Wg = (const float*)d_in[13];
  float* out = (float*)d_out;
  char* ws = (char*)d_ws;

  const size_t MiB = 1024 * 1024;
  // ---- workspace (peak exactly 256 MiB, liveness-audited; same as r9) ----
  u16* Wqkv_h = (u16*)(ws + 0 * MiB);      // 8  ([4096][1024])
  u16* Wqkv_l = (u16*)(ws + 8 * MiB);      // 8
  u16* Wo_h   = (u16*)(ws + 16 * MiB);     // 4
  u16* Wo_l   = (u16*)(ws + 20 * MiB);     // 4
  u16* Wg_h   = (u16*)(ws + 24 * MiB);     // 2
  u16* Wg_l   = (u16*)(ws + 26 * MiB);     // 2
  float* gbuf = (float*)(ws + 28 * MiB);   // 0.5
  u16* x_h    = (u16*)(ws + 32 * MiB);     // 16  [dead after qkv gemm]
  u16* x_l    = (u16*)(ws + 48 * MiB);     // 16
  float* qkv  = (float*)(ws + 64 * MiB);   // 128 [dead after convs]
  u16* q_h = (u16*)(ws + 192 * MiB);       // 16
  u16* q_l = (u16*)(ws + 208 * MiB);       // 16
  u16* k_h = (u16*)(ws + 224 * MiB);       // 16
  u16* k_l = (u16*)(ws + 240 * MiB);       // 16 (ends at 256)
  u16* vg_h = (u16*)(ws + 32 * MiB);       // 32 (x pair dead)
  u16* vg_l = (u16*)d_out;                 // 32 (d_out scratch; dead after scan)
  u16* Sp_h = (u16*)(ws + 96 * MiB);       // 32 (qkv dead)
  u16* Sp_l = (u16*)(ws + 128 * MiB);      // 32
  u16* o_h  = (u16*)(ws + 64 * MiB);       // 32 (qkv head dead)
  u16* o_l  = (u16*)d_out;                 // 32 (vg_l dead after scan)
  float* proj = (float*)(ws + 96 * MiB);   // 32 (Sp_h dead after pass2)
  u16* p_h  = (u16*)(ws + 128 * MiB);      // 16 (Sp_l dead)
  u16* p_l  = (u16*)(ws + 144 * MiB);      // 16

  dim3 blk(256);
  // casts + splits
  castx_sp<<<dim3(8192), blk, 0, stream>>>(x, x_h, x_l);
  transcast_sp<<<dim3(32, 32), blk, 0, stream>>>(Wq, Wqkv_h, Wqkv_l, 1024, 1024);
  transcast_sp<<<dim3(32, 32), blk, 0, stream>>>(Wk, Wqkv_h + 1024 * 1024, Wqkv_l + 1024 * 1024, 1024, 1024);
  transcast_sp<<<dim3(64, 32), blk, 0, stream>>>(Wv, Wqkv_h + 2048 * 1024, Wqkv_l + 2048 * 1024, 1024, 2048);
  transcast_sp<<<dim3(32, 64), blk, 0, stream>>>(Wo, Wo_h, Wo_l, 2048, 1024);
  transcast_sp<<<dim3(32, 32), blk, 0, stream>>>(Wg, Wg_h, Wg_l, 1024, 1024);
  gab_kernel<<<dim3(8192), blk, 0, stream>>>(x, Wa, Wb, gbuf);
  // merged QKV projection: 256^2-tile 4-phase pipelined split GEMM
  gemm_sp_big<<<dim3(16, 32), dim3(512), 0, stream>>>(x_h, x_l, Wqkv_h, Wqkv_l, qkv, 8192, 4096, 1024);
  // fused zrms+conv+silu -> split pairs; v pre-scaled by gab
  conv_fs<1024, 0><<<dim3(8192), dim3(256), 0, stream>>>(qkv, cq, gq, nullptr, q_h, q_l);
  conv_fs<1024, 0><<<dim3(8192), dim3(256), 0, stream>>>(qkv + 1024, ck, gk, nullptr, k_h, k_l);
  conv_fs<2048, 1><<<dim3(8192), dim3(512), 0, stream>>>(qkv + 2048, cv, gv, gbuf, vg_h, vg_l);
  // chunked recurrence
  scan_kernel<<<dim3(512), blk, 0, stream>>>(k_h, k_l, vg_h, vg_l, Sp_h, Sp_l);
  pass2_sp<<<dim3(2048), blk, 0, stream>>>(q_h, q_l, k_h, vg_h, Sp_h, Sp_l, o_h, o_l);
  // output projection + gated final GEMM (split precision)
  gemm_sp<1><<<dim3(8, 64), blk, 0, stream>>>(o_h, o_l, Wo_h, Wo_l, proj, p_h, p_l, nullptr, 8192, 1024, 2048);
  gemm_sp<2><<<dim3(8, 64), blk, 0, stream>>>(p_h, p_l, Wg_h, Wg_l, out, nullptr, nullptr, proj, 8192, 1024, 1024);
}